// Round 1
// baseline (2304.223 us; speedup 1.0000x reference)
//
#include <hip/hip_runtime.h>
#include <hip/hip_bf16.h>
#include <math.h>

// Sizes (fixed by the reference)
#define GG   4096
#define NNODE 64
#define EEDGE 256
#define FFEAT 64
#define DDIM 128
#define EP   32768

// ---------------------------------------------------------------------------
// Kernel 1: one block per graph. Computes h (GCNConv), S (MLP+softmax),
// Laplacian penalty, and g_emb. LDS-resident throughout.
// ---------------------------------------------------------------------------
__global__ __launch_bounds__(256, 2) void k_per_graph(
    const float* __restrict__ x, const int* __restrict__ ei, const float* __restrict__ ew,
    const float* __restrict__ Wg, const float* __restrict__ bg,
    const float* __restrict__ Wf1, const float* __restrict__ bf1,
    const float* __restrict__ Wf2, const float* __restrict__ bf2,
    float* __restrict__ g_embs, float* __restrict__ pens)
{
    __shared__ __align__(16) float sm[14080];
    float* hs    = sm;               // 64 x 132 = 8448 (stride 132 -> banks 4n+d)
    float* xs    = sm;               // 64 x 68  = 4352 (phase 1, dies before hs init)
    float* Wt    = sm + 4352;        // 128 x 20 = 2560 (transposed W chunk, phase 1)
    float* xwsh  = sm + 8448;        // 64 x 68  = 4352 (half of xw, stride 68)
    float* Wf1s  = sm + 8448;        // 2048 (aliases xwsh after scatter done)
    float* a1s   = sm + 10496;       // 1024
    int*   srcs  = (int*)(sm + 12800);  // 256
    int*   dsts  = (int*)(sm + 13056);  // 256
    float* ewx   = sm + 13312;       // 256
    float* degs  = sm + 13568;       // 64
    float* dinvs = sm + 13632;       // 64
    float* Ss    = sm + 13696;       // 64 x 2
    float* deg2s = sm + 13824;       // 64
    float* dinv2s= sm + 13888;       // 64
    float* LSs   = sm + 13952;       // 64 x 2  -> end 14080

    const int g = blockIdx.x;
    const int t = threadIdx.x;

    // ---- Phase 0: stage x (stride 68), edges, init degs (self-loop +1) ----
    {
        const float* xg = x + (size_t)g * (NNODE * FFEAT);
        for (int i = t; i < (NNODE * FFEAT) / 4; i += 256) {
            float4 v = ((const float4*)xg)[i];
            int n = i >> 4, k = (i & 15) * 4;
            *(float4*)&xs[n * 68 + k] = v;
        }
        const int* eg = ei + (size_t)g * (2 * EEDGE);
        srcs[t] = eg[t];
        dsts[t] = eg[EEDGE + t];
        ewx[t]  = ew[(size_t)g * EEDGE + t];
        if (t < NNODE) degs[t] = 1.0f;
    }

    // ---- GEMM: xw = x @ W_gcn1  (64x64 @ 64x128), micro-tile 4n x 8d ----
    const int dq = t & 15;            // d = dq + 16*j, j<8
    const int n0 = (t >> 4) * 4;      // n = n0 + i, i<4
    float acc[4][8];
#pragma unroll
    for (int i = 0; i < 4; ++i)
#pragma unroll
        for (int j = 0; j < 8; ++j) acc[i][j] = 0.f;

    for (int kc = 0; kc < 4; ++kc) {
        __syncthreads();  // kc=0: fences phase-0 writes; kc>0: fences prior Wt reads
        for (int i = t; i < 2048; i += 256) {
            int k = i >> 7, d = i & 127;
            Wt[d * 20 + k] = Wg[(kc * 16 + k) * 128 + d];  // transposed, stride 20
        }
        __syncthreads();
        if (kc == 0) atomicAdd(&degs[dsts[t]], ewx[t]);    // weighted in-degree
#pragma unroll
        for (int k4 = 0; k4 < 4; ++k4) {
            float4 xv[4];
#pragma unroll
            for (int i = 0; i < 4; ++i)
                xv[i] = *(const float4*)&xs[(n0 + i) * 68 + kc * 16 + k4 * 4];
#pragma unroll
            for (int j = 0; j < 8; ++j) {
                float4 wv = *(const float4*)&Wt[(dq + 16 * j) * 20 + k4 * 4];
#pragma unroll
                for (int i = 0; i < 4; ++i)
                    acc[i][j] += xv[i].x * wv.x + xv[i].y * wv.y + xv[i].z * wv.z + xv[i].w * wv.w;
            }
        }
    }
    if (t < NNODE) dinvs[t] = rsqrtf(degs[t]);

    // ---- h = agg + b : two d-halves (xw half -> LDS, init, scatter) ----
    for (int hh = 0; hh < 2; ++hh) {
        __syncthreads();  // hh=0: GEMM reads + dinvs done; hh=1: prior scatter done
#pragma unroll
        for (int j = 0; j < 4; ++j)
#pragma unroll
            for (int i = 0; i < 4; ++i)
                xwsh[(n0 + i) * 68 + dq + 16 * j] = acc[i][hh * 4 + j];
        __syncthreads();
        for (int i = t; i < 4096; i += 256) {  // self-loop + bias init
            int n = i >> 6, d6 = i & 63;
            hs[n * 132 + hh * 64 + d6] =
                xwsh[n * 68 + d6] * dinvs[n] * dinvs[n] + bg[hh * 64 + d6];
        }
        __syncthreads();
        for (int i = t; i < 16384; i += 256) {  // edge scatter (LDS atomics)
            int e = i >> 6, d6 = i & 63;
            int s = srcs[e], dd = dsts[e];
            float nrm = dinvs[s] * ewx[e] * dinvs[dd];
            atomicAdd(&hs[dd * 132 + hh * 64 + d6], xwsh[s * 68 + d6] * nrm);
        }
    }
    __syncthreads();

    // ---- a1 = tanh(h @ W_fc1 + b_fc1)  (64x128 @ 128x16) ----
    for (int i = t; i < 2048; i += 256) Wf1s[i] = Wf1[i];
    __syncthreads();
    {
        int n = t >> 2, j0 = (t & 3) * 4;
        float a0 = bf1[j0], a1v = bf1[j0 + 1], a2 = bf1[j0 + 2], a3 = bf1[j0 + 3];
#pragma unroll
        for (int k4 = 0; k4 < 32; ++k4) {
            float4 hv = *(const float4*)&hs[n * 132 + k4 * 4];
            float hvv[4] = {hv.x, hv.y, hv.z, hv.w};
#pragma unroll
            for (int kk = 0; kk < 4; ++kk) {
                float4 wv = *(const float4*)&Wf1s[(k4 * 4 + kk) * 16 + j0];
                a0 += hvv[kk] * wv.x; a1v += hvv[kk] * wv.y;
                a2 += hvv[kk] * wv.z; a3 += hvv[kk] * wv.w;
            }
        }
        a1s[n * 16 + j0]     = tanhf(a0);
        a1s[n * 16 + j0 + 1] = tanhf(a1v);
        a1s[n * 16 + j0 + 2] = tanhf(a2);
        a1s[n * 16 + j0 + 3] = tanhf(a3);
    }
    __syncthreads();

    // ---- S = softmax(a1 @ W_fc2 + b_fc2, axis=1) ----
    if (t < 128) {
        int n = t >> 1, kk = t & 1;
        float z = bf2[kk];
#pragma unroll
        for (int j = 0; j < 16; ++j) z += a1s[n * 16 + j] * Wf2[j * 2 + kk];
        Ss[n * 2 + kk] = z;
    }
    __syncthreads();
    if (t < 64) {
        float z0 = Ss[t * 2], z1 = Ss[t * 2 + 1];
        float m = fmaxf(z0, z1);
        float e0 = expf(z0 - m), e1 = expf(z1 - m);
        float inv = 1.0f / (e0 + e1);
        Ss[t * 2] = e0 * inv; Ss[t * 2 + 1] = e1 * inv;
    }
    if (t < 64) deg2s[t] = 0.0f;
    __syncthreads();

    // ---- Laplacian: deg from src, LS = L @ S without materializing L ----
    atomicAdd(&deg2s[srcs[t]], ewx[t]);
    __syncthreads();
    if (t < 64) {
        float dg = deg2s[t];
        dinv2s[t] = dg > 0.0f ? rsqrtf(fmaxf(dg, 1e-30f)) : 0.0f;
    }
    if (t < 128) LSs[t] = Ss[t];  // identity part
    __syncthreads();
    for (int i = t; i < 512; i += 256) {
        int e = i >> 1, kk = i & 1;
        int s = srcs[e], dd = dsts[e];
        float lw = -dinv2s[s] * ewx[e] * dinv2s[dd];
        atomicAdd(&LSs[s * 2 + kk], lw * Ss[dd * 2 + kk]);
    }
    __syncthreads();

    // ---- new_adj = S^T (L S) -> penalty ----
    if (t < 64) {
        float s0 = Ss[t * 2], s1 = Ss[t * 2 + 1];
        float l0 = LSs[t * 2], l1 = LSs[t * 2 + 1];
        float p00 = s0 * l0, p01 = s0 * l1, p10 = s1 * l0, p11 = s1 * l1;
        for (int o = 32; o; o >>= 1) {
            p00 += __shfl_down(p00, o); p01 += __shfl_down(p01, o);
            p10 += __shfl_down(p10, o); p11 += __shfl_down(p11, o);
        }
        if (t == 0) {
            float r0 = fmaxf(fabsf(p00) + fabsf(p01), 1e-12f);
            float r1 = fmaxf(fabsf(p10) + fabsf(p11), 1e-12f);
            float d0 = p00 / r0 - 1.0f, d1 = p11 / r1 - 1.0f;
            pens[g] = 0.5f * (d0 * d0 + d1 * d1);
        }
    }

    // ---- g_emb = mean(S^T h, axis=0) = 0.5 * sum_n (S[n,0]+S[n,1]) h[n,:] ----
    if (t < 128) {
        float s = 0.f;
        for (int n = 0; n < 64; ++n)
            s += (Ss[n * 2] + Ss[n * 2 + 1]) * hs[n * 132 + t];
        g_embs[(size_t)g * 128 + t] = 0.5f * s;
    }
}

// ---------------------------------------------------------------------------
// Graph-level degree (indegree count + 1 self loop) and dinv
// ---------------------------------------------------------------------------
__global__ void k_deg(const int* __restrict__ pd, float* __restrict__ deg) {
    int e = blockIdx.x * 256 + threadIdx.x;
    atomicAdd(&deg[pd[e]], 1.0f);
}

__global__ void k_dinv(const float* __restrict__ deg, float* __restrict__ dinv) {
    int i = blockIdx.x * 256 + threadIdx.x;
    dinv[i] = rsqrtf(deg[i] + 1.0f);
}

// ---------------------------------------------------------------------------
// Generic tiled fp32 GEMM: C = A[MxK] @ B[KxN] (+bias). Optional second
// output (shared A): blockIdx.y >= gridDim.y/2 uses (B1,bias1,C1).
// Tile 64x64, 256 threads, 4x4 micro-tile, BK=32.
// ---------------------------------------------------------------------------
__global__ __launch_bounds__(256) void k_gemm(
    const float* __restrict__ A,
    const float* __restrict__ B0, const float* __restrict__ bias0, float* __restrict__ C0,
    const float* __restrict__ B1, const float* __restrict__ bias1, float* __restrict__ C1,
    int M, int K, int N)
{
    __shared__ __align__(16) float At[32 * 68];  // [k][m] stride 68
    __shared__ __align__(16) float Bs[32 * 68];  // [k][n] stride 68
    const float* B = B0; const float* bias = bias0; float* C = C0;
    int by = blockIdx.y;
    if (B1 != nullptr && by >= (int)(gridDim.y >> 1)) {
        B = B1; bias = bias1; C = C1; by -= (gridDim.y >> 1);
    }
    const int mb = blockIdx.x * 64, nb = by * 64;
    const int t = threadIdx.x;
    const int tm = t >> 4, tn = t & 15;
    float acc[4][4] = {};
    for (int k0 = 0; k0 < K; k0 += 32) {
        __syncthreads();
        for (int i = t; i < 2048; i += 256) {
            int m = i >> 5, k = i & 31;
            At[k * 68 + m] = A[(size_t)(mb + m) * K + k0 + k];
        }
        for (int i = t; i < 2048; i += 256) {
            int k = i >> 6, n = i & 63;
            Bs[k * 68 + n] = B[(size_t)(k0 + k) * N + nb + n];
        }
        __syncthreads();
#pragma unroll
        for (int k = 0; k < 32; ++k) {
            float4 av = *(const float4*)&At[k * 68 + tm * 4];
            float4 bv = *(const float4*)&Bs[k * 68 + tn * 4];
            float a_[4] = {av.x, av.y, av.z, av.w};
            float b_[4] = {bv.x, bv.y, bv.z, bv.w};
#pragma unroll
            for (int i = 0; i < 4; ++i)
#pragma unroll
                for (int j = 0; j < 4; ++j) acc[i][j] += a_[i] * b_[j];
        }
    }
#pragma unroll
    for (int i = 0; i < 4; ++i) {
        int m = mb + tm * 4 + i;
        float4 v;
        v.x = acc[i][0] + (bias ? bias[nb + tn * 4 + 0] : 0.f);
        v.y = acc[i][1] + (bias ? bias[nb + tn * 4 + 1] : 0.f);
        v.z = acc[i][2] + (bias ? bias[nb + tn * 4 + 2] : 0.f);
        v.w = acc[i][3] + (bias ? bias[nb + tn * 4 + 3] : 0.f);
        *(float4*)&C[(size_t)m * N + nb + tn * 4] = v;
    }
}

// ---------------------------------------------------------------------------
// Edge scatter for the 256-wide conv: agg[pd] += xw1[ps]*dinv[ps]*dinv[pd]
// ---------------------------------------------------------------------------
__global__ void k_scatter_h(const int* __restrict__ pe, const float* __restrict__ dinv,
                            const float* __restrict__ xw, float* __restrict__ agg) {
    int t = threadIdx.x;
#pragma unroll
    for (int q = 0; q < 4; ++q) {
        int e = blockIdx.x * 4 + q;
        int s = pe[e], d = pe[EP + e];
        float nrm = dinv[s] * dinv[d];
        atomicAdd(&agg[(size_t)d * 256 + t], xw[(size_t)s * 256 + t] * nrm);
    }
}

__global__ void k_fin_h(const float* __restrict__ xw1, const float* __restrict__ dinv,
                        const float* __restrict__ bc1, float* __restrict__ h) {
    int idx = blockIdx.x * 256 + threadIdx.x;
    int g = idx >> 8, c = idx & 255;
    float dv = dinv[g];
    float v = h[idx] + xw1[idx] * dv * dv + bc1[c];
    h[idx] = fmaxf(v, 0.0f);
}

// Fused mu/logstd edge scatter (128 dims each, 256 threads)
__global__ void k_scatter_muls(const int* __restrict__ pe, const float* __restrict__ dinv,
                               const float* __restrict__ xwmu, const float* __restrict__ xwls,
                               float* __restrict__ aggmu, float* __restrict__ aggls) {
    int t = threadIdx.x;
    const float* xw = (t < 128) ? xwmu : xwls;
    float* ag = (t < 128) ? aggmu : aggls;
    int d = t & 127;
#pragma unroll
    for (int q = 0; q < 4; ++q) {
        int e = blockIdx.x * 4 + q;
        int s = pe[e], dd = pe[EP + e];
        float nrm = dinv[s] * dinv[dd];
        atomicAdd(&ag[(size_t)dd * 128 + d], xw[(size_t)s * 128 + d] * nrm);
    }
}

// mu, logstd, z, zc = [emb, z], and per-graph KL partial
__global__ void k_fin_z(const float* __restrict__ aggmu, const float* __restrict__ aggls,
                        const float* __restrict__ xwmu, const float* __restrict__ xwls,
                        const float* __restrict__ dinv,
                        const float* __restrict__ bmu, const float* __restrict__ bls,
                        const float* __restrict__ eps, const float* __restrict__ emb,
                        float* __restrict__ zc, float* __restrict__ klp) {
    __shared__ float smw[2];
    int g = blockIdx.x, d = threadIdx.x;  // 128 threads
    int idx = g * 128 + d;
    float dv = dinv[g], d2 = dv * dv;
    float mu = aggmu[idx] + xwmu[idx] * d2 + bmu[d];
    float ls = aggls[idx] + xwls[idx] * d2 + bls[d];
    ls = fminf(ls, 10.0f);
    float z = mu + eps[idx] * expf(ls);
    zc[(size_t)g * 256 + d] = emb[idx];
    zc[(size_t)g * 256 + 128 + d] = z;
    float term = 1.0f + 2.0f * ls - mu * mu - expf(2.0f * ls);
    for (int o = 32; o; o >>= 1) term += __shfl_down(term, o);
    if ((d & 63) == 0) smw[d >> 6] = term;
    __syncthreads();
    if (d == 0) klp[g] = smw[0] + smw[1];
}

// Edge predictions: sigmoid(dot(Arow[src], Brow[dst])) + per-block log partial
__global__ void k_pred(const float* __restrict__ A, const float* __restrict__ B,
                       const int* __restrict__ pos, const int* __restrict__ neg,
                       float* __restrict__ out, float* __restrict__ predp) {
    __shared__ float smw[4];
    int t = threadIdx.x, w = t >> 6, l = t & 63;
    int eg = blockIdx.x * 4 + w;
    int isneg = eg >= EP;
    int e = eg - (isneg ? EP : 0);
    const int* eix = isneg ? neg : pos;
    int s = eix[e], d = eix[EP + e];
    const float4* Ar = (const float4*)(A + (size_t)s * 256);
    const float4* Br = (const float4*)(B + (size_t)d * 256);
    float4 av = Ar[l], bv = Br[l];
    float dot = av.x * bv.x + av.y * bv.y + av.z * bv.z + av.w * bv.w;
    for (int o = 32; o; o >>= 1) dot += __shfl_down(dot, o);
    if (l == 0) {
        float p = 1.0f / (1.0f + expf(-dot));
        float term;
        if (isneg) { out[2 + EP + e] = p; term = logf(1.0f - p + 1e-15f); }
        else       { out[2 + e] = p;      term = logf(p + 1e-15f); }
        smw[w] = term;
    }
    __syncthreads();
    if (t == 0) predp[blockIdx.x] = smw[0] + smw[1] + smw[2] + smw[3];
}

// Final scalar reductions
__global__ void k_final(const float* __restrict__ pens, const float* __restrict__ klp,
                        const float* __restrict__ predp, float* __restrict__ out) {
    __shared__ float sm[16];
    int t = threadIdx.x;
    float s_pen = 0.f, s_kl = 0.f, s_pos = 0.f, s_neg = 0.f;
    for (int i = t; i < 4096; i += 256) { s_pen += pens[i]; s_kl += klp[i]; }
    for (int i = t; i < 8192; i += 256) { s_pos += predp[i]; s_neg += predp[8192 + i]; }
    for (int o = 32; o; o >>= 1) {
        s_pen += __shfl_down(s_pen, o); s_kl += __shfl_down(s_kl, o);
        s_pos += __shfl_down(s_pos, o); s_neg += __shfl_down(s_neg, o);
    }
    int w = t >> 6;
    if ((t & 63) == 0) { sm[w] = s_pen; sm[4 + w] = s_kl; sm[8 + w] = s_pos; sm[12 + w] = s_neg; }
    __syncthreads();
    if (t == 0) {
        float pen = sm[0] + sm[1] + sm[2] + sm[3];
        float kls = sm[4] + sm[5] + sm[6] + sm[7];
        float pos = sm[8] + sm[9] + sm[10] + sm[11];
        float neg = sm[12] + sm[13] + sm[14] + sm[15];
        float rec = -(pos / 32768.0f) - (neg / 32768.0f);
        out[0] = rec - 0.5f * kls / (4096.0f * 4096.0f);  // rec + (kl)/G, kl = -0.5*kls/G
        out[1] = pen * (1.0f / 4096.0f);
    }
}

extern "C" void kernel_launch(void* const* d_in, const int* in_sizes, int n_in,
                              void* d_out, int out_size, void* d_ws, size_t ws_size,
                              hipStream_t stream) {
    const float* x   = (const float*)d_in[0];
    const int*   ei  = (const int*)d_in[1];
    const float* ew  = (const float*)d_in[2];
    const int*   pos = (const int*)d_in[3];
    const int*   neg = (const int*)d_in[4];
    const float* eps = (const float*)d_in[5];
    const float* Wg  = (const float*)d_in[6];
    const float* bg  = (const float*)d_in[7];
    const float* Wf1 = (const float*)d_in[8];
    const float* bf1 = (const float*)d_in[9];
    const float* Wf2 = (const float*)d_in[10];
    const float* bf2 = (const float*)d_in[11];
    const float* Wc1 = (const float*)d_in[12];
    const float* bc1 = (const float*)d_in[13];
    const float* Wmu = (const float*)d_in[14];
    const float* bmu = (const float*)d_in[15];
    const float* Wls = (const float*)d_in[16];
    const float* bls = (const float*)d_in[17];
    const float* emb = (const float*)d_in[18];
    const float* Wl1 = (const float*)d_in[19];
    const float* bl1 = (const float*)d_in[20];
    const float* Wl2 = (const float*)d_in[21];
    const float* bl2 = (const float*)d_in[22];
    float* out = (float*)d_out;
    float* ws  = (float*)d_ws;

    // Workspace layout (floats): ~30.1 MB total
    float* g_embs = ws + 0;         // 524288
    float* deg    = ws + 524288;    // 4096
    float* dinv   = ws + 528384;    // 4096
    float* xw1    = ws + 532480;    // 1048576
    float* h      = ws + 1581056;   // 1048576 (agg accumulator, then relu'd)
    float* xwmu   = ws + 2629632;   // 524288
    float* xwls   = ws + 3153920;   // 524288
    float* aggmu  = ws + 3678208;   // 524288
    float* aggls  = ws + 4202496;   // 524288
    float* zc     = ws + 4726784;   // 1048576
    float* Abuf   = ws + 5775360;   // 1048576
    float* Bbuf   = ws + 6823936;   // 1048576
    float* pens   = ws + 7872512;   // 4096
    float* klp    = ws + 7876608;   // 4096
    float* predp  = ws + 7880704;   // 16384

    // Zero the scatter accumulators (ws is poisoned 0xAA before every call)
    hipMemsetAsync(deg,   0, 4096u * 4, stream);
    hipMemsetAsync(h,     0, 1048576u * 4, stream);
    hipMemsetAsync(aggmu, 0, 524288u * 4, stream);
    hipMemsetAsync(aggls, 0, 524288u * 4, stream);

    // Stage A: per-graph SAGE pooling
    k_per_graph<<<GG, 256, 0, stream>>>(x, ei, ew, Wg, bg, Wf1, bf1, Wf2, bf2, g_embs, pens);

    // Stage B: graph-level VGAE
    k_deg<<<EP / 256, 256, 0, stream>>>(pos + EP, deg);
    k_dinv<<<GG / 256, 256, 0, stream>>>(deg, dinv);

    // h = relu(gcn(g_embs, W_c1, b_c1))
    k_gemm<<<dim3(64, 4), 256, 0, stream>>>(g_embs, Wc1, nullptr, xw1,
                                            nullptr, nullptr, nullptr, GG, 128, 256);
    k_scatter_h<<<EP / 4, 256, 0, stream>>>(pos, dinv, xw1, h);
    k_fin_h<<<GG, 256, 0, stream>>>(xw1, dinv, bc1, h);

    // mu = gcn(h, W_mu), logstd = min(gcn(h, W_ls), 10); z; zc = [emb, z]; kl
    k_gemm<<<dim3(64, 4), 256, 0, stream>>>(h, Wmu, nullptr, xwmu,
                                            Wls, nullptr, xwls, GG, 256, 128);
    k_scatter_muls<<<EP / 4, 256, 0, stream>>>(pos, dinv, xwmu, xwls, aggmu, aggls);
    k_fin_z<<<GG, 128, 0, stream>>>(aggmu, aggls, xwmu, xwls, dinv, bmu, bls, eps, emb, zc, klp);

    // A = zc@W_lin1+b, B = zc@W_lin2+b (per-node factorization of the edge MLP)
    k_gemm<<<dim3(64, 8), 256, 0, stream>>>(zc, Wl1, bl1, Abuf,
                                            Wl2, bl2, Bbuf, GG, 256, 256);

    // Edge predictions + partial log sums; final scalars
    k_pred<<<(2 * EP) / 4, 256, 0, stream>>>(Abuf, Bbuf, pos, neg, out, predp);
    k_final<<<1, 256, 0, stream>>>(pens, klp, predp, out);
}

// Round 2
// 2293.090 us; speedup vs baseline: 1.0049x; 1.0049x over previous
//
#include <hip/hip_runtime.h>
#include <hip/hip_bf16.h>
#include <math.h>

// Sizes (fixed by the reference)
#define GG   4096
#define NNODE 64
#define EEDGE 256
#define FFEAT 64
#define DDIM 128
#define EP   32768

// ---------------------------------------------------------------------------
// Kernel 1: one block per graph. Computes h (GCNConv), S (MLP+softmax),
// Laplacian penalty, and g_emb. LDS-resident throughout.
// LDS plan (floats, total 18176 = 72.7 KB -> 2 blocks/CU):
//   [0,8448)      hs   64x132   (phase1 alias: xs 64x68 @0, Wt 128x20 @4352)
//   [8448,16896)  xw   64x132   (post-scatter alias: Wf1s 2048 @8448, a1s @10496)
//   [16896,18176) edges + small vectors
// All accumulator indices are compile-time constants -> no scratch spill
// (round-1 post-mortem: dynamic acc[i][hh*4+j] spilled acc -> 4.25 GB HBM).
// ---------------------------------------------------------------------------
__global__ __launch_bounds__(256, 2) void k_per_graph(
    const float* __restrict__ x, const int* __restrict__ ei, const float* __restrict__ ew,
    const float* __restrict__ Wg, const float* __restrict__ bg,
    const float* __restrict__ Wf1, const float* __restrict__ bf1,
    const float* __restrict__ Wf2, const float* __restrict__ bf2,
    float* __restrict__ g_embs, float* __restrict__ pens)
{
    __shared__ __align__(16) float sm[18176];
    float* hs    = sm;                  // 64 x 132
    float* xs    = sm;                  // 64 x 68 (phase 1, dies after GEMM)
    float* Wt    = sm + 4352;           // 128 x 20 (phase 1)
    float* xw    = sm + 8448;           // 64 x 132
    float* Wf1s  = sm + 8448;           // 2048 (aliases xw after scatter done)
    float* a1s   = sm + 10496;          // 1024
    int*   srcs  = (int*)(sm + 16896);  // 256
    int*   dsts  = (int*)(sm + 17152);  // 256
    float* ewx   = sm + 17408;          // 256
    float* degs  = sm + 17664;          // 64
    float* dinvs = sm + 17728;          // 64
    float* Ss    = sm + 17792;          // 64 x 2
    float* deg2s = sm + 17920;          // 64
    float* dinv2s= sm + 17984;          // 64
    float* LSs   = sm + 18048;          // 64 x 2 -> end 18176

    const int g = blockIdx.x;
    const int t = threadIdx.x;

    // ---- Phase 0: stage x (stride 68), edges, init degs (self-loop +1) ----
    {
        const float* xg = x + (size_t)g * (NNODE * FFEAT);
        for (int i = t; i < (NNODE * FFEAT) / 4; i += 256) {
            float4 v = ((const float4*)xg)[i];
            int n = i >> 4, k = (i & 15) * 4;
            *(float4*)&xs[n * 68 + k] = v;
        }
        const int* eg = ei + (size_t)g * (2 * EEDGE);
        srcs[t] = eg[t];
        dsts[t] = eg[EEDGE + t];
        ewx[t]  = ew[(size_t)g * EEDGE + t];
        if (t < NNODE) degs[t] = 1.0f;
    }

    // ---- GEMM: xw = x @ W_gcn1  (64x64 @ 64x128), micro-tile 4n x 8d ----
    const int dq = t & 15;            // d = dq + 16*j, j<8
    const int n0 = (t >> 4) * 4;      // n = n0 + i, i<4
    float acc[4][8];
#pragma unroll
    for (int i = 0; i < 4; ++i)
#pragma unroll
        for (int j = 0; j < 8; ++j) acc[i][j] = 0.f;

    for (int kc = 0; kc < 4; ++kc) {
        __syncthreads();  // kc=0: fences phase-0 writes; kc>0: fences prior Wt reads
        for (int i = t; i < 2048; i += 256) {
            int k = i >> 7, d = i & 127;
            Wt[d * 20 + k] = Wg[(kc * 16 + k) * 128 + d];  // transposed, stride 20
        }
        __syncthreads();
        if (kc == 0) atomicAdd(&degs[dsts[t]], ewx[t]);    // weighted in-degree
#pragma unroll
        for (int k4 = 0; k4 < 4; ++k4) {
            float4 xv[4];
#pragma unroll
            for (int i = 0; i < 4; ++i)
                xv[i] = *(const float4*)&xs[(n0 + i) * 68 + kc * 16 + k4 * 4];
#pragma unroll
            for (int j = 0; j < 8; ++j) {
                float4 wv = *(const float4*)&Wt[(dq + 16 * j) * 20 + k4 * 4];
#pragma unroll
                for (int i = 0; i < 4; ++i)
                    acc[i][j] += xv[i].x * wv.x + xv[i].y * wv.y + xv[i].z * wv.z + xv[i].w * wv.w;
            }
        }
    }
    if (t < NNODE) dinvs[t] = rsqrtf(degs[t]);

    // ---- Store acc -> xw (static indices only; acc stays in VGPRs) ----
#pragma unroll
    for (int i = 0; i < 4; ++i)
#pragma unroll
        for (int j = 0; j < 8; ++j)
            xw[(n0 + i) * 132 + dq + 16 * j] = acc[i][j];
    __syncthreads();  // xw + dinvs ready; xs dead (safe to overwrite with hs)

    // ---- h init: self-loop + bias ----
    for (int i = t; i < 8192; i += 256) {
        int n = i >> 7, d = i & 127;
        hs[n * 132 + d] = xw[n * 132 + d] * dinvs[n] * dinvs[n] + bg[d];
    }
    __syncthreads();

    // ---- Edge scatter: hs[dst] += xw[src] * norm (LDS atomics) ----
    for (int i = t; i < 32768; i += 256) {
        int e = i >> 7, d = i & 127;
        int s = srcs[e], dd = dsts[e];
        float nrm = dinvs[s] * ewx[e] * dinvs[dd];
        atomicAdd(&hs[dd * 132 + d], xw[s * 132 + d] * nrm);
    }
    __syncthreads();

    // ---- a1 = tanh(h @ W_fc1 + b_fc1)  (64x128 @ 128x16) ----
    for (int i = t; i < 2048; i += 256) Wf1s[i] = Wf1[i];
    __syncthreads();
    {
        int n = t >> 2, j0 = (t & 3) * 4;
        float a0 = bf1[j0], a1v = bf1[j0 + 1], a2 = bf1[j0 + 2], a3 = bf1[j0 + 3];
#pragma unroll
        for (int k4 = 0; k4 < 32; ++k4) {
            float4 hv = *(const float4*)&hs[n * 132 + k4 * 4];
            float hvv[4] = {hv.x, hv.y, hv.z, hv.w};
#pragma unroll
            for (int kk = 0; kk < 4; ++kk) {
                float4 wv = *(const float4*)&Wf1s[(k4 * 4 + kk) * 16 + j0];
                a0 += hvv[kk] * wv.x; a1v += hvv[kk] * wv.y;
                a2 += hvv[kk] * wv.z; a3 += hvv[kk] * wv.w;
            }
        }
        a1s[n * 16 + j0]     = tanhf(a0);
        a1s[n * 16 + j0 + 1] = tanhf(a1v);
        a1s[n * 16 + j0 + 2] = tanhf(a2);
        a1s[n * 16 + j0 + 3] = tanhf(a3);
    }
    __syncthreads();

    // ---- S = softmax(a1 @ W_fc2 + b_fc2, axis=1) ----
    if (t < 128) {
        int n = t >> 1, kk = t & 1;
        float z = bf2[kk];
#pragma unroll
        for (int j = 0; j < 16; ++j) z += a1s[n * 16 + j] * Wf2[j * 2 + kk];
        Ss[n * 2 + kk] = z;
    }
    __syncthreads();
    if (t < 64) {
        float z0 = Ss[t * 2], z1 = Ss[t * 2 + 1];
        float m = fmaxf(z0, z1);
        float e0 = expf(z0 - m), e1 = expf(z1 - m);
        float inv = 1.0f / (e0 + e1);
        Ss[t * 2] = e0 * inv; Ss[t * 2 + 1] = e1 * inv;
    }
    if (t < 64) deg2s[t] = 0.0f;
    __syncthreads();

    // ---- Laplacian: deg from src, LS = L @ S without materializing L ----
    atomicAdd(&deg2s[srcs[t]], ewx[t]);
    __syncthreads();
    if (t < 64) {
        float dg = deg2s[t];
        dinv2s[t] = dg > 0.0f ? rsqrtf(fmaxf(dg, 1e-30f)) : 0.0f;
    }
    if (t < 128) LSs[t] = Ss[t];  // identity part
    __syncthreads();
    for (int i = t; i < 512; i += 256) {
        int e = i >> 1, kk = i & 1;
        int s = srcs[e], dd = dsts[e];
        float lw = -dinv2s[s] * ewx[e] * dinv2s[dd];
        atomicAdd(&LSs[s * 2 + kk], lw * Ss[dd * 2 + kk]);
    }
    __syncthreads();

    // ---- new_adj = S^T (L S) -> penalty ----
    if (t < 64) {
        float s0 = Ss[t * 2], s1 = Ss[t * 2 + 1];
        float l0 = LSs[t * 2], l1 = LSs[t * 2 + 1];
        float p00 = s0 * l0, p01 = s0 * l1, p10 = s1 * l0, p11 = s1 * l1;
        for (int o = 32; o; o >>= 1) {
            p00 += __shfl_down(p00, o); p01 += __shfl_down(p01, o);
            p10 += __shfl_down(p10, o); p11 += __shfl_down(p11, o);
        }
        if (t == 0) {
            float r0 = fmaxf(fabsf(p00) + fabsf(p01), 1e-12f);
            float r1 = fmaxf(fabsf(p10) + fabsf(p11), 1e-12f);
            float d0 = p00 / r0 - 1.0f, d1 = p11 / r1 - 1.0f;
            pens[g] = 0.5f * (d0 * d0 + d1 * d1);
        }
    }

    // ---- g_emb = mean(S^T h, axis=0) = 0.5 * sum_n (S[n,0]+S[n,1]) h[n,:] ----
    if (t < 128) {
        float s = 0.f;
        for (int n = 0; n < 64; ++n)
            s += (Ss[n * 2] + Ss[n * 2 + 1]) * hs[n * 132 + t];
        g_embs[(size_t)g * 128 + t] = 0.5f * s;
    }
}

// ---------------------------------------------------------------------------
// Graph-level degree (indegree count + 1 self loop) and dinv
// ---------------------------------------------------------------------------
__global__ void k_deg(const int* __restrict__ pd, float* __restrict__ deg) {
    int e = blockIdx.x * 256 + threadIdx.x;
    atomicAdd(&deg[pd[e]], 1.0f);
}

__global__ void k_dinv(const float* __restrict__ deg, float* __restrict__ dinv) {
    int i = blockIdx.x * 256 + threadIdx.x;
    dinv[i] = rsqrtf(deg[i] + 1.0f);
}

// ---------------------------------------------------------------------------
// Generic tiled fp32 GEMM: C = A[MxK] @ B[KxN] (+bias). Optional second
// output (shared A): blockIdx.y >= gridDim.y/2 uses (B1,bias1,C1).
// Tile 64x64, 256 threads, 4x4 micro-tile, BK=32.
// ---------------------------------------------------------------------------
__global__ __launch_bounds__(256) void k_gemm(
    const float* __restrict__ A,
    const float* __restrict__ B0, const float* __restrict__ bias0, float* __restrict__ C0,
    const float* __restrict__ B1, const float* __restrict__ bias1, float* __restrict__ C1,
    int M, int K, int N)
{
    __shared__ __align__(16) float At[32 * 68];  // [k][m] stride 68
    __shared__ __align__(16) float Bs[32 * 68];  // [k][n] stride 68
    const float* B = B0; const float* bias = bias0; float* C = C0;
    int by = blockIdx.y;
    if (B1 != nullptr && by >= (int)(gridDim.y >> 1)) {
        B = B1; bias = bias1; C = C1; by -= (gridDim.y >> 1);
    }
    const int mb = blockIdx.x * 64, nb = by * 64;
    const int t = threadIdx.x;
    const int tm = t >> 4, tn = t & 15;
    float acc[4][4] = {};
    for (int k0 = 0; k0 < K; k0 += 32) {
        __syncthreads();
        for (int i = t; i < 2048; i += 256) {
            int m = i >> 5, k = i & 31;
            At[k * 68 + m] = A[(size_t)(mb + m) * K + k0 + k];
        }
        for (int i = t; i < 2048; i += 256) {
            int k = i >> 6, n = i & 63;
            Bs[k * 68 + n] = B[(size_t)(k0 + k) * N + nb + n];
        }
        __syncthreads();
#pragma unroll
        for (int k = 0; k < 32; ++k) {
            float4 av = *(const float4*)&At[k * 68 + tm * 4];
            float4 bv = *(const float4*)&Bs[k * 68 + tn * 4];
            float a_[4] = {av.x, av.y, av.z, av.w};
            float b_[4] = {bv.x, bv.y, bv.z, bv.w};
#pragma unroll
            for (int i = 0; i < 4; ++i)
#pragma unroll
                for (int j = 0; j < 4; ++j) acc[i][j] += a_[i] * b_[j];
        }
    }
#pragma unroll
    for (int i = 0; i < 4; ++i) {
        int m = mb + tm * 4 + i;
        float4 v;
        v.x = acc[i][0] + (bias ? bias[nb + tn * 4 + 0] : 0.f);
        v.y = acc[i][1] + (bias ? bias[nb + tn * 4 + 1] : 0.f);
        v.z = acc[i][2] + (bias ? bias[nb + tn * 4 + 2] : 0.f);
        v.w = acc[i][3] + (bias ? bias[nb + tn * 4 + 3] : 0.f);
        *(float4*)&C[(size_t)m * N + nb + tn * 4] = v;
    }
}

// ---------------------------------------------------------------------------
// Edge scatter for the 256-wide conv: agg[pd] += xw1[ps]*dinv[ps]*dinv[pd]
// ---------------------------------------------------------------------------
__global__ void k_scatter_h(const int* __restrict__ pe, const float* __restrict__ dinv,
                            const float* __restrict__ xw, float* __restrict__ agg) {
    int t = threadIdx.x;
#pragma unroll
    for (int q = 0; q < 4; ++q) {
        int e = blockIdx.x * 4 + q;
        int s = pe[e], d = pe[EP + e];
        float nrm = dinv[s] * dinv[d];
        atomicAdd(&agg[(size_t)d * 256 + t], xw[(size_t)s * 256 + t] * nrm);
    }
}

__global__ void k_fin_h(const float* __restrict__ xw1, const float* __restrict__ dinv,
                        const float* __restrict__ bc1, float* __restrict__ h) {
    int idx = blockIdx.x * 256 + threadIdx.x;
    int g = idx >> 8, c = idx & 255;
    float dv = dinv[g];
    float v = h[idx] + xw1[idx] * dv * dv + bc1[c];
    h[idx] = fmaxf(v, 0.0f);
}

// Fused mu/logstd edge scatter (128 dims each, 256 threads)
__global__ void k_scatter_muls(const int* __restrict__ pe, const float* __restrict__ dinv,
                               const float* __restrict__ xwmu, const float* __restrict__ xwls,
                               float* __restrict__ aggmu, float* __restrict__ aggls) {
    int t = threadIdx.x;
    const float* xw = (t < 128) ? xwmu : xwls;
    float* ag = (t < 128) ? aggmu : aggls;
    int d = t & 127;
#pragma unroll
    for (int q = 0; q < 4; ++q) {
        int e = blockIdx.x * 4 + q;
        int s = pe[e], dd = pe[EP + e];
        float nrm = dinv[s] * dinv[dd];
        atomicAdd(&ag[(size_t)dd * 128 + d], xw[(size_t)s * 128 + d] * nrm);
    }
}

// mu, logstd, z, zc = [emb, z], and per-graph KL partial
__global__ void k_fin_z(const float* __restrict__ aggmu, const float* __restrict__ aggls,
                        const float* __restrict__ xwmu, const float* __restrict__ xwls,
                        const float* __restrict__ dinv,
                        const float* __restrict__ bmu, const float* __restrict__ bls,
                        const float* __restrict__ eps, const float* __restrict__ emb,
                        float* __restrict__ zc, float* __restrict__ klp) {
    __shared__ float smw[2];
    int g = blockIdx.x, d = threadIdx.x;  // 128 threads
    int idx = g * 128 + d;
    float dv = dinv[g], d2 = dv * dv;
    float mu = aggmu[idx] + xwmu[idx] * d2 + bmu[d];
    float ls = aggls[idx] + xwls[idx] * d2 + bls[d];
    ls = fminf(ls, 10.0f);
    float z = mu + eps[idx] * expf(ls);
    zc[(size_t)g * 256 + d] = emb[idx];
    zc[(size_t)g * 256 + 128 + d] = z;
    float term = 1.0f + 2.0f * ls - mu * mu - expf(2.0f * ls);
    for (int o = 32; o; o >>= 1) term += __shfl_down(term, o);
    if ((d & 63) == 0) smw[d >> 6] = term;
    __syncthreads();
    if (d == 0) klp[g] = smw[0] + smw[1];
}

// Edge predictions: sigmoid(dot(Arow[src], Brow[dst])) + per-block log partial
__global__ void k_pred(const float* __restrict__ A, const float* __restrict__ B,
                       const int* __restrict__ pos, const int* __restrict__ neg,
                       float* __restrict__ out, float* __restrict__ predp) {
    __shared__ float smw[4];
    int t = threadIdx.x, w = t >> 6, l = t & 63;
    int eg = blockIdx.x * 4 + w;
    int isneg = eg >= EP;
    int e = eg - (isneg ? EP : 0);
    const int* eix = isneg ? neg : pos;
    int s = eix[e], d = eix[EP + e];
    const float4* Ar = (const float4*)(A + (size_t)s * 256);
    const float4* Br = (const float4*)(B + (size_t)d * 256);
    float4 av = Ar[l], bv = Br[l];
    float dot = av.x * bv.x + av.y * bv.y + av.z * bv.z + av.w * bv.w;
    for (int o = 32; o; o >>= 1) dot += __shfl_down(dot, o);
    if (l == 0) {
        float p = 1.0f / (1.0f + expf(-dot));
        float term;
        if (isneg) { out[2 + EP + e] = p; term = logf(1.0f - p + 1e-15f); }
        else       { out[2 + e] = p;      term = logf(p + 1e-15f); }
        smw[w] = term;
    }
    __syncthreads();
    if (t == 0) predp[blockIdx.x] = smw[0] + smw[1] + smw[2] + smw[3];
}

// Final scalar reductions
__global__ void k_final(const float* __restrict__ pens, const float* __restrict__ klp,
                        const float* __restrict__ predp, float* __restrict__ out) {
    __shared__ float sm[16];
    int t = threadIdx.x;
    float s_pen = 0.f, s_kl = 0.f, s_pos = 0.f, s_neg = 0.f;
    for (int i = t; i < 4096; i += 256) { s_pen += pens[i]; s_kl += klp[i]; }
    for (int i = t; i < 8192; i += 256) { s_pos += predp[i]; s_neg += predp[8192 + i]; }
    for (int o = 32; o; o >>= 1) {
        s_pen += __shfl_down(s_pen, o); s_kl += __shfl_down(s_kl, o);
        s_pos += __shfl_down(s_pos, o); s_neg += __shfl_down(s_neg, o);
    }
    int w = t >> 6;
    if ((t & 63) == 0) { sm[w] = s_pen; sm[4 + w] = s_kl; sm[8 + w] = s_pos; sm[12 + w] = s_neg; }
    __syncthreads();
    if (t == 0) {
        float pen = sm[0] + sm[1] + sm[2] + sm[3];
        float kls = sm[4] + sm[5] + sm[6] + sm[7];
        float pos = sm[8] + sm[9] + sm[10] + sm[11];
        float neg = sm[12] + sm[13] + sm[14] + sm[15];
        float rec = -(pos / 32768.0f) - (neg / 32768.0f);
        out[0] = rec - 0.5f * kls / (4096.0f * 4096.0f);  // rec + (kl)/G, kl = -0.5*kls/G
        out[1] = pen * (1.0f / 4096.0f);
    }
}

extern "C" void kernel_launch(void* const* d_in, const int* in_sizes, int n_in,
                              void* d_out, int out_size, void* d_ws, size_t ws_size,
                              hipStream_t stream) {
    const float* x   = (const float*)d_in[0];
    const int*   ei  = (const int*)d_in[1];
    const float* ew  = (const float*)d_in[2];
    const int*   pos = (const int*)d_in[3];
    const int*   neg = (const int*)d_in[4];
    const float* eps = (const float*)d_in[5];
    const float* Wg  = (const float*)d_in[6];
    const float* bg  = (const float*)d_in[7];
    const float* Wf1 = (const float*)d_in[8];
    const float* bf1 = (const float*)d_in[9];
    const float* Wf2 = (const float*)d_in[10];
    const float* bf2 = (const float*)d_in[11];
    const float* Wc1 = (const float*)d_in[12];
    const float* bc1 = (const float*)d_in[13];
    const float* Wmu = (const float*)d_in[14];
    const float* bmu = (const float*)d_in[15];
    const float* Wls = (const float*)d_in[16];
    const float* bls = (const float*)d_in[17];
    const float* emb = (const float*)d_in[18];
    const float* Wl1 = (const float*)d_in[19];
    const float* bl1 = (const float*)d_in[20];
    const float* Wl2 = (const float*)d_in[21];
    const float* bl2 = (const float*)d_in[22];
    float* out = (float*)d_out;
    float* ws  = (float*)d_ws;

    // Workspace layout (floats): ~30.1 MB total
    float* g_embs = ws + 0;         // 524288
    float* deg    = ws + 524288;    // 4096
    float* dinv   = ws + 528384;    // 4096
    float* xw1    = ws + 532480;    // 1048576
    float* h      = ws + 1581056;   // 1048576 (agg accumulator, then relu'd)
    float* xwmu   = ws + 2629632;   // 524288
    float* xwls   = ws + 3153920;   // 524288
    float* aggmu  = ws + 3678208;   // 524288
    float* aggls  = ws + 4202496;   // 524288
    float* zc     = ws + 4726784;   // 1048576
    float* Abuf   = ws + 5775360;   // 1048576
    float* Bbuf   = ws + 6823936;   // 1048576
    float* pens   = ws + 7872512;   // 4096
    float* klp    = ws + 7876608;   // 4096
    float* predp  = ws + 7880704;   // 16384

    // Zero the scatter accumulators (ws is poisoned 0xAA before every call)
    hipMemsetAsync(deg,   0, 4096u * 4, stream);
    hipMemsetAsync(h,     0, 1048576u * 4, stream);
    hipMemsetAsync(aggmu, 0, 524288u * 4, stream);
    hipMemsetAsync(aggls, 0, 524288u * 4, stream);

    // Stage A: per-graph SAGE pooling
    k_per_graph<<<GG, 256, 0, stream>>>(x, ei, ew, Wg, bg, Wf1, bf1, Wf2, bf2, g_embs, pens);

    // Stage B: graph-level VGAE
    k_deg<<<EP / 256, 256, 0, stream>>>(pos + EP, deg);
    k_dinv<<<GG / 256, 256, 0, stream>>>(deg, dinv);

    // h = relu(gcn(g_embs, W_c1, b_c1))
    k_gemm<<<dim3(64, 4), 256, 0, stream>>>(g_embs, Wc1, nullptr, xw1,
                                            nullptr, nullptr, nullptr, GG, 128, 256);
    k_scatter_h<<<EP / 4, 256, 0, stream>>>(pos, dinv, xw1, h);
    k_fin_h<<<GG, 256, 0, stream>>>(xw1, dinv, bc1, h);

    // mu = gcn(h, W_mu), logstd = min(gcn(h, W_ls), 10); z; zc = [emb, z]; kl
    k_gemm<<<dim3(64, 4), 256, 0, stream>>>(h, Wmu, nullptr, xwmu,
                                            Wls, nullptr, xwls, GG, 256, 128);
    k_scatter_muls<<<EP / 4, 256, 0, stream>>>(pos, dinv, xwmu, xwls, aggmu, aggls);
    k_fin_z<<<GG, 128, 0, stream>>>(aggmu, aggls, xwmu, xwls, dinv, bmu, bls, eps, emb, zc, klp);

    // A = zc@W_lin1+b, B = zc@W_lin2+b (per-node factorization of the edge MLP)
    k_gemm<<<dim3(64, 8), 256, 0, stream>>>(zc, Wl1, bl1, Abuf,
                                            Wl2, bl2, Bbuf, GG, 256, 256);

    // Edge predictions + partial log sums; final scalars
    k_pred<<<(2 * EP) / 4, 256, 0, stream>>>(Abuf, Bbuf, pos, neg, out, predp);
    k_final<<<1, 256, 0, stream>>>(pens, klp, predp, out);
}

// Round 3
// 1693.983 us; speedup vs baseline: 1.3602x; 1.3537x over previous
//
#include <hip/hip_runtime.h>
#include <hip/hip_bf16.h>
#include <math.h>

// Sizes (fixed by the reference)
#define GG   4096
#define NNODE 64
#define EEDGE 256
#define FFEAT 64
#define DDIM 128
#define EP   32768

// ---------------------------------------------------------------------------
// Kernel 1: one block per graph. Computes h (GCNConv), S (MLP+softmax),
// Laplacian penalty, and g_emb. LDS-resident throughout.
// LDS plan (floats, total 18176 = 72.7 KB -> 2 blocks/CU):
//   [0,8448)      hs   64x132   (phase1 alias: xs 64x68 @0, Wt 128x20 @4352)
//   [8448,16896)  xw   64x132   (post-scatter alias: Wf1s 2048 @8448, a1s @10496)
//   [16896,18176) edges + small vectors
// Round-2 post-mortem: per-thread ARRAYS (acc[4][8], xv[4], hvv[4]) were
// being spilled to scratch -> 4.2 GB HBM RMW traffic, kernel 1.8 ms.
// This version uses ONLY named scalars/float4s (macro-unrolled) so there is
// no indexable aggregate to spill, and plain __launch_bounds__(256) so the
// allocator can exceed 128 VGPRs instead of spilling.
// ---------------------------------------------------------------------------
__global__ __launch_bounds__(256) void k_per_graph(
    const float* __restrict__ x, const int* __restrict__ ei, const float* __restrict__ ew,
    const float* __restrict__ Wg, const float* __restrict__ bg,
    const float* __restrict__ Wf1, const float* __restrict__ bf1,
    const float* __restrict__ Wf2, const float* __restrict__ bf2,
    float* __restrict__ g_embs, float* __restrict__ pens)
{
    __shared__ __align__(16) float sm[18176];
    float* hs    = sm;                  // 64 x 132
    float* xs    = sm;                  // 64 x 68 (phase 1, dies after GEMM)
    float* Wt    = sm + 4352;           // 128 x 20 (phase 1)
    float* xw    = sm + 8448;           // 64 x 132
    float* Wf1s  = sm + 8448;           // 2048 (aliases xw after scatter done)
    float* a1s   = sm + 10496;          // 1024
    int*   srcs  = (int*)(sm + 16896);  // 256
    int*   dsts  = (int*)(sm + 17152);  // 256
    float* ewx   = sm + 17408;          // 256
    float* degs  = sm + 17664;          // 64
    float* dinvs = sm + 17728;          // 64
    float* Ss    = sm + 17792;          // 64 x 2
    float* deg2s = sm + 17920;          // 64
    float* dinv2s= sm + 17984;          // 64
    float* LSs   = sm + 18048;          // 64 x 2 -> end 18176

    const int g = blockIdx.x;
    const int t = threadIdx.x;

    // ---- Phase 0: stage x (stride 68), edges, init degs (self-loop +1) ----
    {
        const float* xg = x + (size_t)g * (NNODE * FFEAT);
        for (int i = t; i < (NNODE * FFEAT) / 4; i += 256) {
            float4 v = ((const float4*)xg)[i];
            int n = i >> 4, k = (i & 15) * 4;
            *(float4*)&xs[n * 68 + k] = v;
        }
        const int* eg = ei + (size_t)g * (2 * EEDGE);
        srcs[t] = eg[t];
        dsts[t] = eg[EEDGE + t];
        ewx[t]  = ew[(size_t)g * EEDGE + t];
        if (t < NNODE) degs[t] = 1.0f;
    }

    // ---- GEMM: xw = x @ W_gcn1  (64x64 @ 64x128), micro-tile 4n x 8d ----
    // Accumulators: 8 named float4s (no arrays -> cannot spill via indexing).
    const int dq = t & 15;            // d = dq + 16*j, j<8 (j=4*a+elem / 4*b+elem)
    const int n0 = (t >> 4) * 4;      // n = n0 + i, i<4
    float4 z4 = {0.f, 0.f, 0.f, 0.f};
    float4 c0a = z4, c0b = z4, c1a = z4, c1b = z4;
    float4 c2a = z4, c2b = z4, c3a = z4, c3b = z4;

    for (int kc = 0; kc < 4; ++kc) {
        __syncthreads();  // kc=0: fences phase-0 writes; kc>0: fences prior Wt reads
        for (int i = t; i < 2048; i += 256) {
            int k = i >> 7, d = i & 127;
            Wt[d * 20 + k] = Wg[(kc * 16 + k) * 128 + d];  // transposed, stride 20
        }
        __syncthreads();
        if (kc == 0) atomicAdd(&degs[dsts[t]], ewx[t]);    // weighted in-degree
#pragma unroll
        for (int k4 = 0; k4 < 4; ++k4) {
            float4 xv0 = *(const float4*)&xs[(n0 + 0) * 68 + kc * 16 + k4 * 4];
            float4 xv1 = *(const float4*)&xs[(n0 + 1) * 68 + kc * 16 + k4 * 4];
            float4 xv2 = *(const float4*)&xs[(n0 + 2) * 68 + kc * 16 + k4 * 4];
            float4 xv3 = *(const float4*)&xs[(n0 + 3) * 68 + kc * 16 + k4 * 4];
#define GSTEP(J, F) { \
            float4 wv = *(const float4*)&Wt[(dq + 16 * (J)) * 20 + k4 * 4]; \
            c0##F += xv0.x * wv.x + xv0.y * wv.y + xv0.z * wv.z + xv0.w * wv.w; \
            c1##F += xv1.x * wv.x + xv1.y * wv.y + xv1.z * wv.z + xv1.w * wv.w; \
            c2##F += xv2.x * wv.x + xv2.y * wv.y + xv2.z * wv.z + xv2.w * wv.w; \
            c3##F += xv3.x * wv.x + xv3.y * wv.y + xv3.z * wv.z + xv3.w * wv.w; }
            GSTEP(0, a.x) GSTEP(1, a.y) GSTEP(2, a.z) GSTEP(3, a.w)
            GSTEP(4, b.x) GSTEP(5, b.y) GSTEP(6, b.z) GSTEP(7, b.w)
#undef GSTEP
        }
    }
    if (t < NNODE) dinvs[t] = rsqrtf(degs[t]);

    // ---- Store accs -> xw (static addressing; scalar stores) ----
#define GST(I, J, V) xw[(n0 + (I)) * 132 + dq + 16 * (J)] = V;
    GST(0, 0, c0a.x) GST(0, 1, c0a.y) GST(0, 2, c0a.z) GST(0, 3, c0a.w)
    GST(0, 4, c0b.x) GST(0, 5, c0b.y) GST(0, 6, c0b.z) GST(0, 7, c0b.w)
    GST(1, 0, c1a.x) GST(1, 1, c1a.y) GST(1, 2, c1a.z) GST(1, 3, c1a.w)
    GST(1, 4, c1b.x) GST(1, 5, c1b.y) GST(1, 6, c1b.z) GST(1, 7, c1b.w)
    GST(2, 0, c2a.x) GST(2, 1, c2a.y) GST(2, 2, c2a.z) GST(2, 3, c2a.w)
    GST(2, 4, c2b.x) GST(2, 5, c2b.y) GST(2, 6, c2b.z) GST(2, 7, c2b.w)
    GST(3, 0, c3a.x) GST(3, 1, c3a.y) GST(3, 2, c3a.z) GST(3, 3, c3a.w)
    GST(3, 4, c3b.x) GST(3, 5, c3b.y) GST(3, 6, c3b.z) GST(3, 7, c3b.w)
#undef GST
    __syncthreads();  // xw + dinvs ready; xs dead (safe to overwrite with hs)

    // ---- h init: self-loop + bias ----
    for (int i = t; i < 8192; i += 256) {
        int n = i >> 7, d = i & 127;
        hs[n * 132 + d] = xw[n * 132 + d] * dinvs[n] * dinvs[n] + bg[d];
    }
    __syncthreads();

    // ---- Edge scatter: hs[dst] += xw[src] * norm (LDS atomics) ----
    for (int i = t; i < 32768; i += 256) {
        int e = i >> 7, d = i & 127;
        int s = srcs[e], dd = dsts[e];
        float nrm = dinvs[s] * ewx[e] * dinvs[dd];
        atomicAdd(&hs[dd * 132 + d], xw[s * 132 + d] * nrm);
    }
    __syncthreads();

    // ---- a1 = tanh(h @ W_fc1 + b_fc1)  (64x128 @ 128x16) ----
    for (int i = t; i < 2048; i += 256) Wf1s[i] = Wf1[i];
    __syncthreads();
    {
        int n = t >> 2, j0 = (t & 3) * 4;
        float a0 = bf1[j0], a1v = bf1[j0 + 1], a2 = bf1[j0 + 2], a3 = bf1[j0 + 3];
#pragma unroll
        for (int k4 = 0; k4 < 32; ++k4) {
            float4 hv = *(const float4*)&hs[n * 132 + k4 * 4];
            float4 w0 = *(const float4*)&Wf1s[(k4 * 4 + 0) * 16 + j0];
            float4 w1 = *(const float4*)&Wf1s[(k4 * 4 + 1) * 16 + j0];
            float4 w2 = *(const float4*)&Wf1s[(k4 * 4 + 2) * 16 + j0];
            float4 w3 = *(const float4*)&Wf1s[(k4 * 4 + 3) * 16 + j0];
            a0  += hv.x * w0.x + hv.y * w1.x + hv.z * w2.x + hv.w * w3.x;
            a1v += hv.x * w0.y + hv.y * w1.y + hv.z * w2.y + hv.w * w3.y;
            a2  += hv.x * w0.z + hv.y * w1.z + hv.z * w2.z + hv.w * w3.z;
            a3  += hv.x * w0.w + hv.y * w1.w + hv.z * w2.w + hv.w * w3.w;
        }
        a1s[n * 16 + j0]     = tanhf(a0);
        a1s[n * 16 + j0 + 1] = tanhf(a1v);
        a1s[n * 16 + j0 + 2] = tanhf(a2);
        a1s[n * 16 + j0 + 3] = tanhf(a3);
    }
    __syncthreads();

    // ---- S = softmax(a1 @ W_fc2 + b_fc2, axis=1) ----
    if (t < 128) {
        int n = t >> 1, kk = t & 1;
        float z = bf2[kk];
#pragma unroll
        for (int j = 0; j < 16; ++j) z += a1s[n * 16 + j] * Wf2[j * 2 + kk];
        Ss[n * 2 + kk] = z;
    }
    __syncthreads();
    if (t < 64) {
        float z0 = Ss[t * 2], z1 = Ss[t * 2 + 1];
        float m = fmaxf(z0, z1);
        float e0 = expf(z0 - m), e1 = expf(z1 - m);
        float inv = 1.0f / (e0 + e1);
        Ss[t * 2] = e0 * inv; Ss[t * 2 + 1] = e1 * inv;
    }
    if (t < 64) deg2s[t] = 0.0f;
    __syncthreads();

    // ---- Laplacian: deg from src, LS = L @ S without materializing L ----
    atomicAdd(&deg2s[srcs[t]], ewx[t]);
    __syncthreads();
    if (t < 64) {
        float dg = deg2s[t];
        dinv2s[t] = dg > 0.0f ? rsqrtf(fmaxf(dg, 1e-30f)) : 0.0f;
    }
    if (t < 128) LSs[t] = Ss[t];  // identity part
    __syncthreads();
    for (int i = t; i < 512; i += 256) {
        int e = i >> 1, kk = i & 1;
        int s = srcs[e], dd = dsts[e];
        float lw = -dinv2s[s] * ewx[e] * dinv2s[dd];
        atomicAdd(&LSs[s * 2 + kk], lw * Ss[dd * 2 + kk]);
    }
    __syncthreads();

    // ---- new_adj = S^T (L S) -> penalty ----
    if (t < 64) {
        float s0 = Ss[t * 2], s1 = Ss[t * 2 + 1];
        float l0 = LSs[t * 2], l1 = LSs[t * 2 + 1];
        float p00 = s0 * l0, p01 = s0 * l1, p10 = s1 * l0, p11 = s1 * l1;
        for (int o = 32; o; o >>= 1) {
            p00 += __shfl_down(p00, o); p01 += __shfl_down(p01, o);
            p10 += __shfl_down(p10, o); p11 += __shfl_down(p11, o);
        }
        if (t == 0) {
            float r0 = fmaxf(fabsf(p00) + fabsf(p01), 1e-12f);
            float r1 = fmaxf(fabsf(p10) + fabsf(p11), 1e-12f);
            float d0 = p00 / r0 - 1.0f, d1 = p11 / r1 - 1.0f;
            pens[g] = 0.5f * (d0 * d0 + d1 * d1);
        }
    }

    // ---- g_emb = mean(S^T h, axis=0) = 0.5 * sum_n (S[n,0]+S[n,1]) h[n,:] ----
    if (t < 128) {
        float s = 0.f;
        for (int n = 0; n < 64; ++n)
            s += (Ss[n * 2] + Ss[n * 2 + 1]) * hs[n * 132 + t];
        g_embs[(size_t)g * 128 + t] = 0.5f * s;
    }
}

// ---------------------------------------------------------------------------
// Graph-level degree (indegree count + 1 self loop) and dinv
// ---------------------------------------------------------------------------
__global__ void k_deg(const int* __restrict__ pd, float* __restrict__ deg) {
    int e = blockIdx.x * 256 + threadIdx.x;
    atomicAdd(&deg[pd[e]], 1.0f);
}

__global__ void k_dinv(const float* __restrict__ deg, float* __restrict__ dinv) {
    int i = blockIdx.x * 256 + threadIdx.x;
    dinv[i] = rsqrtf(deg[i] + 1.0f);
}

// ---------------------------------------------------------------------------
// Generic tiled fp32 GEMM: C = A[MxK] @ B[KxN] (+bias). Optional second
// output (shared A): blockIdx.y >= gridDim.y/2 uses (B1,bias1,C1).
// Tile 64x64, 256 threads, 4x4 micro-tile, BK=32.
// ---------------------------------------------------------------------------
__global__ __launch_bounds__(256) void k_gemm(
    const float* __restrict__ A,
    const float* __restrict__ B0, const float* __restrict__ bias0, float* __restrict__ C0,
    const float* __restrict__ B1, const float* __restrict__ bias1, float* __restrict__ C1,
    int M, int K, int N)
{
    __shared__ __align__(16) float At[32 * 68];  // [k][m] stride 68
    __shared__ __align__(16) float Bs[32 * 68];  // [k][n] stride 68
    const float* B = B0; const float* bias = bias0; float* C = C0;
    int by = blockIdx.y;
    if (B1 != nullptr && by >= (int)(gridDim.y >> 1)) {
        B = B1; bias = bias1; C = C1; by -= (gridDim.y >> 1);
    }
    const int mb = blockIdx.x * 64, nb = by * 64;
    const int t = threadIdx.x;
    const int tm = t >> 4, tn = t & 15;
    float4 ca0 = {0,0,0,0}, ca1 = {0,0,0,0}, ca2 = {0,0,0,0}, ca3 = {0,0,0,0};
    for (int k0 = 0; k0 < K; k0 += 32) {
        __syncthreads();
        for (int i = t; i < 2048; i += 256) {
            int m = i >> 5, k = i & 31;
            At[k * 68 + m] = A[(size_t)(mb + m) * K + k0 + k];
        }
        for (int i = t; i < 2048; i += 256) {
            int k = i >> 6, n = i & 63;
            Bs[k * 68 + n] = B[(size_t)(k0 + k) * N + nb + n];
        }
        __syncthreads();
#pragma unroll
        for (int k = 0; k < 32; ++k) {
            float4 av = *(const float4*)&At[k * 68 + tm * 4];
            float4 bv = *(const float4*)&Bs[k * 68 + tn * 4];
            ca0.x += av.x * bv.x; ca0.y += av.x * bv.y; ca0.z += av.x * bv.z; ca0.w += av.x * bv.w;
            ca1.x += av.y * bv.x; ca1.y += av.y * bv.y; ca1.z += av.y * bv.z; ca1.w += av.y * bv.w;
            ca2.x += av.z * bv.x; ca2.y += av.z * bv.y; ca2.z += av.z * bv.z; ca2.w += av.z * bv.w;
            ca3.x += av.w * bv.x; ca3.y += av.w * bv.y; ca3.z += av.w * bv.z; ca3.w += av.w * bv.w;
        }
    }
    float4 bv4 = {0, 0, 0, 0};
    if (bias) bv4 = *(const float4*)&bias[nb + tn * 4];
#define CST(I, CV) { \
    float4 v; v.x = CV.x + bv4.x; v.y = CV.y + bv4.y; v.z = CV.z + bv4.z; v.w = CV.w + bv4.w; \
    *(float4*)&C[(size_t)(mb + tm * 4 + (I)) * N + nb + tn * 4] = v; }
    CST(0, ca0) CST(1, ca1) CST(2, ca2) CST(3, ca3)
#undef CST
}

// ---------------------------------------------------------------------------
// Edge scatter for the 256-wide conv: agg[pd] += xw1[ps]*dinv[ps]*dinv[pd]
// ---------------------------------------------------------------------------
__global__ void k_scatter_h(const int* __restrict__ pe, const float* __restrict__ dinv,
                            const float* __restrict__ xw, float* __restrict__ agg) {
    int t = threadIdx.x;
#pragma unroll
    for (int q = 0; q < 4; ++q) {
        int e = blockIdx.x * 4 + q;
        int s = pe[e], d = pe[EP + e];
        float nrm = dinv[s] * dinv[d];
        atomicAdd(&agg[(size_t)d * 256 + t], xw[(size_t)s * 256 + t] * nrm);
    }
}

__global__ void k_fin_h(const float* __restrict__ xw1, const float* __restrict__ dinv,
                        const float* __restrict__ bc1, float* __restrict__ h) {
    int idx = blockIdx.x * 256 + threadIdx.x;
    int g = idx >> 8, c = idx & 255;
    float dv = dinv[g];
    float v = h[idx] + xw1[idx] * dv * dv + bc1[c];
    h[idx] = fmaxf(v, 0.0f);
}

// Fused mu/logstd edge scatter (128 dims each, 256 threads)
__global__ void k_scatter_muls(const int* __restrict__ pe, const float* __restrict__ dinv,
                               const float* __restrict__ xwmu, const float* __restrict__ xwls,
                               float* __restrict__ aggmu, float* __restrict__ aggls) {
    int t = threadIdx.x;
    const float* xw = (t < 128) ? xwmu : xwls;
    float* ag = (t < 128) ? aggmu : aggls;
    int d = t & 127;
#pragma unroll
    for (int q = 0; q < 4; ++q) {
        int e = blockIdx.x * 4 + q;
        int s = pe[e], dd = pe[EP + e];
        float nrm = dinv[s] * dinv[dd];
        atomicAdd(&ag[(size_t)dd * 128 + d], xw[(size_t)s * 128 + d] * nrm);
    }
}

// mu, logstd, z, zc = [emb, z], and per-graph KL partial
__global__ void k_fin_z(const float* __restrict__ aggmu, const float* __restrict__ aggls,
                        const float* __restrict__ xwmu, const float* __restrict__ xwls,
                        const float* __restrict__ dinv,
                        const float* __restrict__ bmu, const float* __restrict__ bls,
                        const float* __restrict__ eps, const float* __restrict__ emb,
                        float* __restrict__ zc, float* __restrict__ klp) {
    __shared__ float smw[2];
    int g = blockIdx.x, d = threadIdx.x;  // 128 threads
    int idx = g * 128 + d;
    float dv = dinv[g], d2 = dv * dv;
    float mu = aggmu[idx] + xwmu[idx] * d2 + bmu[d];
    float ls = aggls[idx] + xwls[idx] * d2 + bls[d];
    ls = fminf(ls, 10.0f);
    float z = mu + eps[idx] * expf(ls);
    zc[(size_t)g * 256 + d] = emb[idx];
    zc[(size_t)g * 256 + 128 + d] = z;
    float term = 1.0f + 2.0f * ls - mu * mu - expf(2.0f * ls);
    for (int o = 32; o; o >>= 1) term += __shfl_down(term, o);
    if ((d & 63) == 0) smw[d >> 6] = term;
    __syncthreads();
    if (d == 0) klp[g] = smw[0] + smw[1];
}

// Edge predictions: sigmoid(dot(Arow[src], Brow[dst])) + per-block log partial
__global__ void k_pred(const float* __restrict__ A, const float* __restrict__ B,
                       const int* __restrict__ pos, const int* __restrict__ neg,
                       float* __restrict__ out, float* __restrict__ predp) {
    __shared__ float smw[4];
    int t = threadIdx.x, w = t >> 6, l = t & 63;
    int eg = blockIdx.x * 4 + w;
    int isneg = eg >= EP;
    int e = eg - (isneg ? EP : 0);
    const int* eix = isneg ? neg : pos;
    int s = eix[e], d = eix[EP + e];
    const float4* Ar = (const float4*)(A + (size_t)s * 256);
    const float4* Br = (const float4*)(B + (size_t)d * 256);
    float4 av = Ar[l], bv = Br[l];
    float dot = av.x * bv.x + av.y * bv.y + av.z * bv.z + av.w * bv.w;
    for (int o = 32; o; o >>= 1) dot += __shfl_down(dot, o);
    if (l == 0) {
        float p = 1.0f / (1.0f + expf(-dot));
        float term;
        if (isneg) { out[2 + EP + e] = p; term = logf(1.0f - p + 1e-15f); }
        else       { out[2 + e] = p;      term = logf(p + 1e-15f); }
        smw[w] = term;
    }
    __syncthreads();
    if (t == 0) predp[blockIdx.x] = smw[0] + smw[1] + smw[2] + smw[3];
}

// Final scalar reductions
__global__ void k_final(const float* __restrict__ pens, const float* __restrict__ klp,
                        const float* __restrict__ predp, float* __restrict__ out) {
    __shared__ float sm[16];
    int t = threadIdx.x;
    float s_pen = 0.f, s_kl = 0.f, s_pos = 0.f, s_neg = 0.f;
    for (int i = t; i < 4096; i += 256) { s_pen += pens[i]; s_kl += klp[i]; }
    for (int i = t; i < 8192; i += 256) { s_pos += predp[i]; s_neg += predp[8192 + i]; }
    for (int o = 32; o; o >>= 1) {
        s_pen += __shfl_down(s_pen, o); s_kl += __shfl_down(s_kl, o);
        s_pos += __shfl_down(s_pos, o); s_neg += __shfl_down(s_neg, o);
    }
    int w = t >> 6;
    if ((t & 63) == 0) { sm[w] = s_pen; sm[4 + w] = s_kl; sm[8 + w] = s_pos; sm[12 + w] = s_neg; }
    __syncthreads();
    if (t == 0) {
        float pen = sm[0] + sm[1] + sm[2] + sm[3];
        float kls = sm[4] + sm[5] + sm[6] + sm[7];
        float pos = sm[8] + sm[9] + sm[10] + sm[11];
        float neg = sm[12] + sm[13] + sm[14] + sm[15];
        float rec = -(pos / 32768.0f) - (neg / 32768.0f);
        out[0] = rec - 0.5f * kls / (4096.0f * 4096.0f);  // rec + (kl)/G, kl = -0.5*kls/G
        out[1] = pen * (1.0f / 4096.0f);
    }
}

extern "C" void kernel_launch(void* const* d_in, const int* in_sizes, int n_in,
                              void* d_out, int out_size, void* d_ws, size_t ws_size,
                              hipStream_t stream) {
    const float* x   = (const float*)d_in[0];
    const int*   ei  = (const int*)d_in[1];
    const float* ew  = (const float*)d_in[2];
    const int*   pos = (const int*)d_in[3];
    const int*   neg = (const int*)d_in[4];
    const float* eps = (const float*)d_in[5];
    const float* Wg  = (const float*)d_in[6];
    const float* bg  = (const float*)d_in[7];
    const float* Wf1 = (const float*)d_in[8];
    const float* bf1 = (const float*)d_in[9];
    const float* Wf2 = (const float*)d_in[10];
    const float* bf2 = (const float*)d_in[11];
    const float* Wc1 = (const float*)d_in[12];
    const float* bc1 = (const float*)d_in[13];
    const float* Wmu = (const float*)d_in[14];
    const float* bmu = (const float*)d_in[15];
    const float* Wls = (const float*)d_in[16];
    const float* bls = (const float*)d_in[17];
    const float* emb = (const float*)d_in[18];
    const float* Wl1 = (const float*)d_in[19];
    const float* bl1 = (const float*)d_in[20];
    const float* Wl2 = (const float*)d_in[21];
    const float* bl2 = (const float*)d_in[22];
    float* out = (float*)d_out;
    float* ws  = (float*)d_ws;

    // Workspace layout (floats): ~30.1 MB total
    float* g_embs = ws + 0;         // 524288
    float* deg    = ws + 524288;    // 4096
    float* dinv   = ws + 528384;    // 4096
    float* xw1    = ws + 532480;    // 1048576
    float* h      = ws + 1581056;   // 1048576 (agg accumulator, then relu'd)
    float* xwmu   = ws + 2629632;   // 524288
    float* xwls   = ws + 3153920;   // 524288
    float* aggmu  = ws + 3678208;   // 524288
    float* aggls  = ws + 4202496;   // 524288
    float* zc     = ws + 4726784;   // 1048576
    float* Abuf   = ws + 5775360;   // 1048576
    float* Bbuf   = ws + 6823936;   // 1048576
    float* pens   = ws + 7872512;   // 4096
    float* klp    = ws + 7876608;   // 4096
    float* predp  = ws + 7880704;   // 16384

    // Zero the scatter accumulators (ws is poisoned 0xAA before every call)
    hipMemsetAsync(deg,   0, 4096u * 4, stream);
    hipMemsetAsync(h,     0, 1048576u * 4, stream);
    hipMemsetAsync(aggmu, 0, 524288u * 4, stream);
    hipMemsetAsync(aggls, 0, 524288u * 4, stream);

    // Stage A: per-graph SAGE pooling
    k_per_graph<<<GG, 256, 0, stream>>>(x, ei, ew, Wg, bg, Wf1, bf1, Wf2, bf2, g_embs, pens);

    // Stage B: graph-level VGAE
    k_deg<<<EP / 256, 256, 0, stream>>>(pos + EP, deg);
    k_dinv<<<GG / 256, 256, 0, stream>>>(deg, dinv);

    // h = relu(gcn(g_embs, W_c1, b_c1))
    k_gemm<<<dim3(64, 4), 256, 0, stream>>>(g_embs, Wc1, nullptr, xw1,
                                            nullptr, nullptr, nullptr, GG, 128, 256);
    k_scatter_h<<<EP / 4, 256, 0, stream>>>(pos, dinv, xw1, h);
    k_fin_h<<<GG, 256, 0, stream>>>(xw1, dinv, bc1, h);

    // mu = gcn(h, W_mu), logstd = min(gcn(h, W_ls), 10); z; zc = [emb, z]; kl
    k_gemm<<<dim3(64, 4), 256, 0, stream>>>(h, Wmu, nullptr, xwmu,
                                            Wls, nullptr, xwls, GG, 256, 128);
    k_scatter_muls<<<EP / 4, 256, 0, stream>>>(pos, dinv, xwmu, xwls, aggmu, aggls);
    k_fin_z<<<GG, 128, 0, stream>>>(aggmu, aggls, xwmu, xwls, dinv, bmu, bls, eps, emb, zc, klp);

    // A = zc@W_lin1+b, B = zc@W_lin2+b (per-node factorization of the edge MLP)
    k_gemm<<<dim3(64, 8), 256, 0, stream>>>(zc, Wl1, bl1, Abuf,
                                            Wl2, bl2, Bbuf, GG, 256, 256);

    // Edge predictions + partial log sums; final scalars
    k_pred<<<(2 * EP) / 4, 256, 0, stream>>>(Abuf, Bbuf, pos, neg, out, predp);
    k_final<<<1, 256, 0, stream>>>(pens, klp, predp, out);
}

// Round 4
// 785.041 us; speedup vs baseline: 2.9352x; 2.1578x over previous
//
#include <hip/hip_runtime.h>
#include <hip/hip_bf16.h>
#include <math.h>

// Sizes (fixed by the reference)
#define GG   4096
#define NNODE 64
#define EEDGE 256
#define FFEAT 64
#define DDIM 128
#define EP   32768

// ---------------------------------------------------------------------------
// Prep (runs once per call, tiny): Wgf1 = Wg @ Wf1  [64x16],
// bcomb = bg @ Wf1 + bf1 [16], bg32 = 32*bg [128].
// Folding is exact linear algebra: h@Wf1 = (Ax)@(Wg@Wf1) + bg@Wf1.
// ---------------------------------------------------------------------------
__global__ void k_prep(const float* __restrict__ Wg, const float* __restrict__ Wf1,
                       const float* __restrict__ bf1, const float* __restrict__ bg,
                       float* __restrict__ Wgf1, float* __restrict__ bcomb,
                       float* __restrict__ bg32) {
    int t = threadIdx.x;
    for (int o = t; o < 1024; o += 256) {
        int f = o >> 4, j = o & 15;
        float s = 0.f;
        for (int d = 0; d < 128; ++d) s += Wg[f * 128 + d] * Wf1[d * 16 + j];
        Wgf1[o] = s;
    }
    if (t < 16) {
        float s = bf1[t];
        for (int d = 0; d < 128; ++d) s += bg[d] * Wf1[d * 16 + t];
        bcomb[t] = s;
    }
    if (t >= 128) bg32[t - 128] = 32.0f * bg[t - 128];
}

// ---------------------------------------------------------------------------
// Per-graph kernel (aggregate-first, h never materialized).
// Computes: xa = A_norm x (64x64, LDS); a1 = tanh(xa@Wgf1+bcomb); S = softmax;
// Laplacian penalty; q = sum_n (S[n,0]+S[n,1]) xa[n] -> Qh = 0.5q.
// g_emb is finished later as Qh@Wg + 32*bg (batched GEMM).
// LDS 30.8 KB -> 5 blocks/CU; no large per-thread arrays -> no spill surface.
// ---------------------------------------------------------------------------
__global__ __launch_bounds__(256) void k_pg(
    const float* __restrict__ x, const int* __restrict__ ei, const float* __restrict__ ew,
    const float* __restrict__ Wgf1, const float* __restrict__ bcomb,
    const float* __restrict__ Wf2, const float* __restrict__ bf2,
    float* __restrict__ Qh, float* __restrict__ pens)
{
    __shared__ __align__(16) float sm[7696];
    float* xa     = sm;                  // 64 x 68
    float* Wgf1s  = sm + 4352;           // 1024
    float* a1s    = sm + 5376;           // 1024
    int*   srcs   = (int*)(sm + 6400);   // 256
    int*   dsts   = (int*)(sm + 6656);   // 256
    float* ewx    = sm + 6912;           // 256
    float* degs   = sm + 7168;           // 64
    float* dinvs  = sm + 7232;           // 64
    float* Ss     = sm + 7296;           // 128
    float* deg2s  = sm + 7424;           // 64
    float* dinv2s = sm + 7488;           // 64
    float* LSs    = sm + 7552;           // 128
    float* bcs    = sm + 7680;           // 16

    const int g = blockIdx.x;
    const int t = threadIdx.x;
    const float* xg = x + (size_t)g * (NNODE * FFEAT);

    // Phase 0: edges, weight folds, deg inits
    {
        const int* eg = ei + (size_t)g * (2 * EEDGE);
        srcs[t] = eg[t];
        dsts[t] = eg[EEDGE + t];
        ewx[t]  = ew[(size_t)g * EEDGE + t];
        for (int i = t; i < 1024; i += 256) Wgf1s[i] = Wgf1[i];
        if (t < 16) bcs[t] = bcomb[t];
        if (t < 64) { degs[t] = 1.0f; deg2s[t] = 0.0f; }
    }
    __syncthreads();
    atomicAdd(&degs[dsts[t]], ewx[t]);    // gcn in-degree (self-loop 1 pre-set)
    atomicAdd(&deg2s[srcs[t]], ewx[t]);   // laplacian out-degree
    __syncthreads();
    if (t < 64) {
        dinvs[t] = rsqrtf(degs[t]);
        float dg = deg2s[t];
        dinv2s[t] = dg > 0.0f ? rsqrtf(fmaxf(dg, 1e-30f)) : 0.0f;
    }
    __syncthreads();

    // xa init: self-loop term x[n]*dinv^2[n]
    for (int i = t; i < 1024; i += 256) {
        int n = i >> 4, k = (i & 15) * 4;
        float4 v = *(const float4*)&xg[n * 64 + k];
        float s = dinvs[n] * dinvs[n];
        float4 r; r.x = v.x * s; r.y = v.y * s; r.z = v.z * s; r.w = v.w * s;
        *(float4*)&xa[n * 68 + k] = r;
    }
    __syncthreads();

    // Edge scatter in F=64 feature space: xa[dst] += x[src]*norm
    for (int i = t; i < 16384; i += 256) {
        int e = i >> 6, d = i & 63;
        int s = srcs[e], dd = dsts[e];
        float nrm = dinvs[s] * ewx[e] * dinvs[dd];
        atomicAdd(&xa[dd * 68 + d], xg[s * 64 + d] * nrm);
    }
    __syncthreads();

    // a1 = tanh(xa @ Wgf1 + bcomb)  (64x64 @ 64x16)
    {
        int n = t >> 2, j0 = (t & 3) * 4;
        float a0 = bcs[j0], a1v = bcs[j0 + 1], a2 = bcs[j0 + 2], a3 = bcs[j0 + 3];
#pragma unroll 4
        for (int k4 = 0; k4 < 16; ++k4) {
            float4 hv = *(const float4*)&xa[n * 68 + k4 * 4];
            float4 w0 = *(const float4*)&Wgf1s[(k4 * 4 + 0) * 16 + j0];
            float4 w1 = *(const float4*)&Wgf1s[(k4 * 4 + 1) * 16 + j0];
            float4 w2 = *(const float4*)&Wgf1s[(k4 * 4 + 2) * 16 + j0];
            float4 w3 = *(const float4*)&Wgf1s[(k4 * 4 + 3) * 16 + j0];
            a0  += hv.x * w0.x + hv.y * w1.x + hv.z * w2.x + hv.w * w3.x;
            a1v += hv.x * w0.y + hv.y * w1.y + hv.z * w2.y + hv.w * w3.y;
            a2  += hv.x * w0.z + hv.y * w1.z + hv.z * w2.z + hv.w * w3.z;
            a3  += hv.x * w0.w + hv.y * w1.w + hv.z * w2.w + hv.w * w3.w;
        }
        a1s[n * 16 + j0]     = tanhf(a0);
        a1s[n * 16 + j0 + 1] = tanhf(a1v);
        a1s[n * 16 + j0 + 2] = tanhf(a2);
        a1s[n * 16 + j0 + 3] = tanhf(a3);
    }
    __syncthreads();

    // S = softmax(a1 @ W_fc2 + b_fc2, axis=1)
    if (t < 128) {
        int n = t >> 1, kk = t & 1;
        float z = bf2[kk];
#pragma unroll
        for (int j = 0; j < 16; ++j) z += a1s[n * 16 + j] * Wf2[j * 2 + kk];
        Ss[n * 2 + kk] = z;
    }
    __syncthreads();
    if (t < 64) {
        float z0 = Ss[t * 2], z1 = Ss[t * 2 + 1];
        float m = fmaxf(z0, z1);
        float e0 = expf(z0 - m), e1 = expf(z1 - m);
        float inv = 1.0f / (e0 + e1);
        Ss[t * 2] = e0 * inv; Ss[t * 2 + 1] = e1 * inv;
    }
    __syncthreads();

    // LS = L @ S (identity part + edge scatter; L never materialized)
    if (t < 128) LSs[t] = Ss[t];
    __syncthreads();
    for (int i = t; i < 512; i += 256) {
        int e = i >> 1, kk = i & 1;
        int s = srcs[e], dd = dsts[e];
        float lw = -dinv2s[s] * ewx[e] * dinv2s[dd];
        atomicAdd(&LSs[s * 2 + kk], lw * Ss[dd * 2 + kk]);
    }
    __syncthreads();

    // wave 0: penalty = 0.5*((norm_adj00-1)^2 + (norm_adj11-1)^2)
    if (t < 64) {
        float s0 = Ss[t * 2], s1 = Ss[t * 2 + 1];
        float l0 = LSs[t * 2], l1 = LSs[t * 2 + 1];
        float p00 = s0 * l0, p01 = s0 * l1, p10 = s1 * l0, p11 = s1 * l1;
        for (int o = 32; o; o >>= 1) {
            p00 += __shfl_down(p00, o); p01 += __shfl_down(p01, o);
            p10 += __shfl_down(p10, o); p11 += __shfl_down(p11, o);
        }
        if (t == 0) {
            float r0 = fmaxf(fabsf(p00) + fabsf(p01), 1e-12f);
            float r1 = fmaxf(fabsf(p10) + fabsf(p11), 1e-12f);
            float d0 = p00 / r0 - 1.0f, d1 = p11 / r1 - 1.0f;
            pens[g] = 0.5f * (d0 * d0 + d1 * d1);
        }
    }
    // wave 1: q[k] = sum_n (S[n,0]+S[n,1]) * xa[n,k]; Qh = 0.5*q
    if (t >= 64 && t < 128) {
        int k = t - 64;
        float qk = 0.f;
        for (int n = 0; n < 64; ++n)
            qk += (Ss[n * 2] + Ss[n * 2 + 1]) * xa[n * 68 + k];
        Qh[(size_t)g * 64 + k] = 0.5f * qk;
    }
}

// ---------------------------------------------------------------------------
// Graph-level degree (indegree count + 1 self loop) and dinv
// ---------------------------------------------------------------------------
__global__ void k_deg(const int* __restrict__ pd, float* __restrict__ deg) {
    int e = blockIdx.x * 256 + threadIdx.x;
    atomicAdd(&deg[pd[e]], 1.0f);
}

__global__ void k_dinv(const float* __restrict__ deg, float* __restrict__ dinv) {
    int i = blockIdx.x * 256 + threadIdx.x;
    dinv[i] = rsqrtf(deg[i] + 1.0f);
}

// ---------------------------------------------------------------------------
// Generic tiled fp32 GEMM: C = A[MxK] @ B[KxN] (+bias, optional relu).
// Optional second output (shared A): blockIdx.y >= gridDim.y/2 uses B1/bias1/C1.
// Tile 64x64, 256 threads, 4x4 micro-tile (named float4 accs), BK=32.
// ---------------------------------------------------------------------------
__global__ __launch_bounds__(256) void k_gemm(
    const float* __restrict__ A,
    const float* __restrict__ B0, const float* __restrict__ bias0, float* __restrict__ C0,
    const float* __restrict__ B1, const float* __restrict__ bias1, float* __restrict__ C1,
    int M, int K, int N, int dorelu)
{
    __shared__ __align__(16) float At[32 * 68];  // [k][m] stride 68
    __shared__ __align__(16) float Bs[32 * 68];  // [k][n] stride 68
    const float* B = B0; const float* bias = bias0; float* C = C0;
    int by = blockIdx.y;
    if (B1 != nullptr && by >= (int)(gridDim.y >> 1)) {
        B = B1; bias = bias1; C = C1; by -= (gridDim.y >> 1);
    }
    const int mb = blockIdx.x * 64, nb = by * 64;
    const int t = threadIdx.x;
    const int tm = t >> 4, tn = t & 15;
    float4 ca0 = {0,0,0,0}, ca1 = {0,0,0,0}, ca2 = {0,0,0,0}, ca3 = {0,0,0,0};
    for (int k0 = 0; k0 < K; k0 += 32) {
        __syncthreads();
        for (int i = t; i < 2048; i += 256) {
            int m = i >> 5, k = i & 31;
            At[k * 68 + m] = A[(size_t)(mb + m) * K + k0 + k];
        }
        for (int i = t; i < 2048; i += 256) {
            int k = i >> 6, n = i & 63;
            Bs[k * 68 + n] = B[(size_t)(k0 + k) * N + nb + n];
        }
        __syncthreads();
#pragma unroll
        for (int k = 0; k < 32; ++k) {
            float4 av = *(const float4*)&At[k * 68 + tm * 4];
            float4 bv = *(const float4*)&Bs[k * 68 + tn * 4];
            ca0.x += av.x * bv.x; ca0.y += av.x * bv.y; ca0.z += av.x * bv.z; ca0.w += av.x * bv.w;
            ca1.x += av.y * bv.x; ca1.y += av.y * bv.y; ca1.z += av.y * bv.z; ca1.w += av.y * bv.w;
            ca2.x += av.z * bv.x; ca2.y += av.z * bv.y; ca2.z += av.z * bv.z; ca2.w += av.z * bv.w;
            ca3.x += av.w * bv.x; ca3.y += av.w * bv.y; ca3.z += av.w * bv.z; ca3.w += av.w * bv.w;
        }
    }
    float4 bv4 = {0, 0, 0, 0};
    if (bias) bv4 = *(const float4*)&bias[nb + tn * 4];
#define CST(I, CV) { \
    float4 v; v.x = CV.x + bv4.x; v.y = CV.y + bv4.y; v.z = CV.z + bv4.z; v.w = CV.w + bv4.w; \
    if (dorelu) { v.x = fmaxf(v.x, 0.f); v.y = fmaxf(v.y, 0.f); v.z = fmaxf(v.z, 0.f); v.w = fmaxf(v.w, 0.f); } \
    *(float4*)&C[(size_t)(mb + tm * 4 + (I)) * N + nb + tn * 4] = v; }
    CST(0, ca0) CST(1, ca1) CST(2, ca2) CST(3, ca3)
#undef CST
}

// ---------------------------------------------------------------------------
// Edge scatters for graph-level convs (aggregate-first: scatter the INPUT,
// then GEMM). 128-wide: 8 edges/block; 256-wide: 4 edges/block.
// ---------------------------------------------------------------------------
__global__ void k_scatter128(const int* __restrict__ pe, const float* __restrict__ dinv,
                             const float* __restrict__ src_arr, float* __restrict__ agg) {
    int d = threadIdx.x & 127, sub = threadIdx.x >> 7;
#pragma unroll
    for (int q = 0; q < 4; ++q) {
        int e = blockIdx.x * 8 + q * 2 + sub;
        int s = pe[e], dd = pe[EP + e];
        float nrm = dinv[s] * dinv[dd];
        atomicAdd(&agg[(size_t)dd * 128 + d], src_arr[(size_t)s * 128 + d] * nrm);
    }
}

__global__ void k_scatter256(const int* __restrict__ pe, const float* __restrict__ dinv,
                             const float* __restrict__ src_arr, float* __restrict__ agg) {
    int t = threadIdx.x;
#pragma unroll
    for (int q = 0; q < 4; ++q) {
        int e = blockIdx.x * 4 + q;
        int s = pe[e], d = pe[EP + e];
        float nrm = dinv[s] * dinv[d];
        atomicAdd(&agg[(size_t)d * 256 + t], src_arr[(size_t)s * 256 + t] * nrm);
    }
}

// dst[idx] += src[idx] * dinv[idx>>shift]^2  (self-loop term)
__global__ void k_fin_axpy(const float* __restrict__ s, const float* __restrict__ dinv,
                           float* __restrict__ d, int shift) {
    int idx = blockIdx.x * 256 + threadIdx.x;
    float dv = dinv[idx >> shift];
    d[idx] += s[idx] * dv * dv;
}

// z = mu + eps*exp(min(ls,10)); zc = [emb, z]; per-graph KL partial
__global__ void k_fin_z(const float* __restrict__ mu_arr, const float* __restrict__ ls_arr,
                        const float* __restrict__ eps, const float* __restrict__ emb,
                        float* __restrict__ zc, float* __restrict__ klp) {
    __shared__ float smw[2];
    int g = blockIdx.x, d = threadIdx.x;  // 128 threads
    int idx = g * 128 + d;
    float mu = mu_arr[idx];
    float ls = fminf(ls_arr[idx], 10.0f);
    float z = mu + eps[idx] * expf(ls);
    zc[(size_t)g * 256 + d] = emb[idx];
    zc[(size_t)g * 256 + 128 + d] = z;
    float term = 1.0f + 2.0f * ls - mu * mu - expf(2.0f * ls);
    for (int o = 32; o; o >>= 1) term += __shfl_down(term, o);
    if ((d & 63) == 0) smw[d >> 6] = term;
    __syncthreads();
    if (d == 0) klp[g] = smw[0] + smw[1];
}

// Edge predictions: sigmoid(dot(Arow[src], Brow[dst])) + per-block log partial
__global__ void k_pred(const float* __restrict__ A, const float* __restrict__ B,
                       const int* __restrict__ pos, const int* __restrict__ neg,
                       float* __restrict__ out, float* __restrict__ predp) {
    __shared__ float smw[4];
    int t = threadIdx.x, w = t >> 6, l = t & 63;
    int eg = blockIdx.x * 4 + w;
    int isneg = eg >= EP;
    int e = eg - (isneg ? EP : 0);
    const int* eix = isneg ? neg : pos;
    int s = eix[e], d = eix[EP + e];
    const float4* Ar = (const float4*)(A + (size_t)s * 256);
    const float4* Br = (const float4*)(B + (size_t)d * 256);
    float4 av = Ar[l], bv = Br[l];
    float dot = av.x * bv.x + av.y * bv.y + av.z * bv.z + av.w * bv.w;
    for (int o = 32; o; o >>= 1) dot += __shfl_down(dot, o);
    if (l == 0) {
        float p = 1.0f / (1.0f + expf(-dot));
        float term;
        if (isneg) { out[2 + EP + e] = p; term = logf(1.0f - p + 1e-15f); }
        else       { out[2 + e] = p;      term = logf(p + 1e-15f); }
        smw[w] = term;
    }
    __syncthreads();
    if (t == 0) predp[blockIdx.x] = smw[0] + smw[1] + smw[2] + smw[3];
}

// Final scalar reductions
__global__ void k_final(const float* __restrict__ pens, const float* __restrict__ klp,
                        const float* __restrict__ predp, float* __restrict__ out) {
    __shared__ float sm[16];
    int t = threadIdx.x;
    float s_pen = 0.f, s_kl = 0.f, s_pos = 0.f, s_neg = 0.f;
    for (int i = t; i < 4096; i += 256) { s_pen += pens[i]; s_kl += klp[i]; }
    for (int i = t; i < 8192; i += 256) { s_pos += predp[i]; s_neg += predp[8192 + i]; }
    for (int o = 32; o; o >>= 1) {
        s_pen += __shfl_down(s_pen, o); s_kl += __shfl_down(s_kl, o);
        s_pos += __shfl_down(s_pos, o); s_neg += __shfl_down(s_neg, o);
    }
    int w = t >> 6;
    if ((t & 63) == 0) { sm[w] = s_pen; sm[4 + w] = s_kl; sm[8 + w] = s_pos; sm[12 + w] = s_neg; }
    __syncthreads();
    if (t == 0) {
        float pen = sm[0] + sm[1] + sm[2] + sm[3];
        float kls = sm[4] + sm[5] + sm[6] + sm[7];
        float pos = sm[8] + sm[9] + sm[10] + sm[11];
        float neg = sm[12] + sm[13] + sm[14] + sm[15];
        float rec = -(pos / 32768.0f) - (neg / 32768.0f);
        out[0] = rec - 0.5f * kls / (4096.0f * 4096.0f);  // rec + kl/G, kl = -0.5*kls/G
        out[1] = pen * (1.0f / 4096.0f);
    }
}

extern "C" void kernel_launch(void* const* d_in, const int* in_sizes, int n_in,
                              void* d_out, int out_size, void* d_ws, size_t ws_size,
                              hipStream_t stream) {
    const float* x   = (const float*)d_in[0];
    const int*   ei  = (const int*)d_in[1];
    const float* ew  = (const float*)d_in[2];
    const int*   pos = (const int*)d_in[3];
    const int*   neg = (const int*)d_in[4];
    const float* eps = (const float*)d_in[5];
    const float* Wg  = (const float*)d_in[6];
    const float* bg  = (const float*)d_in[7];
    const float* Wf1 = (const float*)d_in[8];
    const float* bf1 = (const float*)d_in[9];
    const float* Wf2 = (const float*)d_in[10];
    const float* bf2 = (const float*)d_in[11];
    const float* Wc1 = (const float*)d_in[12];
    const float* bc1 = (const float*)d_in[13];
    const float* Wmu = (const float*)d_in[14];
    const float* bmu = (const float*)d_in[15];
    const float* Wls = (const float*)d_in[16];
    const float* bls = (const float*)d_in[17];
    const float* emb = (const float*)d_in[18];
    const float* Wl1 = (const float*)d_in[19];
    const float* bl1 = (const float*)d_in[20];
    const float* Wl2 = (const float*)d_in[21];
    const float* bl2 = (const float*)d_in[22];
    float* out = (float*)d_out;
    float* ws  = (float*)d_ws;

    // Workspace layout (floats), ~30.5 MB
    float* g_embs = ws + 0;         // 524288
    float* deg    = ws + 524288;    // 4096
    float* dinv   = ws + 528384;    // 4096
    float* Qh     = ws + 532480;    // 262144
    float* ga     = ws + 794624;    // 524288  (A_norm-aggregated g_embs)
    float* h      = ws + 1318912;   // 1048576
    float* ha     = ws + 2367488;   // 1048576 (A_norm-aggregated h)
    float* mu_arr = ws + 3416064;   // 524288
    float* ls_arr = ws + 3940352;   // 524288
    float* zc     = ws + 4464640;   // 1048576
    float* Abuf   = ws + 5513216;   // 1048576
    float* Bbuf   = ws + 6561792;   // 1048576
    float* pens   = ws + 7610368;   // 4096
    float* klp    = ws + 7614464;   // 4096
    float* predp  = ws + 7618560;   // 16384
    float* Wgf1   = ws + 7634944;   // 1024
    float* bcomb  = ws + 7635968;   // 16
    float* bg32   = ws + 7635984;   // 128

    // Zero scatter accumulators (ws re-poisoned 0xAA before every call)
    hipMemsetAsync(deg, 0, 4096u * 4, stream);
    hipMemsetAsync(ga,  0, 524288u * 4, stream);
    hipMemsetAsync(ha,  0, 1048576u * 4, stream);

    // Prep + per-graph stage
    k_prep<<<1, 256, 0, stream>>>(Wg, Wf1, bf1, bg, Wgf1, bcomb, bg32);
    k_pg<<<GG, 256, 0, stream>>>(x, ei, ew, Wgf1, bcomb, Wf2, bf2, Qh, pens);
    // g_embs = Qh @ Wg + 32*bg   [4096x64 @ 64x128]
    k_gemm<<<dim3(64, 2), 256, 0, stream>>>(Qh, Wg, bg32, g_embs,
                                            nullptr, nullptr, nullptr, GG, 64, 128, 0);

    // Graph-level VGAE (aggregate-first on every conv)
    k_deg<<<EP / 256, 256, 0, stream>>>(pos + EP, deg);
    k_dinv<<<GG / 256, 256, 0, stream>>>(deg, dinv);

    // h = relu((A g_embs) @ Wc1 + bc1)
    k_scatter128<<<EP / 8, 256, 0, stream>>>(pos, dinv, g_embs, ga);
    k_fin_axpy<<<2048, 256, 0, stream>>>(g_embs, dinv, ga, 7);
    k_gemm<<<dim3(64, 4), 256, 0, stream>>>(ga, Wc1, bc1, h,
                                            nullptr, nullptr, nullptr, GG, 128, 256, 1);

    // mu = (A h) @ Wmu + bmu ; ls = (A h) @ Wls + bls  (shared aggregation)
    k_scatter256<<<EP / 4, 256, 0, stream>>>(pos, dinv, h, ha);
    k_fin_axpy<<<4096, 256, 0, stream>>>(h, dinv, ha, 8);
    k_gemm<<<dim3(64, 4), 256, 0, stream>>>(ha, Wmu, bmu, mu_arr,
                                            Wls, bls, ls_arr, GG, 256, 128, 0);
    k_fin_z<<<GG, 128, 0, stream>>>(mu_arr, ls_arr, eps, emb, zc, klp);

    // A = zc@W_lin1+b, B = zc@W_lin2+b (per-node factorization of edge MLP)
    k_gemm<<<dim3(64, 8), 256, 0, stream>>>(zc, Wl1, bl1, Abuf,
                                            Wl2, bl2, Bbuf, GG, 256, 256, 0);

    // Edge predictions + scalars
    k_pred<<<(2 * EP) / 4, 256, 0, stream>>>(Abuf, Bbuf, pos, neg, out, predp);
    k_final<<<1, 256, 0, stream>>>(pens, klp, predp, out);
}

// Round 5
// 429.182 us; speedup vs baseline: 5.3689x; 1.8292x over previous
//
#include <hip/hip_runtime.h>
#include <hip/hip_bf16.h>
#include <math.h>

// Sizes (fixed by the reference)
#define GG   4096
#define NNODE 64
#define EEDGE 256
#define FFEAT 64
#define DDIM 128
#define EP   32768

// ---------------------------------------------------------------------------
// Prep (once per call, tiny): Wgf1 = Wg @ Wf1 [64x16],
// bcomb = bg @ Wf1 + bf1 [16], bg32 = 32*bg [128].
// ---------------------------------------------------------------------------
__global__ void k_prep(const float* __restrict__ Wg, const float* __restrict__ Wf1,
                       const float* __restrict__ bf1, const float* __restrict__ bg,
                       float* __restrict__ Wgf1, float* __restrict__ bcomb,
                       float* __restrict__ bg32) {
    int t = threadIdx.x;
    for (int o = t; o < 1024; o += 256) {
        int f = o >> 4, j = o & 15;
        float s = 0.f;
        for (int d = 0; d < 128; ++d) s += Wg[f * 128 + d] * Wf1[d * 16 + j];
        Wgf1[o] = s;
    }
    if (t < 16) {
        float s = bf1[t];
        for (int d = 0; d < 128; ++d) s += bg[d] * Wf1[d * 16 + t];
        bcomb[t] = s;
    }
    if (t >= 128) bg32[t - 128] = 32.0f * bg[t - 128];
}

// ---------------------------------------------------------------------------
// Per-graph kernel v2: CSR-GATHER, no feature-wide atomics, x staged once.
// Round-4 post-mortem: atomic-scatter version was latency-bound (VALUBusy 8%,
// HBM 1%): 64 serialized (LDS idx -> global x -> LDS atomic) chains/thread.
// Here: counting-sort edges by dst in LDS, then each thread owns
// (node, 16 features) and gathers over its ~4 in-edges with float4 LDS reads.
// LDS 51.3 KB -> 3 blocks/CU.
// ---------------------------------------------------------------------------
__global__ __launch_bounds__(256) void k_pg(
    const float* __restrict__ x, const int* __restrict__ ei, const float* __restrict__ ew,
    const float* __restrict__ Wgf1, const float* __restrict__ bcomb,
    const float* __restrict__ Wf2, const float* __restrict__ bf2,
    float* __restrict__ Qh, float* __restrict__ pens)
{
    __shared__ __align__(16) float sm[12816];
    float* xs    = sm;                    // 64x68 (stride 68 = 16B-aligned rows)
    float* xa    = sm + 4352;             // 64x68
    float* Wgf1s = sm + 8704;             // 1024
    float* a1s   = sm + 9728;             // 1024 (reused as Qh partials)
    int*   srcs  = (int*)(sm + 10752);    // 256
    int*   dsts  = (int*)(sm + 11008);    // 256
    float* lwx   = sm + 11264;            // 256: edge weight, then laplacian lw
    int*   lsrc  = (int*)(sm + 11520);    // 256 CSR src
    float* lnrm  = sm + 11776;            // 256 CSR norm
    int*   icnt  = (int*)(sm + 12032);    // 64
    int*   offs  = (int*)(sm + 12096);    // 64
    int*   curs  = (int*)(sm + 12160);    // 64
    float* degw  = sm + 12224;            // 64
    float* dinvs = sm + 12288;            // 64
    float* deg2s = sm + 12352;            // 64
    float* dinv2s= sm + 12416;            // 64
    float* Ss    = sm + 12480;            // 128
    float* Ssum  = sm + 12608;            // 64
    float* LSs   = sm + 12672;            // 128 (scatter-only part; identity added at use)
    float* bcs   = sm + 12800;            // 16

    const int g = blockIdx.x;
    const int t = threadIdx.x;
    const float* xg = x + (size_t)g * 4096;

    // P0: stage x, edges, weights; zero counters
    {
        const int* eg = ei + (size_t)g * 512;
        srcs[t] = eg[t];
        dsts[t] = eg[256 + t];
        lwx[t]  = ew[(size_t)g * 256 + t];
        for (int i = t; i < 1024; i += 256) {
            int n = i >> 4, k = (i & 15) * 4;
            *(float4*)&xs[n * 68 + k] = *(const float4*)&xg[n * 64 + k];
        }
        for (int i = t; i < 1024; i += 256) Wgf1s[i] = Wgf1[i];
        if (t < 16) bcs[t] = bcomb[t];
        if (t < 64) { icnt[t] = 0; degw[t] = 1.0f; deg2s[t] = 0.0f; }
        if (t < 128) LSs[t] = 0.0f;
    }
    __syncthreads();

    // P1: counts + weighted degrees (256 tiny LDS atomics each)
    {
        int dd = dsts[t], s = srcs[t];
        float w = lwx[t];
        atomicAdd(&icnt[dd], 1);
        atomicAdd(&degw[dd], w);
        atomicAdd(&deg2s[s], w);
    }
    __syncthreads();

    // P2: wave0 scans counts -> offsets; dinv
    if (t < 64) {
        int v = icnt[t], own = v;
        for (int o = 1; o < 64; o <<= 1) { int u = __shfl_up(v, o); if (t >= o) v += u; }
        int excl = v - own;
        offs[t] = excl; curs[t] = excl;
        dinvs[t] = rsqrtf(degw[t]);
        float dg = deg2s[t];
        dinv2s[t] = dg > 0.0f ? rsqrtf(fmaxf(dg, 1e-30f)) : 0.0f;
    }
    __syncthreads();

    // P3: place edges into CSR; precompute gcn norm and laplacian lw
    {
        int s = srcs[t], dd = dsts[t];
        float w = lwx[t];
        int pos = atomicAdd(&curs[dd], 1);
        lsrc[pos] = s;
        lnrm[pos] = dinvs[s] * w * dinvs[dd];
        lwx[t] = -dinv2s[s] * w * dinv2s[dd];
    }
    __syncthreads();

    // P4: gather xa[n] = x[n]*dinv^2 + sum_{e->n} x[src]*nrm  (no atomics)
    {
        int n = t >> 2, base = (t & 3) * 16;
        float sc = dinvs[n] * dinvs[n];
        const float* xrow = &xs[n * 68 + base];
        float4 A0 = *(const float4*)&xrow[0];
        float4 A1 = *(const float4*)&xrow[4];
        float4 A2 = *(const float4*)&xrow[8];
        float4 A3 = *(const float4*)&xrow[12];
        A0.x *= sc; A0.y *= sc; A0.z *= sc; A0.w *= sc;
        A1.x *= sc; A1.y *= sc; A1.z *= sc; A1.w *= sc;
        A2.x *= sc; A2.y *= sc; A2.z *= sc; A2.w *= sc;
        A3.x *= sc; A3.y *= sc; A3.z *= sc; A3.w *= sc;
        int o = offs[n], c = icnt[n];
        for (int j = 0; j < c; ++j) {
            int s = lsrc[o + j];
            float nm = lnrm[o + j];
            const float* xr = &xs[s * 68 + base];
            float4 X0 = *(const float4*)&xr[0];
            float4 X1 = *(const float4*)&xr[4];
            float4 X2 = *(const float4*)&xr[8];
            float4 X3 = *(const float4*)&xr[12];
            A0.x += X0.x * nm; A0.y += X0.y * nm; A0.z += X0.z * nm; A0.w += X0.w * nm;
            A1.x += X1.x * nm; A1.y += X1.y * nm; A1.z += X1.z * nm; A1.w += X1.w * nm;
            A2.x += X2.x * nm; A2.y += X2.y * nm; A2.z += X2.z * nm; A2.w += X2.w * nm;
            A3.x += X3.x * nm; A3.y += X3.y * nm; A3.z += X3.z * nm; A3.w += X3.w * nm;
        }
        float* xw = &xa[n * 68 + base];
        *(float4*)&xw[0]  = A0;
        *(float4*)&xw[4]  = A1;
        *(float4*)&xw[8]  = A2;
        *(float4*)&xw[12] = A3;
    }
    __syncthreads();

    // P5: a1 = tanh(xa @ Wgf1 + bcomb)  (64x64 @ 64x16)
    {
        int n = t >> 2, j0 = (t & 3) * 4;
        float a0 = bcs[j0], a1v = bcs[j0 + 1], a2 = bcs[j0 + 2], a3 = bcs[j0 + 3];
#pragma unroll 4
        for (int k4 = 0; k4 < 16; ++k4) {
            float4 hv = *(const float4*)&xa[n * 68 + k4 * 4];
            float4 w0 = *(const float4*)&Wgf1s[(k4 * 4 + 0) * 16 + j0];
            float4 w1 = *(const float4*)&Wgf1s[(k4 * 4 + 1) * 16 + j0];
            float4 w2 = *(const float4*)&Wgf1s[(k4 * 4 + 2) * 16 + j0];
            float4 w3 = *(const float4*)&Wgf1s[(k4 * 4 + 3) * 16 + j0];
            a0  += hv.x * w0.x + hv.y * w1.x + hv.z * w2.x + hv.w * w3.x;
            a1v += hv.x * w0.y + hv.y * w1.y + hv.z * w2.y + hv.w * w3.y;
            a2  += hv.x * w0.z + hv.y * w1.z + hv.z * w2.z + hv.w * w3.z;
            a3  += hv.x * w0.w + hv.y * w1.w + hv.z * w2.w + hv.w * w3.w;
        }
        a1s[n * 16 + j0]     = tanhf(a0);
        a1s[n * 16 + j0 + 1] = tanhf(a1v);
        a1s[n * 16 + j0 + 2] = tanhf(a2);
        a1s[n * 16 + j0 + 3] = tanhf(a3);
    }
    __syncthreads();

    // P6: S logits
    if (t < 128) {
        int n = t >> 1, kk = t & 1;
        float z = bf2[kk];
#pragma unroll
        for (int j = 0; j < 16; ++j) z += a1s[n * 16 + j] * Wf2[j * 2 + kk];
        Ss[n * 2 + kk] = z;
    }
    __syncthreads();

    // P7: softmax rows + row sums
    if (t < 64) {
        float z0 = Ss[t * 2], z1 = Ss[t * 2 + 1];
        float m = fmaxf(z0, z1);
        float e0 = expf(z0 - m), e1 = expf(z1 - m);
        float inv = 1.0f / (e0 + e1);
        e0 *= inv; e1 *= inv;
        Ss[t * 2] = e0; Ss[t * 2 + 1] = e1;
        Ssum[t] = e0 + e1;
    }
    __syncthreads();

    // P8: LS scatter part (identity added at use): 512 LDS atomics
    for (int i = t; i < 512; i += 256) {
        int e = i >> 1, kk = i & 1;
        atomicAdd(&LSs[srcs[e] * 2 + kk], lwx[e] * Ss[dsts[e] * 2 + kk]);
    }
    __syncthreads();

    // P9: penalty (wave0 reduce) + Qh partials (all threads)
    if (t < 64) {
        float s0 = Ss[t * 2], s1 = Ss[t * 2 + 1];
        float l0 = s0 + LSs[t * 2], l1 = s1 + LSs[t * 2 + 1];
        float p00 = s0 * l0, p01 = s0 * l1, p10 = s1 * l0, p11 = s1 * l1;
        for (int o = 32; o; o >>= 1) {
            p00 += __shfl_down(p00, o); p01 += __shfl_down(p01, o);
            p10 += __shfl_down(p10, o); p11 += __shfl_down(p11, o);
        }
        if (t == 0) {
            float r0 = fmaxf(fabsf(p00) + fabsf(p01), 1e-12f);
            float r1 = fmaxf(fabsf(p10) + fabsf(p11), 1e-12f);
            float d0 = p00 / r0 - 1.0f, d1 = p11 / r1 - 1.0f;
            pens[g] = 0.5f * (d0 * d0 + d1 * d1);
        }
    }
    {   // Qh partial: thread (k = t&63, p = t>>6) sums 16 nodes
        int k = t & 63, p = t >> 6;
        float qk = 0.f;
#pragma unroll 4
        for (int n = p * 16; n < p * 16 + 16; ++n)
            qk += Ssum[n] * xa[n * 68 + k];
        __syncthreads();               // a1s reads (P6) done; reuse as partials
        a1s[p * 64 + k] = qk;
    }
    __syncthreads();
    if (t < 64)
        Qh[(size_t)g * 64 + t] = 0.5f * (a1s[t] + a1s[64 + t] + a1s[128 + t] + a1s[192 + t]);
}

// ---------------------------------------------------------------------------
// Global CSR build over pos_edges (dst-keyed): count, scan, place.
// ---------------------------------------------------------------------------
__global__ void k_cnt(const int* __restrict__ pd, int* __restrict__ icnt) {
    int e = blockIdx.x * 256 + threadIdx.x;
    atomicAdd(&icnt[pd[e]], 1);
}

__global__ void k_dinv(const int* __restrict__ icnt, float* __restrict__ dinv) {
    int i = blockIdx.x * 256 + threadIdx.x;
    dinv[i] = rsqrtf((float)icnt[i] + 1.0f);
}

// Single block scans 4096 counts -> exclusive offsets (and cursor copy)
__global__ void k_scan(const int* __restrict__ icnt, int* __restrict__ offs,
                       int* __restrict__ curs) {
    __shared__ int wsum[4];
    int t = threadIdx.x;
    int base = t * 16;
    int l0,l1,l2,l3,l4,l5,l6,l7,l8,l9,l10,l11,l12,l13,l14,l15;
    l0=icnt[base+0]; l1=icnt[base+1]; l2=icnt[base+2]; l3=icnt[base+3];
    l4=icnt[base+4]; l5=icnt[base+5]; l6=icnt[base+6]; l7=icnt[base+7];
    l8=icnt[base+8]; l9=icnt[base+9]; l10=icnt[base+10]; l11=icnt[base+11];
    l12=icnt[base+12]; l13=icnt[base+13]; l14=icnt[base+14]; l15=icnt[base+15];
    int s = l0+l1+l2+l3+l4+l5+l6+l7+l8+l9+l10+l11+l12+l13+l14+l15;
    int lane = t & 63, w = t >> 6;
    int v = s;
    for (int o = 1; o < 64; o <<= 1) { int u = __shfl_up(v, o); if (lane >= o) v += u; }
    if (lane == 63) wsum[w] = v;
    __syncthreads();
    int woff = 0;
    for (int i = 0; i < 4; ++i) if (i < w) woff += wsum[i];
    int run = woff + v - s;
#define SC(L, I) offs[base+(I)] = run; curs[base+(I)] = run; run += L;
    SC(l0,0) SC(l1,1) SC(l2,2) SC(l3,3) SC(l4,4) SC(l5,5) SC(l6,6) SC(l7,7)
    SC(l8,8) SC(l9,9) SC(l10,10) SC(l11,11) SC(l12,12) SC(l13,13) SC(l14,14) SC(l15,15)
#undef SC
}

__global__ void k_place(const int* __restrict__ pe, const float* __restrict__ dinv,
                        int* __restrict__ curs, int* __restrict__ csr_src,
                        float* __restrict__ csr_nrm) {
    int e = blockIdx.x * 256 + threadIdx.x;
    int s = pe[e], d = pe[EP + e];
    int pos = atomicAdd(&curs[d], 1);
    csr_src[pos] = s;
    csr_nrm[pos] = dinv[s] * dinv[d];
}

// ---------------------------------------------------------------------------
// CSR gathers (replace global-atomic scatters): out[g] = in[g]*dinv[g]^2 +
// sum_{edges->g} in[src]*nrm. No atomics, no pre-zeroing.
// ---------------------------------------------------------------------------
__global__ void k_gather128(const int* __restrict__ offs, const int* __restrict__ icnt,
                            const int* __restrict__ csr_src, const float* __restrict__ csr_nrm,
                            const float* __restrict__ dinv, const float* __restrict__ in,
                            float* __restrict__ out) {
    int g = blockIdx.x, d = threadIdx.x;  // 128 threads
    float dv = dinv[g];
    float acc = in[(size_t)g * 128 + d] * dv * dv;
    int o = offs[g], c = icnt[g];
    for (int j = 0; j < c; ++j)
        acc += in[(size_t)csr_src[o + j] * 128 + d] * csr_nrm[o + j];
    out[(size_t)g * 128 + d] = acc;
}

__global__ void k_gather256(const int* __restrict__ offs, const int* __restrict__ icnt,
                            const int* __restrict__ csr_src, const float* __restrict__ csr_nrm,
                            const float* __restrict__ dinv, const float* __restrict__ in,
                            float* __restrict__ out) {
    int g = blockIdx.x, d = threadIdx.x;  // 256 threads
    float dv = dinv[g];
    float acc = in[(size_t)g * 256 + d] * dv * dv;
    int o = offs[g], c = icnt[g];
    for (int j = 0; j < c; ++j)
        acc += in[(size_t)csr_src[o + j] * 256 + d] * csr_nrm[o + j];
    out[(size_t)g * 256 + d] = acc;
}

// ---------------------------------------------------------------------------
// Generic tiled fp32 GEMM: C = A[MxK] @ B[KxN] (+bias, optional relu).
// Optional second output (shared A): blockIdx.y >= gridDim.y/2 uses B1/bias1/C1.
// ---------------------------------------------------------------------------
__global__ __launch_bounds__(256) void k_gemm(
    const float* __restrict__ A,
    const float* __restrict__ B0, const float* __restrict__ bias0, float* __restrict__ C0,
    const float* __restrict__ B1, const float* __restrict__ bias1, float* __restrict__ C1,
    int M, int K, int N, int dorelu)
{
    __shared__ __align__(16) float At[32 * 68];
    __shared__ __align__(16) float Bs[32 * 68];
    const float* B = B0; const float* bias = bias0; float* C = C0;
    int by = blockIdx.y;
    if (B1 != nullptr && by >= (int)(gridDim.y >> 1)) {
        B = B1; bias = bias1; C = C1; by -= (gridDim.y >> 1);
    }
    const int mb = blockIdx.x * 64, nb = by * 64;
    const int t = threadIdx.x;
    const int tm = t >> 4, tn = t & 15;
    float4 ca0 = {0,0,0,0}, ca1 = {0,0,0,0}, ca2 = {0,0,0,0}, ca3 = {0,0,0,0};
    for (int k0 = 0; k0 < K; k0 += 32) {
        __syncthreads();
        for (int i = t; i < 2048; i += 256) {
            int m = i >> 5, k = i & 31;
            At[k * 68 + m] = A[(size_t)(mb + m) * K + k0 + k];
        }
        for (int i = t; i < 2048; i += 256) {
            int k = i >> 6, n = i & 63;
            Bs[k * 68 + n] = B[(size_t)(k0 + k) * N + nb + n];
        }
        __syncthreads();
#pragma unroll
        for (int k = 0; k < 32; ++k) {
            float4 av = *(const float4*)&At[k * 68 + tm * 4];
            float4 bv = *(const float4*)&Bs[k * 68 + tn * 4];
            ca0.x += av.x * bv.x; ca0.y += av.x * bv.y; ca0.z += av.x * bv.z; ca0.w += av.x * bv.w;
            ca1.x += av.y * bv.x; ca1.y += av.y * bv.y; ca1.z += av.y * bv.z; ca1.w += av.y * bv.w;
            ca2.x += av.z * bv.x; ca2.y += av.z * bv.y; ca2.z += av.z * bv.z; ca2.w += av.z * bv.w;
            ca3.x += av.w * bv.x; ca3.y += av.w * bv.y; ca3.z += av.w * bv.z; ca3.w += av.w * bv.w;
        }
    }
    float4 bv4 = {0, 0, 0, 0};
    if (bias) bv4 = *(const float4*)&bias[nb + tn * 4];
#define CST(I, CV) { \
    float4 v; v.x = CV.x + bv4.x; v.y = CV.y + bv4.y; v.z = CV.z + bv4.z; v.w = CV.w + bv4.w; \
    if (dorelu) { v.x = fmaxf(v.x, 0.f); v.y = fmaxf(v.y, 0.f); v.z = fmaxf(v.z, 0.f); v.w = fmaxf(v.w, 0.f); } \
    *(float4*)&C[(size_t)(mb + tm * 4 + (I)) * N + nb + tn * 4] = v; }
    CST(0, ca0) CST(1, ca1) CST(2, ca2) CST(3, ca3)
#undef CST
}

// z = mu + eps*exp(min(ls,10)); zc = [emb, z]; per-graph KL partial
__global__ void k_fin_z(const float* __restrict__ mu_arr, const float* __restrict__ ls_arr,
                        const float* __restrict__ eps, const float* __restrict__ emb,
                        float* __restrict__ zc, float* __restrict__ klp) {
    __shared__ float smw[2];
    int g = blockIdx.x, d = threadIdx.x;  // 128 threads
    int idx = g * 128 + d;
    float mu = mu_arr[idx];
    float ls = fminf(ls_arr[idx], 10.0f);
    float z = mu + eps[idx] * expf(ls);
    zc[(size_t)g * 256 + d] = emb[idx];
    zc[(size_t)g * 256 + 128 + d] = z;
    float term = 1.0f + 2.0f * ls - mu * mu - expf(2.0f * ls);
    for (int o = 32; o; o >>= 1) term += __shfl_down(term, o);
    if ((d & 63) == 0) smw[d >> 6] = term;
    __syncthreads();
    if (d == 0) klp[g] = smw[0] + smw[1];
}

// Edge predictions: sigmoid(dot(Arow[src], Brow[dst])) + per-block log partial
__global__ void k_pred(const float* __restrict__ A, const float* __restrict__ B,
                       const int* __restrict__ pos, const int* __restrict__ neg,
                       float* __restrict__ out, float* __restrict__ predp) {
    __shared__ float smw[4];
    int t = threadIdx.x, w = t >> 6, l = t & 63;
    int eg = blockIdx.x * 4 + w;
    int isneg = eg >= EP;
    int e = eg - (isneg ? EP : 0);
    const int* eix = isneg ? neg : pos;
    int s = eix[e], d = eix[EP + e];
    const float4* Ar = (const float4*)(A + (size_t)s * 256);
    const float4* Br = (const float4*)(B + (size_t)d * 256);
    float4 av = Ar[l], bv = Br[l];
    float dot = av.x * bv.x + av.y * bv.y + av.z * bv.z + av.w * bv.w;
    for (int o = 32; o; o >>= 1) dot += __shfl_down(dot, o);
    if (l == 0) {
        float p = 1.0f / (1.0f + expf(-dot));
        float term;
        if (isneg) { out[2 + EP + e] = p; term = logf(1.0f - p + 1e-15f); }
        else       { out[2 + e] = p;      term = logf(p + 1e-15f); }
        smw[w] = term;
    }
    __syncthreads();
    if (t == 0) predp[blockIdx.x] = smw[0] + smw[1] + smw[2] + smw[3];
}

// Final scalar reductions
__global__ void k_final(const float* __restrict__ pens, const float* __restrict__ klp,
                        const float* __restrict__ predp, float* __restrict__ out) {
    __shared__ float sm[16];
    int t = threadIdx.x;
    float s_pen = 0.f, s_kl = 0.f, s_pos = 0.f, s_neg = 0.f;
    for (int i = t; i < 4096; i += 256) { s_pen += pens[i]; s_kl += klp[i]; }
    for (int i = t; i < 8192; i += 256) { s_pos += predp[i]; s_neg += predp[8192 + i]; }
    for (int o = 32; o; o >>= 1) {
        s_pen += __shfl_down(s_pen, o); s_kl += __shfl_down(s_kl, o);
        s_pos += __shfl_down(s_pos, o); s_neg += __shfl_down(s_neg, o);
    }
    int w = t >> 6;
    if ((t & 63) == 0) { sm[w] = s_pen; sm[4 + w] = s_kl; sm[8 + w] = s_pos; sm[12 + w] = s_neg; }
    __syncthreads();
    if (t == 0) {
        float pen = sm[0] + sm[1] + sm[2] + sm[3];
        float kls = sm[4] + sm[5] + sm[6] + sm[7];
        float pos = sm[8] + sm[9] + sm[10] + sm[11];
        float neg = sm[12] + sm[13] + sm[14] + sm[15];
        float rec = -(pos / 32768.0f) - (neg / 32768.0f);
        out[0] = rec - 0.5f * kls / (4096.0f * 4096.0f);
        out[1] = pen * (1.0f / 4096.0f);
    }
}

extern "C" void kernel_launch(void* const* d_in, const int* in_sizes, int n_in,
                              void* d_out, int out_size, void* d_ws, size_t ws_size,
                              hipStream_t stream) {
    const float* x   = (const float*)d_in[0];
    const int*   ei  = (const int*)d_in[1];
    const float* ew  = (const float*)d_in[2];
    const int*   pos = (const int*)d_in[3];
    const int*   neg = (const int*)d_in[4];
    const float* eps = (const float*)d_in[5];
    const float* Wg  = (const float*)d_in[6];
    const float* bg  = (const float*)d_in[7];
    const float* Wf1 = (const float*)d_in[8];
    const float* bf1 = (const float*)d_in[9];
    const float* Wf2 = (const float*)d_in[10];
    const float* bf2 = (const float*)d_in[11];
    const float* Wc1 = (const float*)d_in[12];
    const float* bc1 = (const float*)d_in[13];
    const float* Wmu = (const float*)d_in[14];
    const float* bmu = (const float*)d_in[15];
    const float* Wls = (const float*)d_in[16];
    const float* bls = (const float*)d_in[17];
    const float* emb = (const float*)d_in[18];
    const float* Wl1 = (const float*)d_in[19];
    const float* bl1 = (const float*)d_in[20];
    const float* Wl2 = (const float*)d_in[21];
    const float* bl2 = (const float*)d_in[22];
    float* out = (float*)d_out;
    float* ws  = (float*)d_ws;

    // Workspace layout (floats), ~30.8 MB
    float* g_embs  = ws + 0;         // 524288
    float* dinv    = ws + 524288;    // 4096
    int*   icnt_g  = (int*)(ws + 528384);  // 4096
    int*   off_g   = (int*)(ws + 532480);  // 4096
    int*   cur_g   = (int*)(ws + 536576);  // 4096
    int*   csr_src = (int*)(ws + 540672);  // 32768
    float* csr_nrm = ws + 573440;    // 32768
    float* Qh      = ws + 606208;    // 262144
    float* ga      = ws + 868352;    // 524288
    float* h       = ws + 1392640;   // 1048576
    float* ha      = ws + 2441216;   // 1048576
    float* mu_arr  = ws + 3489792;   // 524288
    float* ls_arr  = ws + 4014080;   // 524288
    float* zc      = ws + 4538368;   // 1048576
    float* Abuf    = ws + 5586944;   // 1048576
    float* Bbuf    = ws + 6635520;   // 1048576
    float* pens    = ws + 7684096;   // 4096
    float* klp     = ws + 7688192;   // 4096
    float* predp   = ws + 7692288;   // 16384
    float* Wgf1    = ws + 7708672;   // 1024
    float* bcomb   = ws + 7709696;   // 16
    float* bg32    = ws + 7709712;   // 128

    // Only the global CSR counter needs zeroing now (16 KB)
    hipMemsetAsync(icnt_g, 0, 4096u * 4, stream);

    // Prep + per-graph stage
    k_prep<<<1, 256, 0, stream>>>(Wg, Wf1, bf1, bg, Wgf1, bcomb, bg32);
    k_pg<<<GG, 256, 0, stream>>>(x, ei, ew, Wgf1, bcomb, Wf2, bf2, Qh, pens);
    // g_embs = Qh @ Wg + 32*bg
    k_gemm<<<dim3(64, 2), 256, 0, stream>>>(Qh, Wg, bg32, g_embs,
                                            nullptr, nullptr, nullptr, GG, 64, 128, 0);

    // Global CSR over pos_edges (dst-keyed)
    k_cnt<<<EP / 256, 256, 0, stream>>>(pos + EP, icnt_g);
    k_dinv<<<GG / 256, 256, 0, stream>>>(icnt_g, dinv);
    k_scan<<<1, 256, 0, stream>>>(icnt_g, off_g, cur_g);
    k_place<<<EP / 256, 256, 0, stream>>>(pos, dinv, cur_g, csr_src, csr_nrm);

    // h = relu((A g_embs) @ Wc1 + bc1)   — gather, no atomics
    k_gather128<<<GG, 128, 0, stream>>>(off_g, icnt_g, csr_src, csr_nrm, dinv, g_embs, ga);
    k_gemm<<<dim3(64, 4), 256, 0, stream>>>(ga, Wc1, bc1, h,
                                            nullptr, nullptr, nullptr, GG, 128, 256, 1);

    // mu/ls = (A h) @ {Wmu,Wls} + {bmu,bls}  — shared gather
    k_gather256<<<GG, 256, 0, stream>>>(off_g, icnt_g, csr_src, csr_nrm, dinv, h, ha);
    k_gemm<<<dim3(64, 4), 256, 0, stream>>>(ha, Wmu, bmu, mu_arr,
                                            Wls, bls, ls_arr, GG, 256, 128, 0);
    k_fin_z<<<GG, 128, 0, stream>>>(mu_arr, ls_arr, eps, emb, zc, klp);

    // A = zc@W_lin1+b, B = zc@W_lin2+b
    k_gemm<<<dim3(64, 8), 256, 0, stream>>>(zc, Wl1, bl1, Abuf,
                                            Wl2, bl2, Bbuf, GG, 256, 256, 0);

    // Edge predictions + scalars
    k_pred<<<(2 * EP) / 4, 256, 0, stream>>>(Abuf, Bbuf, pos, neg, out, predp);
    k_final<<<1, 256, 0, stream>>>(pens, klp, predp, out);
}

// Round 6
// 418.206 us; speedup vs baseline: 5.5098x; 1.0262x over previous
//
#include <hip/hip_runtime.h>
#include <hip/hip_bf16.h>
#include <math.h>

// Sizes (fixed by the reference)
#define GG   4096
#define NNODE 64
#define EEDGE 256
#define FFEAT 64
#define DDIM 128
#define EP   32768

// ---------------------------------------------------------------------------
// Prep (once per call, tiny): Wgf1 = Wg @ Wf1 [64x16],
// bcomb = bg @ Wf1 + bf1 [16], bg32 = 32*bg [128].
// ---------------------------------------------------------------------------
__global__ void k_prep(const float* __restrict__ Wg, const float* __restrict__ Wf1,
                       const float* __restrict__ bf1, const float* __restrict__ bg,
                       float* __restrict__ Wgf1, float* __restrict__ bcomb,
                       float* __restrict__ bg32) {
    int t = threadIdx.x;
    for (int o = t; o < 1024; o += 256) {
        int f = o >> 4, j = o & 15;
        float s = 0.f;
        for (int d = 0; d < 128; ++d) s += Wg[f * 128 + d] * Wf1[d * 16 + j];
        Wgf1[o] = s;
    }
    if (t < 16) {
        float s = bf1[t];
        for (int d = 0; d < 128; ++d) s += bg[d] * Wf1[d * 16 + t];
        bcomb[t] = s;
    }
    if (t >= 128) bg32[t - 128] = 32.0f * bg[t - 128];
}

// ---------------------------------------------------------------------------
// Per-graph kernel (CSR-gather version; unchanged from round 5).
// ---------------------------------------------------------------------------
__global__ __launch_bounds__(256) void k_pg(
    const float* __restrict__ x, const int* __restrict__ ei, const float* __restrict__ ew,
    const float* __restrict__ Wgf1, const float* __restrict__ bcomb,
    const float* __restrict__ Wf2, const float* __restrict__ bf2,
    float* __restrict__ Qh, float* __restrict__ pens)
{
    __shared__ __align__(16) float sm[12816];
    float* xs    = sm;                    // 64x68
    float* xa    = sm + 4352;             // 64x68
    float* Wgf1s = sm + 8704;             // 1024
    float* a1s   = sm + 9728;             // 1024 (reused as Qh partials)
    int*   srcs  = (int*)(sm + 10752);    // 256
    int*   dsts  = (int*)(sm + 11008);    // 256
    float* lwx   = sm + 11264;            // 256
    int*   lsrc  = (int*)(sm + 11520);    // 256 CSR src
    float* lnrm  = sm + 11776;            // 256 CSR norm
    int*   icnt  = (int*)(sm + 12032);    // 64
    int*   offs  = (int*)(sm + 12096);    // 64
    int*   curs  = (int*)(sm + 12160);    // 64
    float* degw  = sm + 12224;            // 64
    float* dinvs = sm + 12288;            // 64
    float* deg2s = sm + 12352;            // 64
    float* dinv2s= sm + 12416;            // 64
    float* Ss    = sm + 12480;            // 128
    float* Ssum  = sm + 12608;            // 64
    float* LSs   = sm + 12672;            // 128
    float* bcs   = sm + 12800;            // 16

    const int g = blockIdx.x;
    const int t = threadIdx.x;
    const float* xg = x + (size_t)g * 4096;

    {
        const int* eg = ei + (size_t)g * 512;
        srcs[t] = eg[t];
        dsts[t] = eg[256 + t];
        lwx[t]  = ew[(size_t)g * 256 + t];
        for (int i = t; i < 1024; i += 256) {
            int n = i >> 4, k = (i & 15) * 4;
            *(float4*)&xs[n * 68 + k] = *(const float4*)&xg[n * 64 + k];
        }
        for (int i = t; i < 1024; i += 256) Wgf1s[i] = Wgf1[i];
        if (t < 16) bcs[t] = bcomb[t];
        if (t < 64) { icnt[t] = 0; degw[t] = 1.0f; deg2s[t] = 0.0f; }
        if (t < 128) LSs[t] = 0.0f;
    }
    __syncthreads();

    {
        int dd = dsts[t], s = srcs[t];
        float w = lwx[t];
        atomicAdd(&icnt[dd], 1);
        atomicAdd(&degw[dd], w);
        atomicAdd(&deg2s[s], w);
    }
    __syncthreads();

    if (t < 64) {
        int v = icnt[t], own = v;
        for (int o = 1; o < 64; o <<= 1) { int u = __shfl_up(v, o); if (t >= o) v += u; }
        int excl = v - own;
        offs[t] = excl; curs[t] = excl;
        dinvs[t] = rsqrtf(degw[t]);
        float dg = deg2s[t];
        dinv2s[t] = dg > 0.0f ? rsqrtf(fmaxf(dg, 1e-30f)) : 0.0f;
    }
    __syncthreads();

    {
        int s = srcs[t], dd = dsts[t];
        float w = lwx[t];
        int pos = atomicAdd(&curs[dd], 1);
        lsrc[pos] = s;
        lnrm[pos] = dinvs[s] * w * dinvs[dd];
        lwx[t] = -dinv2s[s] * w * dinv2s[dd];
    }
    __syncthreads();

    {
        int n = t >> 2, base = (t & 3) * 16;
        float sc = dinvs[n] * dinvs[n];
        const float* xrow = &xs[n * 68 + base];
        float4 A0 = *(const float4*)&xrow[0];
        float4 A1 = *(const float4*)&xrow[4];
        float4 A2 = *(const float4*)&xrow[8];
        float4 A3 = *(const float4*)&xrow[12];
        A0.x *= sc; A0.y *= sc; A0.z *= sc; A0.w *= sc;
        A1.x *= sc; A1.y *= sc; A1.z *= sc; A1.w *= sc;
        A2.x *= sc; A2.y *= sc; A2.z *= sc; A2.w *= sc;
        A3.x *= sc; A3.y *= sc; A3.z *= sc; A3.w *= sc;
        int o = offs[n], c = icnt[n];
        for (int j = 0; j < c; ++j) {
            int s = lsrc[o + j];
            float nm = lnrm[o + j];
            const float* xr = &xs[s * 68 + base];
            float4 X0 = *(const float4*)&xr[0];
            float4 X1 = *(const float4*)&xr[4];
            float4 X2 = *(const float4*)&xr[8];
            float4 X3 = *(const float4*)&xr[12];
            A0.x += X0.x * nm; A0.y += X0.y * nm; A0.z += X0.z * nm; A0.w += X0.w * nm;
            A1.x += X1.x * nm; A1.y += X1.y * nm; A1.z += X1.z * nm; A1.w += X1.w * nm;
            A2.x += X2.x * nm; A2.y += X2.y * nm; A2.z += X2.z * nm; A2.w += X2.w * nm;
            A3.x += X3.x * nm; A3.y += X3.y * nm; A3.z += X3.z * nm; A3.w += X3.w * nm;
        }
        float* xw = &xa[n * 68 + base];
        *(float4*)&xw[0]  = A0;
        *(float4*)&xw[4]  = A1;
        *(float4*)&xw[8]  = A2;
        *(float4*)&xw[12] = A3;
    }
    __syncthreads();

    {
        int n = t >> 2, j0 = (t & 3) * 4;
        float a0 = bcs[j0], a1v = bcs[j0 + 1], a2 = bcs[j0 + 2], a3 = bcs[j0 + 3];
#pragma unroll 4
        for (int k4 = 0; k4 < 16; ++k4) {
            float4 hv = *(const float4*)&xa[n * 68 + k4 * 4];
            float4 w0 = *(const float4*)&Wgf1s[(k4 * 4 + 0) * 16 + j0];
            float4 w1 = *(const float4*)&Wgf1s[(k4 * 4 + 1) * 16 + j0];
            float4 w2 = *(const float4*)&Wgf1s[(k4 * 4 + 2) * 16 + j0];
            float4 w3 = *(const float4*)&Wgf1s[(k4 * 4 + 3) * 16 + j0];
            a0  += hv.x * w0.x + hv.y * w1.x + hv.z * w2.x + hv.w * w3.x;
            a1v += hv.x * w0.y + hv.y * w1.y + hv.z * w2.y + hv.w * w3.y;
            a2  += hv.x * w0.z + hv.y * w1.z + hv.z * w2.z + hv.w * w3.z;
            a3  += hv.x * w0.w + hv.y * w1.w + hv.z * w2.w + hv.w * w3.w;
        }
        a1s[n * 16 + j0]     = tanhf(a0);
        a1s[n * 16 + j0 + 1] = tanhf(a1v);
        a1s[n * 16 + j0 + 2] = tanhf(a2);
        a1s[n * 16 + j0 + 3] = tanhf(a3);
    }
    __syncthreads();

    if (t < 128) {
        int n = t >> 1, kk = t & 1;
        float z = bf2[kk];
#pragma unroll
        for (int j = 0; j < 16; ++j) z += a1s[n * 16 + j] * Wf2[j * 2 + kk];
        Ss[n * 2 + kk] = z;
    }
    __syncthreads();

    if (t < 64) {
        float z0 = Ss[t * 2], z1 = Ss[t * 2 + 1];
        float m = fmaxf(z0, z1);
        float e0 = expf(z0 - m), e1 = expf(z1 - m);
        float inv = 1.0f / (e0 + e1);
        e0 *= inv; e1 *= inv;
        Ss[t * 2] = e0; Ss[t * 2 + 1] = e1;
        Ssum[t] = e0 + e1;
    }
    __syncthreads();

    for (int i = t; i < 512; i += 256) {
        int e = i >> 1, kk = i & 1;
        atomicAdd(&LSs[srcs[e] * 2 + kk], lwx[e] * Ss[dsts[e] * 2 + kk]);
    }
    __syncthreads();

    if (t < 64) {
        float s0 = Ss[t * 2], s1 = Ss[t * 2 + 1];
        float l0 = s0 + LSs[t * 2], l1 = s1 + LSs[t * 2 + 1];
        float p00 = s0 * l0, p01 = s0 * l1, p10 = s1 * l0, p11 = s1 * l1;
        for (int o = 32; o; o >>= 1) {
            p00 += __shfl_down(p00, o); p01 += __shfl_down(p01, o);
            p10 += __shfl_down(p10, o); p11 += __shfl_down(p11, o);
        }
        if (t == 0) {
            float r0 = fmaxf(fabsf(p00) + fabsf(p01), 1e-12f);
            float r1 = fmaxf(fabsf(p10) + fabsf(p11), 1e-12f);
            float d0 = p00 / r0 - 1.0f, d1 = p11 / r1 - 1.0f;
            pens[g] = 0.5f * (d0 * d0 + d1 * d1);
        }
    }
    {
        int k = t & 63, p = t >> 6;
        float qk = 0.f;
#pragma unroll 4
        for (int n = p * 16; n < p * 16 + 16; ++n)
            qk += Ssum[n] * xa[n * 68 + k];
        __syncthreads();
        a1s[p * 64 + k] = qk;
    }
    __syncthreads();
    if (t < 64)
        Qh[(size_t)g * 64 + t] = 0.5f * (a1s[t] + a1s[64 + t] + a1s[128 + t] + a1s[192 + t]);
}

// ---------------------------------------------------------------------------
// CSR build over pos_edges, single block 1024 threads (merges round-5's
// k_cnt + k_dinv + k_scan + k_place; removes the icnt memset).
// ---------------------------------------------------------------------------
__global__ __launch_bounds__(1024) void k_csr(
    const int* __restrict__ pe, int* __restrict__ icnt_g, int* __restrict__ off_g,
    float* __restrict__ dinv, int* __restrict__ csr_src, float* __restrict__ csr_nrm)
{
    __shared__ int icnt_l[4096];
    __shared__ int curs_l[4096];
    __shared__ int wsum[16];
    const int t = threadIdx.x;
    const int base = t * 4;
#pragma unroll
    for (int i = 0; i < 4; ++i) icnt_l[base + i] = 0;
    __syncthreads();
#pragma unroll 8
    for (int q = 0; q < 32; ++q) atomicAdd(&icnt_l[pe[EP + q * 1024 + t]], 1);
    __syncthreads();
    int c0 = icnt_l[base], c1 = icnt_l[base + 1], c2 = icnt_l[base + 2], c3 = icnt_l[base + 3];
    int s = c0 + c1 + c2 + c3;
    int lane = t & 63, w = t >> 6;
    int v = s;
    for (int o = 1; o < 64; o <<= 1) { int u = __shfl_up(v, o); if (lane >= o) v += u; }
    if (lane == 63) wsum[w] = v;
    __syncthreads();
    int woff = 0;
    for (int i = 0; i < 16; ++i) if (i < w) woff += wsum[i];
    int run = woff + v - s;
    off_g[base] = run;     curs_l[base] = run;     run += c0;
    off_g[base + 1] = run; curs_l[base + 1] = run; run += c1;
    off_g[base + 2] = run; curs_l[base + 2] = run; run += c2;
    off_g[base + 3] = run; curs_l[base + 3] = run;
    icnt_g[base] = c0; icnt_g[base + 1] = c1; icnt_g[base + 2] = c2; icnt_g[base + 3] = c3;
    dinv[base]     = rsqrtf((float)c0 + 1.0f);
    dinv[base + 1] = rsqrtf((float)c1 + 1.0f);
    dinv[base + 2] = rsqrtf((float)c2 + 1.0f);
    dinv[base + 3] = rsqrtf((float)c3 + 1.0f);
    __syncthreads();
    for (int q = 0; q < 32; ++q) {
        int e = q * 1024 + t;
        int sg = pe[e], d = pe[EP + e];
        int p = atomicAdd(&curs_l[d], 1);
        csr_src[p] = sg;
        csr_nrm[p] = rsqrtf((float)icnt_l[sg] + 1.0f) * rsqrtf((float)icnt_l[d] + 1.0f);
    }
}

// ---------------------------------------------------------------------------
// CSR gathers: out[g] = in[g]*dinv[g]^2 + sum_{edges->g} in[src]*nrm.
// ---------------------------------------------------------------------------
__global__ void k_gather128(const int* __restrict__ offs, const int* __restrict__ icnt,
                            const int* __restrict__ csr_src, const float* __restrict__ csr_nrm,
                            const float* __restrict__ dinv, const float* __restrict__ in,
                            float* __restrict__ out) {
    int g = blockIdx.x, d = threadIdx.x;  // 128 threads
    float dv = dinv[g];
    float acc = in[(size_t)g * 128 + d] * dv * dv;
    int o = offs[g], c = icnt[g];
    for (int j = 0; j < c; ++j)
        acc += in[(size_t)csr_src[o + j] * 128 + d] * csr_nrm[o + j];
    out[(size_t)g * 128 + d] = acc;
}

__global__ void k_gather256(const int* __restrict__ offs, const int* __restrict__ icnt,
                            const int* __restrict__ csr_src, const float* __restrict__ csr_nrm,
                            const float* __restrict__ dinv, const float* __restrict__ in,
                            float* __restrict__ out) {
    int g = blockIdx.x, d = threadIdx.x;  // 256 threads
    float dv = dinv[g];
    float acc = in[(size_t)g * 256 + d] * dv * dv;
    int o = offs[g], c = icnt[g];
    for (int j = 0; j < c; ++j)
        acc += in[(size_t)csr_src[o + j] * 256 + d] * csr_nrm[o + j];
    out[(size_t)g * 256 + d] = acc;
}

// ---------------------------------------------------------------------------
// Double-buffered tiled fp32 GEMM: C = A[MxK] @ B[KxN] (+bias, opt relu).
// 64x64 tile, 256 threads, 4x4 microtile, BK=32, register-prefetch +
// 2x LDS buffers (one barrier per K-iter; global loads overlap compute).
// LDS 34.8 KB -> 4 blocks/CU. Round-5 post-mortem: single-buffered version
// exposed full global latency on each of the 8 K-iters (~6 TF effective).
// Dual-output option: blockIdx.y >= gridDim.y/2 uses B1/bias1/C1 (shared A).
// ---------------------------------------------------------------------------
__global__ __launch_bounds__(256) void k_gemm(
    const float* __restrict__ A,
    const float* __restrict__ B0, const float* __restrict__ bias0, float* __restrict__ C0,
    const float* __restrict__ B1, const float* __restrict__ bias1, float* __restrict__ C1,
    int M, int K, int N, int dorelu)
{
    __shared__ __align__(16) float lds[2 * 4352];  // per buf: At 32x68, Bs 32x68
    const float* B = B0; const float* bias = bias0; float* C = C0;
    int by = blockIdx.y;
    if (B1 != nullptr && by >= (int)(gridDim.y >> 1)) {
        B = B1; bias = bias1; C = C1; by -= (gridDim.y >> 1);
    }
    const int mb = blockIdx.x * 64, nbb = by * 64;
    const int t = threadIdx.x;
    const int tm4 = (t >> 4) * 4, tn4 = (t & 15) * 4;
    // staging coords
    const int ma = t >> 2, ka = (t & 3) * 8;     // A: (ma, ka..ka+7)
    const int kb = t >> 3, nb8 = (t & 7) * 8;    // B: (kb, nb8..nb8+7)

    float4 pa0, pa1, pb0, pb1;
#define LOADT(K0) { \
    const float* Ap = &A[(size_t)(mb + ma) * K + (K0) + ka]; \
    pa0 = *(const float4*)Ap; pa1 = *(const float4*)(Ap + 4); \
    const float* Bp = &B[(size_t)((K0) + kb) * N + nbb + nb8]; \
    pb0 = *(const float4*)Bp; pb1 = *(const float4*)(Bp + 4); }
#define STORET(BUF) { \
    float* At_ = lds + (BUF) * 4352; \
    At_[(ka + 0) * 68 + ma] = pa0.x; At_[(ka + 1) * 68 + ma] = pa0.y; \
    At_[(ka + 2) * 68 + ma] = pa0.z; At_[(ka + 3) * 68 + ma] = pa0.w; \
    At_[(ka + 4) * 68 + ma] = pa1.x; At_[(ka + 5) * 68 + ma] = pa1.y; \
    At_[(ka + 6) * 68 + ma] = pa1.z; At_[(ka + 7) * 68 + ma] = pa1.w; \
    float* Bs_ = lds + (BUF) * 4352 + 2176; \
    *(float4*)&Bs_[kb * 68 + nb8] = pb0; *(float4*)&Bs_[kb * 68 + nb8 + 4] = pb1; }

    float4 ca0 = {0,0,0,0}, ca1 = {0,0,0,0}, ca2 = {0,0,0,0}, ca3 = {0,0,0,0};
    const int nk0 = K >> 5;
    LOADT(0)
    STORET(0)
    __syncthreads();
    for (int it = 0; it < nk0; ++it) {
        if (it + 1 < nk0) LOADT((it + 1) * 32)
        const float* At_ = lds + (it & 1) * 4352;
        const float* Bs_ = At_ + 2176;
#pragma unroll
        for (int k = 0; k < 32; ++k) {
            float4 av = *(const float4*)&At_[k * 68 + tm4];
            float4 bv = *(const float4*)&Bs_[k * 68 + tn4];
            ca0.x += av.x * bv.x; ca0.y += av.x * bv.y; ca0.z += av.x * bv.z; ca0.w += av.x * bv.w;
            ca1.x += av.y * bv.x; ca1.y += av.y * bv.y; ca1.z += av.y * bv.z; ca1.w += av.y * bv.w;
            ca2.x += av.z * bv.x; ca2.y += av.z * bv.y; ca2.z += av.z * bv.z; ca2.w += av.z * bv.w;
            ca3.x += av.w * bv.x; ca3.y += av.w * bv.y; ca3.z += av.w * bv.z; ca3.w += av.w * bv.w;
        }
        if (it + 1 < nk0) {
            STORET((it + 1) & 1)
            __syncthreads();
        }
    }
#undef LOADT
#undef STORET
    float4 bv4 = {0, 0, 0, 0};
    if (bias) bv4 = *(const float4*)&bias[nbb + tn4];
#define CST(I, CV) { \
    float4 v; v.x = CV.x + bv4.x; v.y = CV.y + bv4.y; v.z = CV.z + bv4.z; v.w = CV.w + bv4.w; \
    if (dorelu) { v.x = fmaxf(v.x, 0.f); v.y = fmaxf(v.y, 0.f); v.z = fmaxf(v.z, 0.f); v.w = fmaxf(v.w, 0.f); } \
    *(float4*)&C[(size_t)(mb + tm4 + (I)) * N + nbb + tn4] = v; }
    CST(0, ca0) CST(1, ca1) CST(2, ca2) CST(3, ca3)
#undef CST
}

// z = mu + eps*exp(min(ls,10)); zc = [emb, z]; per-graph KL partial
__global__ void k_fin_z(const float* __restrict__ mu_arr, const float* __restrict__ ls_arr,
                        const float* __restrict__ eps, const float* __restrict__ emb,
                        float* __restrict__ zc, float* __restrict__ klp) {
    __shared__ float smw[2];
    int g = blockIdx.x, d = threadIdx.x;  // 128 threads
    int idx = g * 128 + d;
    float mu = mu_arr[idx];
    float ls = fminf(ls_arr[idx], 10.0f);
    float z = mu + eps[idx] * expf(ls);
    zc[(size_t)g * 256 + d] = emb[idx];
    zc[(size_t)g * 256 + 128 + d] = z;
    float term = 1.0f + 2.0f * ls - mu * mu - expf(2.0f * ls);
    for (int o = 32; o; o >>= 1) term += __shfl_down(term, o);
    if ((d & 63) == 0) smw[d >> 6] = term;
    __syncthreads();
    if (d == 0) klp[g] = smw[0] + smw[1];
}

// Edge predictions: sigmoid(dot(Arow[src], Brow[dst])) + per-block log partial
__global__ void k_pred(const float* __restrict__ A, const float* __restrict__ B,
                       const int* __restrict__ pos, const int* __restrict__ neg,
                       float* __restrict__ out, float* __restrict__ predp) {
    __shared__ float smw[4];
    int t = threadIdx.x, w = t >> 6, l = t & 63;
    int eg = blockIdx.x * 4 + w;
    int isneg = eg >= EP;
    int e = eg - (isneg ? EP : 0);
    const int* eix = isneg ? neg : pos;
    int s = eix[e], d = eix[EP + e];
    const float4* Ar = (const float4*)(A + (size_t)s * 256);
    const float4* Br = (const float4*)(B + (size_t)d * 256);
    float4 av = Ar[l], bv = Br[l];
    float dot = av.x * bv.x + av.y * bv.y + av.z * bv.z + av.w * bv.w;
    for (int o = 32; o; o >>= 1) dot += __shfl_down(dot, o);
    if (l == 0) {
        float p = 1.0f / (1.0f + expf(-dot));
        float term;
        if (isneg) { out[2 + EP + e] = p; term = logf(1.0f - p + 1e-15f); }
        else       { out[2 + e] = p;      term = logf(p + 1e-15f); }
        smw[w] = term;
    }
    __syncthreads();
    if (t == 0) predp[blockIdx.x] = smw[0] + smw[1] + smw[2] + smw[3];
}

// Final scalar reductions
__global__ void k_final(const float* __restrict__ pens, const float* __restrict__ klp,
                        const float* __restrict__ predp, float* __restrict__ out) {
    __shared__ float sm[16];
    int t = threadIdx.x;
    float s_pen = 0.f, s_kl = 0.f, s_pos = 0.f, s_neg = 0.f;
    for (int i = t; i < 4096; i += 256) { s_pen += pens[i]; s_kl += klp[i]; }
    for (int i = t; i < 8192; i += 256) { s_pos += predp[i]; s_neg += predp[8192 + i]; }
    for (int o = 32; o; o >>= 1) {
        s_pen += __shfl_down(s_pen, o); s_kl += __shfl_down(s_kl, o);
        s_pos += __shfl_down(s_pos, o); s_neg += __shfl_down(s_neg, o);
    }
    int w = t >> 6;
    if ((t & 63) == 0) { sm[w] = s_pen; sm[4 + w] = s_kl; sm[8 + w] = s_pos; sm[12 + w] = s_neg; }
    __syncthreads();
    if (t == 0) {
        float pen = sm[0] + sm[1] + sm[2] + sm[3];
        float kls = sm[4] + sm[5] + sm[6] + sm[7];
        float pos = sm[8] + sm[9] + sm[10] + sm[11];
        float neg = sm[12] + sm[13] + sm[14] + sm[15];
        float rec = -(pos / 32768.0f) - (neg / 32768.0f);
        out[0] = rec - 0.5f * kls / (4096.0f * 4096.0f);
        out[1] = pen * (1.0f / 4096.0f);
    }
}

extern "C" void kernel_launch(void* const* d_in, const int* in_sizes, int n_in,
                              void* d_out, int out_size, void* d_ws, size_t ws_size,
                              hipStream_t stream) {
    const float* x   = (const float*)d_in[0];
    const int*   ei  = (const int*)d_in[1];
    const float* ew  = (const float*)d_in[2];
    const int*   pos = (const int*)d_in[3];
    const int*   neg = (const int*)d_in[4];
    const float* eps = (const float*)d_in[5];
    const float* Wg  = (const float*)d_in[6];
    const float* bg  = (const float*)d_in[7];
    const float* Wf1 = (const float*)d_in[8];
    const float* bf1 = (const float*)d_in[9];
    const float* Wf2 = (const float*)d_in[10];
    const float* bf2 = (const float*)d_in[11];
    const float* Wc1 = (const float*)d_in[12];
    const float* bc1 = (const float*)d_in[13];
    const float* Wmu = (const float*)d_in[14];
    const float* bmu = (const float*)d_in[15];
    const float* Wls = (const float*)d_in[16];
    const float* bls = (const float*)d_in[17];
    const float* emb = (const float*)d_in[18];
    const float* Wl1 = (const float*)d_in[19];
    const float* bl1 = (const float*)d_in[20];
    const float* Wl2 = (const float*)d_in[21];
    const float* bl2 = (const float*)d_in[22];
    float* out = (float*)d_out;
    float* ws  = (float*)d_ws;

    // Workspace layout (floats), ~30.8 MB
    float* g_embs  = ws + 0;         // 524288
    float* dinv    = ws + 524288;    // 4096
    int*   icnt_g  = (int*)(ws + 528384);  // 4096
    int*   off_g   = (int*)(ws + 532480);  // 4096
    int*   csr_src = (int*)(ws + 540672);  // 32768
    float* csr_nrm = ws + 573440;    // 32768
    float* Qh      = ws + 606208;    // 262144
    float* ga      = ws + 868352;    // 524288
    float* h       = ws + 1392640;   // 1048576
    float* ha      = ws + 2441216;   // 1048576
    float* mu_arr  = ws + 3489792;   // 524288
    float* ls_arr  = ws + 4014080;   // 524288
    float* zc      = ws + 4538368;   // 1048576
    float* Abuf    = ws + 5586944;   // 1048576
    float* Bbuf    = ws + 6635520;   // 1048576
    float* pens    = ws + 7684096;   // 4096
    float* klp     = ws + 7688192;   // 4096
    float* predp   = ws + 7692288;   // 16384
    float* Wgf1    = ws + 7708672;   // 1024
    float* bcomb   = ws + 7709696;   // 16
    float* bg32    = ws + 7709712;   // 128

    // Prep + per-graph stage
    k_prep<<<1, 256, 0, stream>>>(Wg, Wf1, bf1, bg, Wgf1, bcomb, bg32);
    k_pg<<<GG, 256, 0, stream>>>(x, ei, ew, Wgf1, bcomb, Wf2, bf2, Qh, pens);
    // g_embs = Qh @ Wg + 32*bg
    k_gemm<<<dim3(64, 2), 256, 0, stream>>>(Qh, Wg, bg32, g_embs,
                                            nullptr, nullptr, nullptr, GG, 64, 128, 0);

    // Global CSR over pos_edges (single merged kernel; no memset needed)
    k_csr<<<1, 1024, 0, stream>>>(pos, icnt_g, off_g, dinv, csr_src, csr_nrm);

    // h = relu((A g_embs) @ Wc1 + bc1)
    k_gather128<<<GG, 128, 0, stream>>>(off_g, icnt_g, csr_src, csr_nrm, dinv, g_embs, ga);
    k_gemm<<<dim3(64, 4), 256, 0, stream>>>(ga, Wc1, bc1, h,
                                            nullptr, nullptr, nullptr, GG, 128, 256, 1);

    // mu/ls = (A h) @ {Wmu,Wls} + {bmu,bls}
    k_gather256<<<GG, 256, 0, stream>>>(off_g, icnt_g, csr_src, csr_nrm, dinv, h, ha);
    k_gemm<<<dim3(64, 4), 256, 0, stream>>>(ha, Wmu, bmu, mu_arr,
                                            Wls, bls, ls_arr, GG, 256, 128, 0);
    k_fin_z<<<GG, 128, 0, stream>>>(mu_arr, ls_arr, eps, emb, zc, klp);

    // A = zc@W_lin1+b, B = zc@W_lin2+b
    k_gemm<<<dim3(64, 8), 256, 0, stream>>>(zc, Wl1, bl1, Abuf,
                                            Wl2, bl2, Bbuf, GG, 256, 256, 0);

    // Edge predictions + scalars
    k_pred<<<(2 * EP) / 4, 256, 0, stream>>>(Abuf, Bbuf, pos, neg, out, predp);
    k_final<<<1, 256, 0, stream>>>(pens, klp, predp, out);
}

// Round 7
// 336.971 us; speedup vs baseline: 6.8380x; 1.2411x over previous
//
#include <hip/hip_runtime.h>
#include <hip/hip_bf16.h>
#include <math.h>

// Sizes (fixed by the reference)
#define GG   4096
#define NNODE 64
#define EEDGE 256
#define FFEAT 64
#define DDIM 128
#define EP   32768

// ---------------------------------------------------------------------------
// Prep (once per call, tiny): Wgf1 = Wg @ Wf1 [64x16],
// bcomb = bg @ Wf1 + bf1 [16], bg32 = 32*bg [128].
// ---------------------------------------------------------------------------
__global__ void k_prep(const float* __restrict__ Wg, const float* __restrict__ Wf1,
                       const float* __restrict__ bf1, const float* __restrict__ bg,
                       float* __restrict__ Wgf1, float* __restrict__ bcomb,
                       float* __restrict__ bg32) {
    int t = threadIdx.x;
    for (int o = t; o < 1024; o += 256) {
        int f = o >> 4, j = o & 15;
        float s = 0.f;
        for (int d = 0; d < 128; ++d) s += Wg[f * 128 + d] * Wf1[d * 16 + j];
        Wgf1[o] = s;
    }
    if (t < 16) {
        float s = bf1[t];
        for (int d = 0; d < 128; ++d) s += bg[d] * Wf1[d * 16 + t];
        bcomb[t] = s;
    }
    if (t >= 128) bg32[t - 128] = 32.0f * bg[t - 128];
}

// ---------------------------------------------------------------------------
// Per-graph kernel (CSR-gather version; unchanged from round 5).
// ---------------------------------------------------------------------------
__global__ __launch_bounds__(256) void k_pg(
    const float* __restrict__ x, const int* __restrict__ ei, const float* __restrict__ ew,
    const float* __restrict__ Wgf1, const float* __restrict__ bcomb,
    const float* __restrict__ Wf2, const float* __restrict__ bf2,
    float* __restrict__ Qh, float* __restrict__ pens)
{
    __shared__ __align__(16) float sm[12816];
    float* xs    = sm;                    // 64x68
    float* xa    = sm + 4352;             // 64x68
    float* Wgf1s = sm + 8704;             // 1024
    float* a1s   = sm + 9728;             // 1024 (reused as Qh partials)
    int*   srcs  = (int*)(sm + 10752);    // 256
    int*   dsts  = (int*)(sm + 11008);    // 256
    float* lwx   = sm + 11264;            // 256
    int*   lsrc  = (int*)(sm + 11520);    // 256 CSR src
    float* lnrm  = sm + 11776;            // 256 CSR norm
    int*   icnt  = (int*)(sm + 12032);    // 64
    int*   offs  = (int*)(sm + 12096);    // 64
    int*   curs  = (int*)(sm + 12160);    // 64
    float* degw  = sm + 12224;            // 64
    float* dinvs = sm + 12288;            // 64
    float* deg2s = sm + 12352;            // 64
    float* dinv2s= sm + 12416;            // 64
    float* Ss    = sm + 12480;            // 128
    float* Ssum  = sm + 12608;            // 64
    float* LSs   = sm + 12672;            // 128
    float* bcs   = sm + 12800;            // 16

    const int g = blockIdx.x;
    const int t = threadIdx.x;
    const float* xg = x + (size_t)g * 4096;

    {
        const int* eg = ei + (size_t)g * 512;
        srcs[t] = eg[t];
        dsts[t] = eg[256 + t];
        lwx[t]  = ew[(size_t)g * 256 + t];
        for (int i = t; i < 1024; i += 256) {
            int n = i >> 4, k = (i & 15) * 4;
            *(float4*)&xs[n * 68 + k] = *(const float4*)&xg[n * 64 + k];
        }
        for (int i = t; i < 1024; i += 256) Wgf1s[i] = Wgf1[i];
        if (t < 16) bcs[t] = bcomb[t];
        if (t < 64) { icnt[t] = 0; degw[t] = 1.0f; deg2s[t] = 0.0f; }
        if (t < 128) LSs[t] = 0.0f;
    }
    __syncthreads();

    {
        int dd = dsts[t], s = srcs[t];
        float w = lwx[t];
        atomicAdd(&icnt[dd], 1);
        atomicAdd(&degw[dd], w);
        atomicAdd(&deg2s[s], w);
    }
    __syncthreads();

    if (t < 64) {
        int v = icnt[t], own = v;
        for (int o = 1; o < 64; o <<= 1) { int u = __shfl_up(v, o); if (t >= o) v += u; }
        int excl = v - own;
        offs[t] = excl; curs[t] = excl;
        dinvs[t] = rsqrtf(degw[t]);
        float dg = deg2s[t];
        dinv2s[t] = dg > 0.0f ? rsqrtf(fmaxf(dg, 1e-30f)) : 0.0f;
    }
    __syncthreads();

    {
        int s = srcs[t], dd = dsts[t];
        float w = lwx[t];
        int pos = atomicAdd(&curs[dd], 1);
        lsrc[pos] = s;
        lnrm[pos] = dinvs[s] * w * dinvs[dd];
        lwx[t] = -dinv2s[s] * w * dinv2s[dd];
    }
    __syncthreads();

    {
        int n = t >> 2, base = (t & 3) * 16;
        float sc = dinvs[n] * dinvs[n];
        const float* xrow = &xs[n * 68 + base];
        float4 A0 = *(const float4*)&xrow[0];
        float4 A1 = *(const float4*)&xrow[4];
        float4 A2 = *(const float4*)&xrow[8];
        float4 A3 = *(const float4*)&xrow[12];
        A0.x *= sc; A0.y *= sc; A0.z *= sc; A0.w *= sc;
        A1.x *= sc; A1.y *= sc; A1.z *= sc; A1.w *= sc;
        A2.x *= sc; A2.y *= sc; A2.z *= sc; A2.w *= sc;
        A3.x *= sc; A3.y *= sc; A3.z *= sc; A3.w *= sc;
        int o = offs[n], c = icnt[n];
        for (int j = 0; j < c; ++j) {
            int s = lsrc[o + j];
            float nm = lnrm[o + j];
            const float* xr = &xs[s * 68 + base];
            float4 X0 = *(const float4*)&xr[0];
            float4 X1 = *(const float4*)&xr[4];
            float4 X2 = *(const float4*)&xr[8];
            float4 X3 = *(const float4*)&xr[12];
            A0.x += X0.x * nm; A0.y += X0.y * nm; A0.z += X0.z * nm; A0.w += X0.w * nm;
            A1.x += X1.x * nm; A1.y += X1.y * nm; A1.z += X1.z * nm; A1.w += X1.w * nm;
            A2.x += X2.x * nm; A2.y += X2.y * nm; A2.z += X2.z * nm; A2.w += X2.w * nm;
            A3.x += X3.x * nm; A3.y += X3.y * nm; A3.z += X3.z * nm; A3.w += X3.w * nm;
        }
        float* xw = &xa[n * 68 + base];
        *(float4*)&xw[0]  = A0;
        *(float4*)&xw[4]  = A1;
        *(float4*)&xw[8]  = A2;
        *(float4*)&xw[12] = A3;
    }
    __syncthreads();

    {
        int n = t >> 2, j0 = (t & 3) * 4;
        float a0 = bcs[j0], a1v = bcs[j0 + 1], a2 = bcs[j0 + 2], a3 = bcs[j0 + 3];
#pragma unroll 4
        for (int k4 = 0; k4 < 16; ++k4) {
            float4 hv = *(const float4*)&xa[n * 68 + k4 * 4];
            float4 w0 = *(const float4*)&Wgf1s[(k4 * 4 + 0) * 16 + j0];
            float4 w1 = *(const float4*)&Wgf1s[(k4 * 4 + 1) * 16 + j0];
            float4 w2 = *(const float4*)&Wgf1s[(k4 * 4 + 2) * 16 + j0];
            float4 w3 = *(const float4*)&Wgf1s[(k4 * 4 + 3) * 16 + j0];
            a0  += hv.x * w0.x + hv.y * w1.x + hv.z * w2.x + hv.w * w3.x;
            a1v += hv.x * w0.y + hv.y * w1.y + hv.z * w2.y + hv.w * w3.y;
            a2  += hv.x * w0.z + hv.y * w1.z + hv.z * w2.z + hv.w * w3.z;
            a3  += hv.x * w0.w + hv.y * w1.w + hv.z * w2.w + hv.w * w3.w;
        }
        a1s[n * 16 + j0]     = tanhf(a0);
        a1s[n * 16 + j0 + 1] = tanhf(a1v);
        a1s[n * 16 + j0 + 2] = tanhf(a2);
        a1s[n * 16 + j0 + 3] = tanhf(a3);
    }
    __syncthreads();

    if (t < 128) {
        int n = t >> 1, kk = t & 1;
        float z = bf2[kk];
#pragma unroll
        for (int j = 0; j < 16; ++j) z += a1s[n * 16 + j] * Wf2[j * 2 + kk];
        Ss[n * 2 + kk] = z;
    }
    __syncthreads();

    if (t < 64) {
        float z0 = Ss[t * 2], z1 = Ss[t * 2 + 1];
        float m = fmaxf(z0, z1);
        float e0 = expf(z0 - m), e1 = expf(z1 - m);
        float inv = 1.0f / (e0 + e1);
        e0 *= inv; e1 *= inv;
        Ss[t * 2] = e0; Ss[t * 2 + 1] = e1;
        Ssum[t] = e0 + e1;
    }
    __syncthreads();

    for (int i = t; i < 512; i += 256) {
        int e = i >> 1, kk = i & 1;
        atomicAdd(&LSs[srcs[e] * 2 + kk], lwx[e] * Ss[dsts[e] * 2 + kk]);
    }
    __syncthreads();

    if (t < 64) {
        float s0 = Ss[t * 2], s1 = Ss[t * 2 + 1];
        float l0 = s0 + LSs[t * 2], l1 = s1 + LSs[t * 2 + 1];
        float p00 = s0 * l0, p01 = s0 * l1, p10 = s1 * l0, p11 = s1 * l1;
        for (int o = 32; o; o >>= 1) {
            p00 += __shfl_down(p00, o); p01 += __shfl_down(p01, o);
            p10 += __shfl_down(p10, o); p11 += __shfl_down(p11, o);
        }
        if (t == 0) {
            float r0 = fmaxf(fabsf(p00) + fabsf(p01), 1e-12f);
            float r1 = fmaxf(fabsf(p10) + fabsf(p11), 1e-12f);
            float d0 = p00 / r0 - 1.0f, d1 = p11 / r1 - 1.0f;
            pens[g] = 0.5f * (d0 * d0 + d1 * d1);
        }
    }
    {
        int k = t & 63, p = t >> 6;
        float qk = 0.f;
#pragma unroll 4
        for (int n = p * 16; n < p * 16 + 16; ++n)
            qk += Ssum[n] * xa[n * 68 + k];
        __syncthreads();
        a1s[p * 64 + k] = qk;
    }
    __syncthreads();
    if (t < 64)
        Qh[(size_t)g * 64 + t] = 0.5f * (a1s[t] + a1s[64 + t] + a1s[128 + t] + a1s[192 + t]);
}

// ---------------------------------------------------------------------------
// Parallel CSR build over pos_edges (round-6 post-mortem: the merged
// single-block version serialized on one CU -> 97 us; parallel 3-kernel
// version is ~10 us total despite extra launches).
// ---------------------------------------------------------------------------
__global__ void k_cnt(const int* __restrict__ pd, int* __restrict__ icnt) {
    int e = blockIdx.x * 256 + threadIdx.x;
    atomicAdd(&icnt[pd[e]], 1);
}

// Single block: scan 4096 counts -> offsets/cursors; also dinv = rsqrt(cnt+1)
__global__ void k_scan(const int* __restrict__ icnt, int* __restrict__ offs,
                       int* __restrict__ curs, float* __restrict__ dinv) {
    __shared__ int wsum[4];
    int t = threadIdx.x;
    int base = t * 16;
    int l0,l1,l2,l3,l4,l5,l6,l7,l8,l9,l10,l11,l12,l13,l14,l15;
    l0=icnt[base+0]; l1=icnt[base+1]; l2=icnt[base+2]; l3=icnt[base+3];
    l4=icnt[base+4]; l5=icnt[base+5]; l6=icnt[base+6]; l7=icnt[base+7];
    l8=icnt[base+8]; l9=icnt[base+9]; l10=icnt[base+10]; l11=icnt[base+11];
    l12=icnt[base+12]; l13=icnt[base+13]; l14=icnt[base+14]; l15=icnt[base+15];
    int s = l0+l1+l2+l3+l4+l5+l6+l7+l8+l9+l10+l11+l12+l13+l14+l15;
    int lane = t & 63, w = t >> 6;
    int v = s;
    for (int o = 1; o < 64; o <<= 1) { int u = __shfl_up(v, o); if (lane >= o) v += u; }
    if (lane == 63) wsum[w] = v;
    __syncthreads();
    int woff = 0;
    for (int i = 0; i < 4; ++i) if (i < w) woff += wsum[i];
    int run = woff + v - s;
#define SC(L, I) offs[base+(I)] = run; curs[base+(I)] = run; \
    dinv[base+(I)] = rsqrtf((float)(L) + 1.0f); run += L;
    SC(l0,0) SC(l1,1) SC(l2,2) SC(l3,3) SC(l4,4) SC(l5,5) SC(l6,6) SC(l7,7)
    SC(l8,8) SC(l9,9) SC(l10,10) SC(l11,11) SC(l12,12) SC(l13,13) SC(l14,14) SC(l15,15)
#undef SC
}

__global__ void k_place(const int* __restrict__ pe, const float* __restrict__ dinv,
                        int* __restrict__ curs, int* __restrict__ csr_src,
                        float* __restrict__ csr_nrm) {
    int e = blockIdx.x * 256 + threadIdx.x;
    int s = pe[e], d = pe[EP + e];
    int pos = atomicAdd(&curs[d], 1);
    csr_src[pos] = s;
    csr_nrm[pos] = dinv[s] * dinv[d];
}

// ---------------------------------------------------------------------------
// CSR gathers: out[g] = in[g]*dinv[g]^2 + sum_{edges->g} in[src]*nrm.
// ---------------------------------------------------------------------------
__global__ void k_gather128(const int* __restrict__ offs, const int* __restrict__ icnt,
                            const int* __restrict__ csr_src, const float* __restrict__ csr_nrm,
                            const float* __restrict__ dinv, const float* __restrict__ in,
                            float* __restrict__ out) {
    int g = blockIdx.x, d = threadIdx.x;  // 128 threads
    float dv = dinv[g];
    float acc = in[(size_t)g * 128 + d] * dv * dv;
    int o = offs[g], c = icnt[g];
    for (int j = 0; j < c; ++j)
        acc += in[(size_t)csr_src[o + j] * 128 + d] * csr_nrm[o + j];
    out[(size_t)g * 128 + d] = acc;
}

__global__ void k_gather256(const int* __restrict__ offs, const int* __restrict__ icnt,
                            const int* __restrict__ csr_src, const float* __restrict__ csr_nrm,
                            const float* __restrict__ dinv, const float* __restrict__ in,
                            float* __restrict__ out) {
    int g = blockIdx.x, d = threadIdx.x;  // 256 threads
    float dv = dinv[g];
    float acc = in[(size_t)g * 256 + d] * dv * dv;
    int o = offs[g], c = icnt[g];
    for (int j = 0; j < c; ++j)
        acc += in[(size_t)csr_src[o + j] * 256 + d] * csr_nrm[o + j];
    out[(size_t)g * 256 + d] = acc;
}

// ---------------------------------------------------------------------------
// Double-buffered tiled fp32 GEMM (unchanged from round 6): 64x64 tile,
// 256 threads, 4x4 microtile, BK=32, register-prefetch + 2x LDS buffers.
// Dual-output option: blockIdx.y >= gridDim.y/2 uses B1/bias1/C1 (shared A).
// ---------------------------------------------------------------------------
__global__ __launch_bounds__(256) void k_gemm(
    const float* __restrict__ A,
    const float* __restrict__ B0, const float* __restrict__ bias0, float* __restrict__ C0,
    const float* __restrict__ B1, const float* __restrict__ bias1, float* __restrict__ C1,
    int M, int K, int N, int dorelu)
{
    __shared__ __align__(16) float lds[2 * 4352];  // per buf: At 32x68, Bs 32x68
    const float* B = B0; const float* bias = bias0; float* C = C0;
    int by = blockIdx.y;
    if (B1 != nullptr && by >= (int)(gridDim.y >> 1)) {
        B = B1; bias = bias1; C = C1; by -= (gridDim.y >> 1);
    }
    const int mb = blockIdx.x * 64, nbb = by * 64;
    const int t = threadIdx.x;
    const int tm4 = (t >> 4) * 4, tn4 = (t & 15) * 4;
    const int ma = t >> 2, ka = (t & 3) * 8;     // A: (ma, ka..ka+7)
    const int kb = t >> 3, nb8 = (t & 7) * 8;    // B: (kb, nb8..nb8+7)

    float4 pa0, pa1, pb0, pb1;
#define LOADT(K0) { \
    const float* Ap = &A[(size_t)(mb + ma) * K + (K0) + ka]; \
    pa0 = *(const float4*)Ap; pa1 = *(const float4*)(Ap + 4); \
    const float* Bp = &B[(size_t)((K0) + kb) * N + nbb + nb8]; \
    pb0 = *(const float4*)Bp; pb1 = *(const float4*)(Bp + 4); }
#define STORET(BUF) { \
    float* At_ = lds + (BUF) * 4352; \
    At_[(ka + 0) * 68 + ma] = pa0.x; At_[(ka + 1) * 68 + ma] = pa0.y; \
    At_[(ka + 2) * 68 + ma] = pa0.z; At_[(ka + 3) * 68 + ma] = pa0.w; \
    At_[(ka + 4) * 68 + ma] = pa1.x; At_[(ka + 5) * 68 + ma] = pa1.y; \
    At_[(ka + 6) * 68 + ma] = pa1.z; At_[(ka + 7) * 68 + ma] = pa1.w; \
    float* Bs_ = lds + (BUF) * 4352 + 2176; \
    *(float4*)&Bs_[kb * 68 + nb8] = pb0; *(float4*)&Bs_[kb * 68 + nb8 + 4] = pb1; }

    float4 ca0 = {0,0,0,0}, ca1 = {0,0,0,0}, ca2 = {0,0,0,0}, ca3 = {0,0,0,0};
    const int nk0 = K >> 5;
    LOADT(0)
    STORET(0)
    __syncthreads();
    for (int it = 0; it < nk0; ++it) {
        if (it + 1 < nk0) LOADT((it + 1) * 32)
        const float* At_ = lds + (it & 1) * 4352;
        const float* Bs_ = At_ + 2176;
#pragma unroll
        for (int k = 0; k < 32; ++k) {
            float4 av = *(const float4*)&At_[k * 68 + tm4];
            float4 bv = *(const float4*)&Bs_[k * 68 + tn4];
            ca0.x += av.x * bv.x; ca0.y += av.x * bv.y; ca0.z += av.x * bv.z; ca0.w += av.x * bv.w;
            ca1.x += av.y * bv.x; ca1.y += av.y * bv.y; ca1.z += av.y * bv.z; ca1.w += av.y * bv.w;
            ca2.x += av.z * bv.x; ca2.y += av.z * bv.y; ca2.z += av.z * bv.z; ca2.w += av.z * bv.w;
            ca3.x += av.w * bv.x; ca3.y += av.w * bv.y; ca3.z += av.w * bv.z; ca3.w += av.w * bv.w;
        }
        if (it + 1 < nk0) {
            STORET((it + 1) & 1)
            __syncthreads();
        }
    }
#undef LOADT
#undef STORET
    float4 bv4 = {0, 0, 0, 0};
    if (bias) bv4 = *(const float4*)&bias[nbb + tn4];
#define CST(I, CV) { \
    float4 v; v.x = CV.x + bv4.x; v.y = CV.y + bv4.y; v.z = CV.z + bv4.z; v.w = CV.w + bv4.w; \
    if (dorelu) { v.x = fmaxf(v.x, 0.f); v.y = fmaxf(v.y, 0.f); v.z = fmaxf(v.z, 0.f); v.w = fmaxf(v.w, 0.f); } \
    *(float4*)&C[(size_t)(mb + tm4 + (I)) * N + nbb + tn4] = v; }
    CST(0, ca0) CST(1, ca1) CST(2, ca2) CST(3, ca3)
#undef CST
}

// z = mu + eps*exp(min(ls,10)); zc = [emb, z]; per-graph KL partial
__global__ void k_fin_z(const float* __restrict__ mu_arr, const float* __restrict__ ls_arr,
                        const float* __restrict__ eps, const float* __restrict__ emb,
                        float* __restrict__ zc, float* __restrict__ klp) {
    __shared__ float smw[2];
    int g = blockIdx.x, d = threadIdx.x;  // 128 threads
    int idx = g * 128 + d;
    float mu = mu_arr[idx];
    float ls = fminf(ls_arr[idx], 10.0f);
    float z = mu + eps[idx] * expf(ls);
    zc[(size_t)g * 256 + d] = emb[idx];
    zc[(size_t)g * 256 + 128 + d] = z;
    float term = 1.0f + 2.0f * ls - mu * mu - expf(2.0f * ls);
    for (int o = 32; o; o >>= 1) term += __shfl_down(term, o);
    if ((d & 63) == 0) smw[d >> 6] = term;
    __syncthreads();
    if (d == 0) klp[g] = smw[0] + smw[1];
}

// Edge predictions: sigmoid(dot(Arow[src], Brow[dst])) + per-block log partial
__global__ void k_pred(const float* __restrict__ A, const float* __restrict__ B,
                       const int* __restrict__ pos, const int* __restrict__ neg,
                       float* __restrict__ out, float* __restrict__ predp) {
    __shared__ float smw[4];
    int t = threadIdx.x, w = t >> 6, l = t & 63;
    int eg = blockIdx.x * 4 + w;
    int isneg = eg >= EP;
    int e = eg - (isneg ? EP : 0);
    const int* eix = isneg ? neg : pos;
    int s = eix[e], d = eix[EP + e];
    const float4* Ar = (const float4*)(A + (size_t)s * 256);
    const float4* Br = (const float4*)(B + (size_t)d * 256);
    float4 av = Ar[l], bv = Br[l];
    float dot = av.x * bv.x + av.y * bv.y + av.z * bv.z + av.w * bv.w;
    for (int o = 32; o; o >>= 1) dot += __shfl_down(dot, o);
    if (l == 0) {
        float p = 1.0f / (1.0f + expf(-dot));
        float term;
        if (isneg) { out[2 + EP + e] = p; term = logf(1.0f - p + 1e-15f); }
        else       { out[2 + e] = p;      term = logf(p + 1e-15f); }
        smw[w] = term;
    }
    __syncthreads();
    if (t == 0) predp[blockIdx.x] = smw[0] + smw[1] + smw[2] + smw[3];
}

// Final scalar reductions
__global__ void k_final(const float* __restrict__ pens, const float* __restrict__ klp,
                        const float* __restrict__ predp, float* __restrict__ out) {
    __shared__ float sm[16];
    int t = threadIdx.x;
    float s_pen = 0.f, s_kl = 0.f, s_pos = 0.f, s_neg = 0.f;
    for (int i = t; i < 4096; i += 256) { s_pen += pens[i]; s_kl += klp[i]; }
    for (int i = t; i < 8192; i += 256) { s_pos += predp[i]; s_neg += predp[8192 + i]; }
    for (int o = 32; o; o >>= 1) {
        s_pen += __shfl_down(s_pen, o); s_kl += __shfl_down(s_kl, o);
        s_pos += __shfl_down(s_pos, o); s_neg += __shfl_down(s_neg, o);
    }
    int w = t >> 6;
    if ((t & 63) == 0) { sm[w] = s_pen; sm[4 + w] = s_kl; sm[8 + w] = s_pos; sm[12 + w] = s_neg; }
    __syncthreads();
    if (t == 0) {
        float pen = sm[0] + sm[1] + sm[2] + sm[3];
        float kls = sm[4] + sm[5] + sm[6] + sm[7];
        float pos = sm[8] + sm[9] + sm[10] + sm[11];
        float neg = sm[12] + sm[13] + sm[14] + sm[15];
        float rec = -(pos / 32768.0f) - (neg / 32768.0f);
        out[0] = rec - 0.5f * kls / (4096.0f * 4096.0f);
        out[1] = pen * (1.0f / 4096.0f);
    }
}

extern "C" void kernel_launch(void* const* d_in, const int* in_sizes, int n_in,
                              void* d_out, int out_size, void* d_ws, size_t ws_size,
                              hipStream_t stream) {
    const float* x   = (const float*)d_in[0];
    const int*   ei  = (const int*)d_in[1];
    const float* ew  = (const float*)d_in[2];
    const int*   pos = (const int*)d_in[3];
    const int*   neg = (const int*)d_in[4];
    const float* eps = (const float*)d_in[5];
    const float* Wg  = (const float*)d_in[6];
    const float* bg  = (const float*)d_in[7];
    const float* Wf1 = (const float*)d_in[8];
    const float* bf1 = (const float*)d_in[9];
    const float* Wf2 = (const float*)d_in[10];
    const float* bf2 = (const float*)d_in[11];
    const float* Wc1 = (const float*)d_in[12];
    const float* bc1 = (const float*)d_in[13];
    const float* Wmu = (const float*)d_in[14];
    const float* bmu = (const float*)d_in[15];
    const float* Wls = (const float*)d_in[16];
    const float* bls = (const float*)d_in[17];
    const float* emb = (const float*)d_in[18];
    const float* Wl1 = (const float*)d_in[19];
    const float* bl1 = (const float*)d_in[20];
    const float* Wl2 = (const float*)d_in[21];
    const float* bl2 = (const float*)d_in[22];
    float* out = (float*)d_out;
    float* ws  = (float*)d_ws;

    // Workspace layout (floats), ~30.8 MB
    float* g_embs  = ws + 0;         // 524288
    float* dinv    = ws + 524288;    // 4096
    int*   icnt_g  = (int*)(ws + 528384);  // 4096
    int*   off_g   = (int*)(ws + 532480);  // 4096
    int*   cur_g   = (int*)(ws + 536576);  // 4096
    int*   csr_src = (int*)(ws + 540672);  // 32768
    float* csr_nrm = ws + 573440;    // 32768
    float* Qh      = ws + 606208;    // 262144
    float* ga      = ws + 868352;    // 524288
    float* h       = ws + 1392640;   // 1048576
    float* ha      = ws + 2441216;   // 1048576
    float* mu_arr  = ws + 3489792;   // 524288
    float* ls_arr  = ws + 4014080;   // 524288
    float* zc      = ws + 4538368;   // 1048576
    float* Abuf    = ws + 5586944;   // 1048576
    float* Bbuf    = ws + 6635520;   // 1048576
    float* pens    = ws + 7684096;   // 4096
    float* klp     = ws + 7688192;   // 4096
    float* predp   = ws + 7692288;   // 16384
    float* Wgf1    = ws + 7708672;   // 1024
    float* bcomb   = ws + 7709696;   // 16
    float* bg32    = ws + 7709712;   // 128

    // Zero the CSR counter (16 KB)
    hipMemsetAsync(icnt_g, 0, 4096u * 4, stream);

    // Prep + per-graph stage
    k_prep<<<1, 256, 0, stream>>>(Wg, Wf1, bf1, bg, Wgf1, bcomb, bg32);
    k_pg<<<GG, 256, 0, stream>>>(x, ei, ew, Wgf1, bcomb, Wf2, bf2, Qh, pens);
    // g_embs = Qh @ Wg + 32*bg
    k_gemm<<<dim3(64, 2), 256, 0, stream>>>(Qh, Wg, bg32, g_embs,
                                            nullptr, nullptr, nullptr, GG, 64, 128, 0);

    // Parallel CSR build over pos_edges
    k_cnt<<<EP / 256, 256, 0, stream>>>(pos + EP, icnt_g);
    k_scan<<<1, 256, 0, stream>>>(icnt_g, off_g, cur_g, dinv);
    k_place<<<EP / 256, 256, 0, stream>>>(pos, dinv, cur_g, csr_src, csr_nrm);

    // h = relu((A g_embs) @ Wc1 + bc1)
    k_gather128<<<GG, 128, 0, stream>>>(off_g, icnt_g, csr_src, csr_nrm, dinv, g_embs, ga);
    k_gemm<<<dim3(64, 4), 256, 0, stream>>>(ga, Wc1, bc1, h,
                                            nullptr, nullptr, nullptr, GG, 128, 256, 1);

    // mu/ls = (A h) @ {Wmu,Wls} + {bmu,bls}
    k_gather256<<<GG, 256, 0, stream>>>(off_g, icnt_g, csr_src, csr_nrm, dinv, h, ha);
    k_gemm<<<dim3(64, 4), 256, 0, stream>>>(ha, Wmu, bmu, mu_arr,
                                            Wls, bls, ls_arr, GG, 256, 128, 0);
    k_fin_z<<<GG, 128, 0, stream>>>(mu_arr, ls_arr, eps, emb, zc, klp);

    // A = zc@W_lin1+b, B = zc@W_lin2+b
    k_gemm<<<dim3(64, 8), 256, 0, stream>>>(zc, Wl1, bl1, Abuf,
                                            Wl2, bl2, Bbuf, GG, 256, 256, 0);

    // Edge predictions + scalars
    k_pred<<<(2 * EP) / 4, 256, 0, stream>>>(Abuf, Bbuf, pos, neg, out, predp);
    k_final<<<1, 256, 0, stream>>>(pens, klp, predp, out);
}

// Round 8
// 320.463 us; speedup vs baseline: 7.1903x; 1.0515x over previous
//
#include <hip/hip_runtime.h>
#include <hip/hip_bf16.h>
#include <math.h>

// Sizes (fixed by the reference)
#define GG   4096
#define NNODE 64
#define EEDGE 256
#define FFEAT 64
#define DDIM 128
#define EP   32768

// ---------------------------------------------------------------------------
// Prep (once per call, tiny): Wgf1 = Wg @ Wf1 [64x16],
// bcomb = bg @ Wf1 + bf1 [16], bg32 = 32*bg [128].
// ---------------------------------------------------------------------------
__global__ void k_prep(const float* __restrict__ Wg, const float* __restrict__ Wf1,
                       const float* __restrict__ bf1, const float* __restrict__ bg,
                       float* __restrict__ Wgf1, float* __restrict__ bcomb,
                       float* __restrict__ bg32) {
    int t = threadIdx.x;
    for (int o = t; o < 1024; o += 256) {
        int f = o >> 4, j = o & 15;
        float s = 0.f;
        for (int d = 0; d < 128; ++d) s += Wg[f * 128 + d] * Wf1[d * 16 + j];
        Wgf1[o] = s;
    }
    if (t < 16) {
        float s = bf1[t];
        for (int d = 0; d < 128; ++d) s += bg[d] * Wf1[d * 16 + t];
        bcomb[t] = s;
    }
    if (t >= 128) bg32[t - 128] = 32.0f * bg[t - 128];
}

// ---------------------------------------------------------------------------
// Per-graph kernel. Round-7 post-mortem: latency-bound at 3 blocks/CU
// (LDS 51.7 KB). This version computes the gathered rows in registers and
// writes them back IN PLACE over xs (one extra barrier), deleting the
// separate xa buffer: LDS 33.9 KB -> 4 blocks/CU.
// ---------------------------------------------------------------------------
__global__ __launch_bounds__(256) void k_pg(
    const float* __restrict__ x, const int* __restrict__ ei, const float* __restrict__ ew,
    const float* __restrict__ Wgf1, const float* __restrict__ bcomb,
    const float* __restrict__ Wf2, const float* __restrict__ bf2,
    float* __restrict__ Qh, float* __restrict__ pens)
{
    __shared__ __align__(16) float sm[8464];
    float* xs    = sm;                    // 64x68; holds x, then (in place) xa
    float* Wgf1s = sm + 4352;             // 1024
    float* a1s   = sm + 5376;             // 1024 (reused as Qh partials)
    int*   srcs  = (int*)(sm + 6400);     // 256
    int*   dsts  = (int*)(sm + 6656);     // 256
    float* lwx   = sm + 6912;             // 256
    int*   lsrc  = (int*)(sm + 7168);     // 256 CSR src
    float* lnrm  = sm + 7424;             // 256 CSR norm
    int*   icnt  = (int*)(sm + 7680);     // 64
    int*   offs  = (int*)(sm + 7744);     // 64
    int*   curs  = (int*)(sm + 7808);     // 64
    float* degw  = sm + 7872;             // 64
    float* dinvs = sm + 7936;             // 64
    float* deg2s = sm + 8000;             // 64
    float* dinv2s= sm + 8064;             // 64
    float* Ss    = sm + 8128;             // 128
    float* Ssum  = sm + 8256;             // 64
    float* LSs   = sm + 8320;             // 128
    float* bcs   = sm + 8448;             // 16

    const int g = blockIdx.x;
    const int t = threadIdx.x;
    const float* xg = x + (size_t)g * 4096;

    // P0: stage x, edges, weights; zero counters
    {
        const int* eg = ei + (size_t)g * 512;
        srcs[t] = eg[t];
        dsts[t] = eg[256 + t];
        lwx[t]  = ew[(size_t)g * 256 + t];
        for (int i = t; i < 1024; i += 256) {
            int n = i >> 4, k = (i & 15) * 4;
            *(float4*)&xs[n * 68 + k] = *(const float4*)&xg[n * 64 + k];
        }
        for (int i = t; i < 1024; i += 256) Wgf1s[i] = Wgf1[i];
        if (t < 16) bcs[t] = bcomb[t];
        if (t < 64) { icnt[t] = 0; degw[t] = 1.0f; deg2s[t] = 0.0f; }
        if (t < 128) LSs[t] = 0.0f;
    }
    __syncthreads();

    // P1: counts + weighted degrees
    {
        int dd = dsts[t], s = srcs[t];
        float w = lwx[t];
        atomicAdd(&icnt[dd], 1);
        atomicAdd(&degw[dd], w);
        atomicAdd(&deg2s[s], w);
    }
    __syncthreads();

    // P2: wave0 scans counts -> offsets; dinv
    if (t < 64) {
        int v = icnt[t], own = v;
        for (int o = 1; o < 64; o <<= 1) { int u = __shfl_up(v, o); if (t >= o) v += u; }
        int excl = v - own;
        offs[t] = excl; curs[t] = excl;
        dinvs[t] = rsqrtf(degw[t]);
        float dg = deg2s[t];
        dinv2s[t] = dg > 0.0f ? rsqrtf(fmaxf(dg, 1e-30f)) : 0.0f;
    }
    __syncthreads();

    // P3: place edges into CSR; precompute gcn norm and laplacian lw
    {
        int s = srcs[t], dd = dsts[t];
        float w = lwx[t];
        int pos = atomicAdd(&curs[dd], 1);
        lsrc[pos] = s;
        lnrm[pos] = dinvs[s] * w * dinvs[dd];
        lwx[t] = -dinv2s[s] * w * dinv2s[dd];
    }
    __syncthreads();

    // P4: gather xa[n] = x[n]*dinv^2 + sum_{e->n} x[src]*nrm into REGISTERS,
    // then write back in place over xs (extra barrier, -17 KB LDS).
    {
        int n = t >> 2, base = (t & 3) * 16;
        float sc = dinvs[n] * dinvs[n];
        const float* xrow = &xs[n * 68 + base];
        float4 A0 = *(const float4*)&xrow[0];
        float4 A1 = *(const float4*)&xrow[4];
        float4 A2 = *(const float4*)&xrow[8];
        float4 A3 = *(const float4*)&xrow[12];
        A0.x *= sc; A0.y *= sc; A0.z *= sc; A0.w *= sc;
        A1.x *= sc; A1.y *= sc; A1.z *= sc; A1.w *= sc;
        A2.x *= sc; A2.y *= sc; A2.z *= sc; A2.w *= sc;
        A3.x *= sc; A3.y *= sc; A3.z *= sc; A3.w *= sc;
        int o = offs[n], c = icnt[n];
        for (int j = 0; j < c; ++j) {
            int s = lsrc[o + j];
            float nm = lnrm[o + j];
            const float* xr = &xs[s * 68 + base];
            float4 X0 = *(const float4*)&xr[0];
            float4 X1 = *(const float4*)&xr[4];
            float4 X2 = *(const float4*)&xr[8];
            float4 X3 = *(const float4*)&xr[12];
            A0.x += X0.x * nm; A0.y += X0.y * nm; A0.z += X0.z * nm; A0.w += X0.w * nm;
            A1.x += X1.x * nm; A1.y += X1.y * nm; A1.z += X1.z * nm; A1.w += X1.w * nm;
            A2.x += X2.x * nm; A2.y += X2.y * nm; A2.z += X2.z * nm; A2.w += X2.w * nm;
            A3.x += X3.x * nm; A3.y += X3.y * nm; A3.z += X3.z * nm; A3.w += X3.w * nm;
        }
        __syncthreads();   // all reads of x (in xs) complete
        float* xw = &xs[n * 68 + base];
        *(float4*)&xw[0]  = A0;
        *(float4*)&xw[4]  = A1;
        *(float4*)&xw[8]  = A2;
        *(float4*)&xw[12] = A3;
    }
    __syncthreads();       // xa (in xs) visible

    // P5: a1 = tanh(xa @ Wgf1 + bcomb)  (64x64 @ 64x16)
    {
        int n = t >> 2, j0 = (t & 3) * 4;
        float a0 = bcs[j0], a1v = bcs[j0 + 1], a2 = bcs[j0 + 2], a3 = bcs[j0 + 3];
#pragma unroll 4
        for (int k4 = 0; k4 < 16; ++k4) {
            float4 hv = *(const float4*)&xs[n * 68 + k4 * 4];
            float4 w0 = *(const float4*)&Wgf1s[(k4 * 4 + 0) * 16 + j0];
            float4 w1 = *(const float4*)&Wgf1s[(k4 * 4 + 1) * 16 + j0];
            float4 w2 = *(const float4*)&Wgf1s[(k4 * 4 + 2) * 16 + j0];
            float4 w3 = *(const float4*)&Wgf1s[(k4 * 4 + 3) * 16 + j0];
            a0  += hv.x * w0.x + hv.y * w1.x + hv.z * w2.x + hv.w * w3.x;
            a1v += hv.x * w0.y + hv.y * w1.y + hv.z * w2.y + hv.w * w3.y;
            a2  += hv.x * w0.z + hv.y * w1.z + hv.z * w2.z + hv.w * w3.z;
            a3  += hv.x * w0.w + hv.y * w1.w + hv.z * w2.w + hv.w * w3.w;
        }
        a1s[n * 16 + j0]     = tanhf(a0);
        a1s[n * 16 + j0 + 1] = tanhf(a1v);
        a1s[n * 16 + j0 + 2] = tanhf(a2);
        a1s[n * 16 + j0 + 3] = tanhf(a3);
    }
    __syncthreads();

    // P6: S logits
    if (t < 128) {
        int n = t >> 1, kk = t & 1;
        float z = bf2[kk];
#pragma unroll
        for (int j = 0; j < 16; ++j) z += a1s[n * 16 + j] * Wf2[j * 2 + kk];
        Ss[n * 2 + kk] = z;
    }
    __syncthreads();

    // P7: softmax rows + row sums
    if (t < 64) {
        float z0 = Ss[t * 2], z1 = Ss[t * 2 + 1];
        float m = fmaxf(z0, z1);
        float e0 = expf(z0 - m), e1 = expf(z1 - m);
        float inv = 1.0f / (e0 + e1);
        e0 *= inv; e1 *= inv;
        Ss[t * 2] = e0; Ss[t * 2 + 1] = e1;
        Ssum[t] = e0 + e1;
    }
    __syncthreads();

    // P8: LS scatter part (identity added at use)
    for (int i = t; i < 512; i += 256) {
        int e = i >> 1, kk = i & 1;
        atomicAdd(&LSs[srcs[e] * 2 + kk], lwx[e] * Ss[dsts[e] * 2 + kk]);
    }
    __syncthreads();

    // P9: penalty (wave0) + Qh partials (all threads)
    if (t < 64) {
        float s0 = Ss[t * 2], s1 = Ss[t * 2 + 1];
        float l0 = s0 + LSs[t * 2], l1 = s1 + LSs[t * 2 + 1];
        float p00 = s0 * l0, p01 = s0 * l1, p10 = s1 * l0, p11 = s1 * l1;
        for (int o = 32; o; o >>= 1) {
            p00 += __shfl_down(p00, o); p01 += __shfl_down(p01, o);
            p10 += __shfl_down(p10, o); p11 += __shfl_down(p11, o);
        }
        if (t == 0) {
            float r0 = fmaxf(fabsf(p00) + fabsf(p01), 1e-12f);
            float r1 = fmaxf(fabsf(p10) + fabsf(p11), 1e-12f);
            float d0 = p00 / r0 - 1.0f, d1 = p11 / r1 - 1.0f;
            pens[g] = 0.5f * (d0 * d0 + d1 * d1);
        }
    }
    {
        int k = t & 63, p = t >> 6;
        float qk = 0.f;
#pragma unroll 4
        for (int n = p * 16; n < p * 16 + 16; ++n)
            qk += Ssum[n] * xs[n * 68 + k];
        __syncthreads();
        a1s[p * 64 + k] = qk;
    }
    __syncthreads();
    if (t < 64)
        Qh[(size_t)g * 64 + t] = 0.5f * (a1s[t] + a1s[64 + t] + a1s[128 + t] + a1s[192 + t]);
}

// ---------------------------------------------------------------------------
// Parallel CSR build over pos_edges (3 small kernels; round-6 showed the
// merged single-block version serializes on one CU).
// ---------------------------------------------------------------------------
__global__ void k_cnt(const int* __restrict__ pd, int* __restrict__ icnt) {
    int e = blockIdx.x * 256 + threadIdx.x;
    atomicAdd(&icnt[pd[e]], 1);
}

__global__ void k_scan(const int* __restrict__ icnt, int* __restrict__ offs,
                       int* __restrict__ curs, float* __restrict__ dinv) {
    __shared__ int wsum[4];
    int t = threadIdx.x;
    int base = t * 16;
    int l0,l1,l2,l3,l4,l5,l6,l7,l8,l9,l10,l11,l12,l13,l14,l15;
    l0=icnt[base+0]; l1=icnt[base+1]; l2=icnt[base+2]; l3=icnt[base+3];
    l4=icnt[base+4]; l5=icnt[base+5]; l6=icnt[base+6]; l7=icnt[base+7];
    l8=icnt[base+8]; l9=icnt[base+9]; l10=icnt[base+10]; l11=icnt[base+11];
    l12=icnt[base+12]; l13=icnt[base+13]; l14=icnt[base+14]; l15=icnt[base+15];
    int s = l0+l1+l2+l3+l4+l5+l6+l7+l8+l9+l10+l11+l12+l13+l14+l15;
    int lane = t & 63, w = t >> 6;
    int v = s;
    for (int o = 1; o < 64; o <<= 1) { int u = __shfl_up(v, o); if (lane >= o) v += u; }
    if (lane == 63) wsum[w] = v;
    __syncthreads();
    int woff = 0;
    for (int i = 0; i < 4; ++i) if (i < w) woff += wsum[i];
    int run = woff + v - s;
#define SC(L, I) offs[base+(I)] = run; curs[base+(I)] = run; \
    dinv[base+(I)] = rsqrtf((float)(L) + 1.0f); run += L;
    SC(l0,0) SC(l1,1) SC(l2,2) SC(l3,3) SC(l4,4) SC(l5,5) SC(l6,6) SC(l7,7)
    SC(l8,8) SC(l9,9) SC(l10,10) SC(l11,11) SC(l12,12) SC(l13,13) SC(l14,14) SC(l15,15)
#undef SC
}

__global__ void k_place(const int* __restrict__ pe, const float* __restrict__ dinv,
                        int* __restrict__ curs, int* __restrict__ csr_src,
                        float* __restrict__ csr_nrm) {
    int e = blockIdx.x * 256 + threadIdx.x;
    int s = pe[e], d = pe[EP + e];
    int pos = atomicAdd(&curs[d], 1);
    csr_src[pos] = s;
    csr_nrm[pos] = dinv[s] * dinv[d];
}

// ---------------------------------------------------------------------------
// CSR gathers: out[g] = in[g]*dinv[g]^2 + sum_{edges->g} in[src]*nrm.
// ---------------------------------------------------------------------------
__global__ void k_gather128(const int* __restrict__ offs, const int* __restrict__ icnt,
                            const int* __restrict__ csr_src, const float* __restrict__ csr_nrm,
                            const float* __restrict__ dinv, const float* __restrict__ in,
                            float* __restrict__ out) {
    int g = blockIdx.x, d = threadIdx.x;  // 128 threads
    float dv = dinv[g];
    float acc = in[(size_t)g * 128 + d] * dv * dv;
    int o = offs[g], c = icnt[g];
    for (int j = 0; j < c; ++j)
        acc += in[(size_t)csr_src[o + j] * 128 + d] * csr_nrm[o + j];
    out[(size_t)g * 128 + d] = acc;
}

__global__ void k_gather256(const int* __restrict__ offs, const int* __restrict__ icnt,
                            const int* __restrict__ csr_src, const float* __restrict__ csr_nrm,
                            const float* __restrict__ dinv, const float* __restrict__ in,
                            float* __restrict__ out) {
    int g = blockIdx.x, d = threadIdx.x;  // 256 threads
    float dv = dinv[g];
    float acc = in[(size_t)g * 256 + d] * dv * dv;
    int o = offs[g], c = icnt[g];
    for (int j = 0; j < c; ++j)
        acc += in[(size_t)csr_src[o + j] * 256 + d] * csr_nrm[o + j];
    out[(size_t)g * 256 + d] = acc;
}

// ---------------------------------------------------------------------------
// Double-buffered tiled fp32 GEMM (unchanged): 64x64 tile, 256 threads,
// 4x4 microtile, BK=32, register-prefetch + 2x LDS buffers.
// Dual-output option: blockIdx.y >= gridDim.y/2 uses B1/bias1/C1 (shared A).
// ---------------------------------------------------------------------------
__global__ __launch_bounds__(256) void k_gemm(
    const float* __restrict__ A,
    const float* __restrict__ B0, const float* __restrict__ bias0, float* __restrict__ C0,
    const float* __restrict__ B1, const float* __restrict__ bias1, float* __restrict__ C1,
    int M, int K, int N, int dorelu)
{
    __shared__ __align__(16) float lds[2 * 4352];
    const float* B = B0; const float* bias = bias0; float* C = C0;
    int by = blockIdx.y;
    if (B1 != nullptr && by >= (int)(gridDim.y >> 1)) {
        B = B1; bias = bias1; C = C1; by -= (gridDim.y >> 1);
    }
    const int mb = blockIdx.x * 64, nbb = by * 64;
    const int t = threadIdx.x;
    const int tm4 = (t >> 4) * 4, tn4 = (t & 15) * 4;
    const int ma = t >> 2, ka = (t & 3) * 8;
    const int kb = t >> 3, nb8 = (t & 7) * 8;

    float4 pa0, pa1, pb0, pb1;
#define LOADT(K0) { \
    const float* Ap = &A[(size_t)(mb + ma) * K + (K0) + ka]; \
    pa0 = *(const float4*)Ap; pa1 = *(const float4*)(Ap + 4); \
    const float* Bp = &B[(size_t)((K0) + kb) * N + nbb + nb8]; \
    pb0 = *(const float4*)Bp; pb1 = *(const float4*)(Bp + 4); }
#define STORET(BUF) { \
    float* At_ = lds + (BUF) * 4352; \
    At_[(ka + 0) * 68 + ma] = pa0.x; At_[(ka + 1) * 68 + ma] = pa0.y; \
    At_[(ka + 2) * 68 + ma] = pa0.z; At_[(ka + 3) * 68 + ma] = pa0.w; \
    At_[(ka + 4) * 68 + ma] = pa1.x; At_[(ka + 5) * 68 + ma] = pa1.y; \
    At_[(ka + 6) * 68 + ma] = pa1.z; At_[(ka + 7) * 68 + ma] = pa1.w; \
    float* Bs_ = lds + (BUF) * 4352 + 2176; \
    *(float4*)&Bs_[kb * 68 + nb8] = pb0; *(float4*)&Bs_[kb * 68 + nb8 + 4] = pb1; }

    float4 ca0 = {0,0,0,0}, ca1 = {0,0,0,0}, ca2 = {0,0,0,0}, ca3 = {0,0,0,0};
    const int nk0 = K >> 5;
    LOADT(0)
    STORET(0)
    __syncthreads();
    for (int it = 0; it < nk0; ++it) {
        if (it + 1 < nk0) LOADT((it + 1) * 32)
        const float* At_ = lds + (it & 1) * 4352;
        const float* Bs_ = At_ + 2176;
#pragma unroll
        for (int k = 0; k < 32; ++k) {
            float4 av = *(const float4*)&At_[k * 68 + tm4];
            float4 bv = *(const float4*)&Bs_[k * 68 + tn4];
            ca0.x += av.x * bv.x; ca0.y += av.x * bv.y; ca0.z += av.x * bv.z; ca0.w += av.x * bv.w;
            ca1.x += av.y * bv.x; ca1.y += av.y * bv.y; ca1.z += av.y * bv.z; ca1.w += av.y * bv.w;
            ca2.x += av.z * bv.x; ca2.y += av.z * bv.y; ca2.z += av.z * bv.z; ca2.w += av.z * bv.w;
            ca3.x += av.w * bv.x; ca3.y += av.w * bv.y; ca3.z += av.w * bv.z; ca3.w += av.w * bv.w;
        }
        if (it + 1 < nk0) {
            STORET((it + 1) & 1)
            __syncthreads();
        }
    }
#undef LOADT
#undef STORET
    float4 bv4 = {0, 0, 0, 0};
    if (bias) bv4 = *(const float4*)&bias[nbb + tn4];
#define CST(I, CV) { \
    float4 v; v.x = CV.x + bv4.x; v.y = CV.y + bv4.y; v.z = CV.z + bv4.z; v.w = CV.w + bv4.w; \
    if (dorelu) { v.x = fmaxf(v.x, 0.f); v.y = fmaxf(v.y, 0.f); v.z = fmaxf(v.z, 0.f); v.w = fmaxf(v.w, 0.f); } \
    *(float4*)&C[(size_t)(mb + tm4 + (I)) * N + nbb + tn4] = v; }
    CST(0, ca0) CST(1, ca1) CST(2, ca2) CST(3, ca3)
#undef CST
}

// z = mu + eps*exp(min(ls,10)); zc = [emb, z]; per-graph KL partial
__global__ void k_fin_z(const float* __restrict__ mu_arr, const float* __restrict__ ls_arr,
                        const float* __restrict__ eps, const float* __restrict__ emb,
                        float* __restrict__ zc, float* __restrict__ klp) {
    __shared__ float smw[2];
    int g = blockIdx.x, d = threadIdx.x;  // 128 threads
    int idx = g * 128 + d;
    float mu = mu_arr[idx];
    float ls = fminf(ls_arr[idx], 10.0f);
    float z = mu + eps[idx] * expf(ls);
    zc[(size_t)g * 256 + d] = emb[idx];
    zc[(size_t)g * 256 + 128 + d] = z;
    float term = 1.0f + 2.0f * ls - mu * mu - expf(2.0f * ls);
    for (int o = 32; o; o >>= 1) term += __shfl_down(term, o);
    if ((d & 63) == 0) smw[d >> 6] = term;
    __syncthreads();
    if (d == 0) klp[g] = smw[0] + smw[1];
}

// Edge predictions, 16 lanes per edge (4 edges in flight per wave, 4-step
// reduce): sigmoid(dot(A[src], B[dst])) + per-block log partial (16 edges).
__global__ void k_pred(const float* __restrict__ A, const float* __restrict__ B,
                       const int* __restrict__ pos, const int* __restrict__ neg,
                       float* __restrict__ out, float* __restrict__ predp) {
    __shared__ float smw[16];
    int t = threadIdx.x, sub = t >> 4, l = t & 15;
    int eg = blockIdx.x * 16 + sub;
    int isneg = eg >= EP;
    int e = eg - (isneg ? EP : 0);
    const int* eix = isneg ? neg : pos;
    int s = eix[e], d = eix[EP + e];
    const float4* Ar = (const float4*)(A + (size_t)s * 256);
    const float4* Br = (const float4*)(B + (size_t)d * 256);
    float dot = 0.f;
#pragma unroll
    for (int q = 0; q < 4; ++q) {
        float4 av = Ar[l + 16 * q], bv = Br[l + 16 * q];
        dot += av.x * bv.x + av.y * bv.y + av.z * bv.z + av.w * bv.w;
    }
    for (int o = 8; o; o >>= 1) dot += __shfl_down(dot, o);
    if (l == 0) {
        float p = 1.0f / (1.0f + expf(-dot));
        float term;
        if (isneg) { out[2 + EP + e] = p; term = logf(1.0f - p + 1e-15f); }
        else       { out[2 + e] = p;      term = logf(p + 1e-15f); }
        smw[sub] = term;
    }
    __syncthreads();
    if (t == 0) {
        float s16 = 0.f;
#pragma unroll
        for (int i = 0; i < 16; ++i) s16 += smw[i];
        predp[blockIdx.x] = s16;
    }
}

// Final scalar reductions (predp now 4096 entries: 2048 pos + 2048 neg)
__global__ void k_final(const float* __restrict__ pens, const float* __restrict__ klp,
                        const float* __restrict__ predp, float* __restrict__ out) {
    __shared__ float sm[16];
    int t = threadIdx.x;
    float s_pen = 0.f, s_kl = 0.f, s_pos = 0.f, s_neg = 0.f;
    for (int i = t; i < 4096; i += 256) { s_pen += pens[i]; s_kl += klp[i]; }
    for (int i = t; i < 2048; i += 256) { s_pos += predp[i]; s_neg += predp[2048 + i]; }
    for (int o = 32; o; o >>= 1) {
        s_pen += __shfl_down(s_pen, o); s_kl += __shfl_down(s_kl, o);
        s_pos += __shfl_down(s_pos, o); s_neg += __shfl_down(s_neg, o);
    }
    int w = t >> 6;
    if ((t & 63) == 0) { sm[w] = s_pen; sm[4 + w] = s_kl; sm[8 + w] = s_pos; sm[12 + w] = s_neg; }
    __syncthreads();
    if (t == 0) {
        float pen = sm[0] + sm[1] + sm[2] + sm[3];
        float kls = sm[4] + sm[5] + sm[6] + sm[7];
        float pos = sm[8] + sm[9] + sm[10] + sm[11];
        float neg = sm[12] + sm[13] + sm[14] + sm[15];
        float rec = -(pos / 32768.0f) - (neg / 32768.0f);
        out[0] = rec - 0.5f * kls / (4096.0f * 4096.0f);
        out[1] = pen * (1.0f / 4096.0f);
    }
}

extern "C" void kernel_launch(void* const* d_in, const int* in_sizes, int n_in,
                              void* d_out, int out_size, void* d_ws, size_t ws_size,
                              hipStream_t stream) {
    const float* x   = (const float*)d_in[0];
    const int*   ei  = (const int*)d_in[1];
    const float* ew  = (const float*)d_in[2];
    const int*   pos = (const int*)d_in[3];
    const int*   neg = (const int*)d_in[4];
    const float* eps = (const float*)d_in[5];
    const float* Wg  = (const float*)d_in[6];
    const float* bg  = (const float*)d_in[7];
    const float* Wf1 = (const float*)d_in[8];
    const float* bf1 = (const float*)d_in[9];
    const float* Wf2 = (const float*)d_in[10];
    const float* bf2 = (const float*)d_in[11];
    const float* Wc1 = (const float*)d_in[12];
    const float* bc1 = (const float*)d_in[13];
    const float* Wmu = (const float*)d_in[14];
    const float* bmu = (const float*)d_in[15];
    const float* Wls = (const float*)d_in[16];
    const float* bls = (const float*)d_in[17];
    const float* emb = (const float*)d_in[18];
    const float* Wl1 = (const float*)d_in[19];
    const float* bl1 = (const float*)d_in[20];
    const float* Wl2 = (const float*)d_in[21];
    const float* bl2 = (const float*)d_in[22];
    float* out = (float*)d_out;
    float* ws  = (float*)d_ws;

    // Workspace layout (floats), ~30.8 MB
    float* g_embs  = ws + 0;         // 524288
    float* dinv    = ws + 524288;    // 4096
    int*   icnt_g  = (int*)(ws + 528384);  // 4096
    int*   off_g   = (int*)(ws + 532480);  // 4096
    int*   cur_g   = (int*)(ws + 536576);  // 4096
    int*   csr_src = (int*)(ws + 540672);  // 32768
    float* csr_nrm = ws + 573440;    // 32768
    float* Qh      = ws + 606208;    // 262144
    float* ga      = ws + 868352;    // 524288
    float* h       = ws + 1392640;   // 1048576
    float* ha      = ws + 2441216;   // 1048576
    float* mu_arr  = ws + 3489792;   // 524288
    float* ls_arr  = ws + 4014080;   // 524288
    float* zc      = ws + 4538368;   // 1048576
    float* Abuf    = ws + 5586944;   // 1048576
    float* Bbuf    = ws + 6635520;   // 1048576
    float* pens    = ws + 7684096;   // 4096
    float* klp     = ws + 7688192;   // 4096
    float* predp   = ws + 7692288;   // 4096
    float* Wgf1    = ws + 7708672;   // 1024
    float* bcomb   = ws + 7709696;   // 16
    float* bg32    = ws + 7709712;   // 128

    // Zero the CSR counter (16 KB)
    hipMemsetAsync(icnt_g, 0, 4096u * 4, stream);

    // Prep + per-graph stage
    k_prep<<<1, 256, 0, stream>>>(Wg, Wf1, bf1, bg, Wgf1, bcomb, bg32);
    k_pg<<<GG, 256, 0, stream>>>(x, ei, ew, Wgf1, bcomb, Wf2, bf2, Qh, pens);
    // g_embs = Qh @ Wg + 32*bg
    k_gemm<<<dim3(64, 2), 256, 0, stream>>>(Qh, Wg, bg32, g_embs,
                                            nullptr, nullptr, nullptr, GG, 64, 128, 0);

    // Parallel CSR build over pos_edges
    k_cnt<<<EP / 256, 256, 0, stream>>>(pos + EP, icnt_g);
    k_scan<<<1, 256, 0, stream>>>(icnt_g, off_g, cur_g, dinv);
    k_place<<<EP / 256, 256, 0, stream>>>(pos, dinv, cur_g, csr_src, csr_nrm);

    // h = relu((A g_embs) @ Wc1 + bc1)
    k_gather128<<<GG, 128, 0, stream>>>(off_g, icnt_g, csr_src, csr_nrm, dinv, g_embs, ga);
    k_gemm<<<dim3(64, 4), 256, 0, stream>>>(ga, Wc1, bc1, h,
                                            nullptr, nullptr, nullptr, GG, 128, 256, 1);

    // mu/ls = (A h) @ {Wmu,Wls} + {bmu,bls}
    k_gather256<<<GG, 256, 0, stream>>>(off_g, icnt_g, csr_src, csr_nrm, dinv, h, ha);
    k_gemm<<<dim3(64, 4), 256, 0, stream>>>(ha, Wmu, bmu, mu_arr,
                                            Wls, bls, ls_arr, GG, 256, 128, 0);
    k_fin_z<<<GG, 128, 0, stream>>>(mu_arr, ls_arr, eps, emb, zc, klp);

    // A = zc@W_lin1+b, B = zc@W_lin2+b
    k_gemm<<<dim3(64, 8), 256, 0, stream>>>(zc, Wl1, bl1, Abuf,
                                            Wl2, bl2, Bbuf, GG, 256, 256, 0);

    // Edge predictions + scalars (16 edges/block)
    k_pred<<<(2 * EP) / 16, 256, 0, stream>>>(Abuf, Bbuf, pos, neg, out, predp);
    k_final<<<1, 256, 0, stream>>>(pens, klp, predp, out);
}